// Round 7
// baseline (1218.789 us; speedup 1.0000x reference)
//
#include <hip/hip_runtime.h>
#include <cstdint>
#include <cstddef>

#define NN     20000
#define NE     320000
#define NR     16
#define DIN    128
#define DH     512
#define DOUT   128
#define NT     50000
#define TILE   64
#define CHUNKS 8
#define CHD    2500
#define SB     625                     // src block size
#define NSB    32                      // src blocks
#define NKEY1  (CHUNKS * NR * NSB)     // 4096 fine keys, layer 1
#define NKEY2  (NSB * NR)              // 512 fine keys, layer 2 (srcblk-major)
#define NBUCKET (CHUNKS * NR)          // 128 coarse buckets (layer-1 tile cut)
#define MSGROWS 46080                  // max edges per chunk
#define MAXTPC  768                    // l1 grid per chunk (%8==0)
#define MAXT2   5632                   // l2 grid (%8==0, >= NE/64+NKEY2=5512)
#define NTILESMAX (NE / TILE + NBUCKET)

typedef __attribute__((ext_vector_type(8))) short bf16x8;
typedef __attribute__((ext_vector_type(4))) float f32x4;

__device__ __forceinline__ unsigned short f2bf(float x) {
    unsigned int b = __float_as_uint(x);
    b = b + 0x7fffu + ((b >> 16) & 1u);
    return (unsigned short)(b >> 16);
}
__device__ __forceinline__ float bf2f(unsigned short u) {
    return __uint_as_float(((unsigned int)u) << 16);
}
__device__ __forceinline__ unsigned packbf(float lo, float hi) {
    return (unsigned)f2bf(lo) | ((unsigned)f2bf(hi) << 16);
}

// ---------------- fold attention vectors into weights ----------------
__global__ void alpha1_kernel(const float* __restrict__ W1, const float* __restrict__ aq1,
                              const float* __restrict__ ak1, float* __restrict__ alpha1) {
    int i = blockIdx.x;
    int c = threadIdx.x;
    int r = c >> 4, s = (c >> 3) & 1, h = c & 7;
    const float* att = (s == 0 ? aq1 : ak1) + (r * 8 + h) * 64;
    const float* w = W1 + ((size_t)(r * DIN + i)) * DH + h * 64;
    float acc = 0.f;
    #pragma unroll 8
    for (int o = 0; o < 64; ++o) acc += w[o] * att[o];
    alpha1[i * 256 + c] = acc;
}

__global__ void alpha2_kernel(const float* __restrict__ W2, const float* __restrict__ aq2,
                              const float* __restrict__ ak2, float* __restrict__ alpha2) {
    int g = blockIdx.x * blockDim.x + threadIdx.x;
    if (g >= DH * 32) return;
    int i = g >> 5, c = g & 31;
    int r = c >> 1, s = c & 1;
    const float* att = (s == 0 ? aq2 : ak2) + r * DOUT;
    const float* w = W2 + ((size_t)(r * DH + i)) * DOUT;
    float acc = 0.f;
    #pragma unroll 8
    for (int o = 0; o < DOUT; ++o) acc += w[o] * att[o];
    alpha2[i * 32 + c] = acc;
}

// ---------------- bf16 hi/lo precompute ----------------
__global__ void split_x_kernel(const float* __restrict__ x, unsigned short* __restrict__ xhi,
                               unsigned short* __restrict__ xlo) {
    int g = blockIdx.x * 256 + threadIdx.x;
    if (g >= NN * DIN / 4) return;
    float4 v = ((const float4*)x)[g];
    ushort4 h, l;
    h.x = f2bf(v.x); l.x = f2bf(v.x - bf2f(h.x));
    h.y = f2bf(v.y); l.y = f2bf(v.y - bf2f(h.y));
    h.z = f2bf(v.z); l.z = f2bf(v.z - bf2f(h.z));
    h.w = f2bf(v.w); l.w = f2bf(v.w - bf2f(h.w));
    ((ushort4*)xhi)[g] = h;
    ((ushort4*)xlo)[g] = l;
}

__global__ void splitW1T_kernel(const float* __restrict__ W1, unsigned short* __restrict__ Whi,
                                unsigned short* __restrict__ Wlo) {
    __shared__ float T[128 * 65];
    int r = blockIdx.x >> 3;
    int ob = blockIdx.x & 7;
    int tid = threadIdx.x;
    for (int idx = tid; idx < 128 * 64; idx += 256) {
        int i = idx >> 6, o = idx & 63;
        T[i * 65 + o] = W1[((size_t)(r * DIN + i)) * DH + ob * 64 + o];
    }
    __syncthreads();
    for (int idx = tid; idx < 64 * 128; idx += 256) {
        int o = idx >> 7, i = idx & 127;
        float v = T[i * 65 + o];
        unsigned short h = f2bf(v);
        size_t off = ((size_t)r * DH + ob * 64 + o) * DIN + i;
        Whi[off] = h;
        Wlo[off] = f2bf(v - bf2f(h));
    }
}

__global__ void splitW2T_kernel(const float* __restrict__ W2, unsigned short* __restrict__ Whi,
                                unsigned short* __restrict__ Wlo) {
    __shared__ float T[128 * 65];
    int r = blockIdx.x >> 1;
    int ob = blockIdx.x & 1;
    int tid = threadIdx.x;
    for (int kc = 0; kc < 4; ++kc) {
        if (kc) __syncthreads();
        for (int idx = tid; idx < 128 * 64; idx += 256) {
            int k = idx >> 6, o = idx & 63;
            T[k * 65 + o] = W2[((size_t)(r * DH + kc * 128 + k)) * DOUT + ob * 64 + o];
        }
        __syncthreads();
        for (int idx = tid; idx < 64 * 128; idx += 256) {
            int o = idx >> 7, k = idx & 127;
            float v = T[k * 65 + o];
            unsigned short h = f2bf(v);
            size_t off = ((size_t)r * DOUT + ob * 64 + o) * DH + kc * 128 + k;
            Whi[off] = h;
            Wlo[off] = f2bf(v - bf2f(h));
        }
    }
}

__global__ void splitLw1_kernel(const float* __restrict__ lw1, unsigned short* __restrict__ Lhi,
                                unsigned short* __restrict__ Llo) {
    int g = blockIdx.x * 256 + threadIdx.x;
    if (g >= 256 * 128) return;
    int o = g >> 8, k = g & 255;
    float v = lw1[k * 128 + o];
    unsigned short h = f2bf(v);
    Lhi[(size_t)o * 256 + k] = h;
    Llo[(size_t)o * 256 + k] = f2bf(v - bf2f(h));
}

// ---------------- sorts ----------------
__global__ void hist_all_kernel(const int* __restrict__ ei, const int* __restrict__ et,
                                int* __restrict__ hist1, int* __restrict__ hist2,
                                int* __restrict__ cnt_d) {
    __shared__ int b1[NKEY1];
    __shared__ int b2[NKEY2];
    int t = threadIdx.x;
    for (int i = t; i < NKEY1; i += 256) b1[i] = 0;
    for (int i = t; i < NKEY2; i += 256) b2[i] = 0;
    __syncthreads();
    int e = blockIdx.x * 256 + t;
    if (e < NE) {
        int s = ei[e], d = ei[NE + e], r = et[e];
        int k1 = ((d / CHD) * NR + r) * NSB + s / SB;
        int k2 = (s / SB) * NR + r;
        atomicAdd(&b1[k1], 1);
        atomicAdd(&b2[k2], 1);
        atomicAdd(&cnt_d[d], 1);
    }
    __syncthreads();
    for (int i = t; i < NKEY1; i += 256) if (b1[i]) atomicAdd(&hist1[i], b1[i]);
    for (int i = t; i < NKEY2; i += 256) if (b2[i]) atomicAdd(&hist2[i], b2[i]);
}

__global__ void scan1_kernel(const int* __restrict__ hist1, int* __restrict__ offs1,
                             int* __restrict__ cursor1, int* __restrict__ boffs,
                             int* __restrict__ cts) {
    __shared__ int part[1024];
    int t = threadIdx.x;
    int base = t * 4;
    int v0 = hist1[base], v1 = hist1[base + 1], v2 = hist1[base + 2], v3 = hist1[base + 3];
    int s = v0 + v1 + v2 + v3;
    part[t] = s;
    __syncthreads();
    for (int off = 1; off < 1024; off <<= 1) {
        int v = (t >= off) ? part[t - off] : 0;
        __syncthreads();
        part[t] += v;
        __syncthreads();
    }
    int run = part[t] - s;
    offs1[base] = run; cursor1[base] = run; run += v0;
    offs1[base + 1] = run; cursor1[base + 1] = run; run += v1;
    offs1[base + 2] = run; cursor1[base + 2] = run; run += v2;
    offs1[base + 3] = run; cursor1[base + 3] = run;
    if (t == 1023) offs1[NKEY1] = part[1023];
    __syncthreads();
    if (t == 0) {
        int tiles = 0;
        for (int b = 0; b < NBUCKET; ++b) {
            if ((b & (NR - 1)) == 0) cts[b >> 4] = tiles;
            boffs[b] = offs1[b * NSB];
            int cn = offs1[(b + 1) * NSB] - offs1[b * NSB];
            tiles += (cn + TILE - 1) / TILE;
        }
        boffs[NBUCKET] = offs1[NKEY1];
        cts[CHUNKS] = tiles;
    }
}

__global__ void scan2_kernel(const int* __restrict__ hist2, int* __restrict__ offs2,
                             int* __restrict__ cursor2) {
    __shared__ int part[NKEY2];
    int t = threadIdx.x;
    int s = hist2[t];
    part[t] = s;
    __syncthreads();
    for (int off = 1; off < NKEY2; off <<= 1) {
        int v = (t >= off) ? part[t - off] : 0;
        __syncthreads();
        part[t] += v;
        __syncthreads();
    }
    offs2[t] = part[t] - s;
    cursor2[t] = part[t] - s;
    if (t == NKEY2 - 1) offs2[NKEY2] = part[t];
}

// layer-1 tile map over 128 coarse buckets
__global__ void tilemap_kernel(const int* __restrict__ boffs, int* __restrict__ tile_b,
                               int* __restrict__ tile_s) {
    __shared__ int bo[NBUCKET + 1];
    int tid = threadIdx.x;
    if (tid <= NBUCKET) bo[tid] = boffs[tid];
    __syncthreads();
    int t = blockIdx.x * 256 + tid;
    if (t >= NTILESMAX) return;
    int acc = 0, bb = -1, ss = 0;
    for (int b = 0; b < NBUCKET; ++b) {
        int cn = bo[b + 1] - bo[b];
        int nt = (cn + TILE - 1) / TILE;
        if (t >= acc && t < acc + nt) { bb = b; ss = bo[b] + (t - acc) * TILE; }
        acc += nt;
    }
    tile_b[t] = bb; tile_s[t] = ss;
}

// layer-2 tile map over 512 fine buckets
__global__ void tilemap2_kernel(const int* __restrict__ offs2, int* __restrict__ tile_b2,
                                int* __restrict__ tile_s2) {
    __shared__ int bo[NKEY2 + 1];
    int tid = threadIdx.x;
    for (int i = tid; i <= NKEY2; i += 256) bo[i] = offs2[i];
    __syncthreads();
    int t = blockIdx.x * 256 + tid;
    if (t >= MAXT2) return;
    int acc = 0, bb = -1, ss = 0;
    for (int b = 0; b < NKEY2; ++b) {
        int cn = bo[b + 1] - bo[b];
        int nt = (cn + TILE - 1) / TILE;
        if (t >= acc && t < acc + nt) { bb = b; ss = bo[b] + (t - acc) * TILE; }
        acc += nt;
    }
    tile_b2[t] = bb; tile_s2[t] = ss;
}

__global__ void place1_kernel(const int* __restrict__ ei, const int* __restrict__ et,
                              int* __restrict__ cursor1, int* __restrict__ border1) {
    __shared__ int binc[NKEY1];
    __shared__ int base_[NKEY1];
    __shared__ int rank_[NKEY1];
    int t = threadIdx.x;
    for (int i = t; i < NKEY1; i += 256) { binc[i] = 0; rank_[i] = 0; }
    __syncthreads();
    int e = blockIdx.x * 256 + t;
    int key = -1;
    if (e < NE) {
        int s = ei[e], d = ei[NE + e];
        key = ((d / CHD) * NR + et[e]) * NSB + s / SB;
        atomicAdd(&binc[key], 1);
    }
    __syncthreads();
    for (int i = t; i < NKEY1; i += 256) if (binc[i]) base_[i] = atomicAdd(&cursor1[i], binc[i]);
    __syncthreads();
    if (key >= 0) border1[base_[key] + atomicAdd(&rank_[key], 1)] = e;
}

__global__ void place2_kernel(const int* __restrict__ ei, const int* __restrict__ et,
                              int* __restrict__ cursor2, int* __restrict__ border2) {
    __shared__ int binc[NKEY2];
    __shared__ int base_[NKEY2];
    __shared__ int rank_[NKEY2];
    int t = threadIdx.x;
    for (int i = t; i < NKEY2; i += 256) { binc[i] = 0; rank_[i] = 0; }
    __syncthreads();
    int e = blockIdx.x * 256 + t;
    int key = -1;
    if (e < NE) {
        key = (ei[e] / SB) * NR + et[e];
        atomicAdd(&binc[key], 1);
    }
    __syncthreads();
    for (int i = t; i < NKEY2; i += 256) if (binc[i]) base_[i] = atomicAdd(&cursor2[i], binc[i]);
    __syncthreads();
    if (key >= 0) border2[base_[key] + atomicAdd(&rank_[key], 1)] = e;
}

__global__ void scan_dst_kernel(const int* __restrict__ cnt_d, int* __restrict__ doffs,
                                int* __restrict__ cursor_d) {
    __shared__ int part[1024];
    int t = threadIdx.x;
    int base = t * 20;
    int s = 0;
    for (int i = 0; i < 20 && base + i < NN; ++i) s += cnt_d[base + i];
    part[t] = s;
    __syncthreads();
    for (int off = 1; off < 1024; off <<= 1) {
        int v = (t >= off) ? part[t - off] : 0;
        __syncthreads();
        part[t] += v;
        __syncthreads();
    }
    int run = part[t] - s;
    for (int i = 0; i < 20 && base + i < NN; ++i) {
        doffs[base + i] = run; cursor_d[base + i] = run;
        run += cnt_d[base + i];
    }
    if (t == 1023) doffs[NN] = part[1023];
}

__global__ void place_dst_kernel(const int* __restrict__ border, const int* __restrict__ ei,
                                 int* __restrict__ cursor_d, int* __restrict__ dlist,
                                 int* __restrict__ dedge) {
    int pos = blockIdx.x * 256 + threadIdx.x;
    if (pos >= NE) return;
    int e = border[pos];
    int d = ei[NE + e];
    int idx = atomicAdd(&cursor_d[d], 1);
    dlist[idx] = pos;
    dedge[idx] = e;
}

// ---------------- qk1 = x @ alpha1 ----------------
__global__ void qk1_kernel(const float* __restrict__ x, const float* __restrict__ alpha1,
                           float* __restrict__ qk1) {
    __shared__ float Xt[TILE][DIN + 1];
    int n0 = blockIdx.x * TILE;
    int tid = threadIdx.x;
    for (int idx = tid; idx < TILE * DIN; idx += 256) {
        int row = idx >> 7, i = idx & 127;
        int n = n0 + row;
        Xt[row][i] = (n < NN) ? x[(size_t)n * DIN + i] : 0.f;
    }
    __syncthreads();
    int to = tid >> 4, te = tid & 15;
    for (int c = 0; c < 2; ++c) {
        float acc[4][8] = {};
        const float* Wp = alpha1 + c * 128 + to * 8;
        for (int i = 0; i < DIN; ++i) {
            float4 w0 = *(const float4*)(Wp + (size_t)i * 256);
            float4 w1 = *(const float4*)(Wp + (size_t)i * 256 + 4);
            float w[8] = {w0.x, w0.y, w0.z, w0.w, w1.x, w1.y, w1.z, w1.w};
            #pragma unroll
            for (int a = 0; a < 4; ++a) {
                float xv = Xt[te * 4 + a][i];
                #pragma unroll
                for (int b = 0; b < 8; ++b) acc[a][b] += xv * w[b];
            }
        }
        #pragma unroll
        for (int a = 0; a < 4; ++a) {
            int n = n0 + te * 4 + a;
            if (n < NN) {
                float* op = qk1 + (size_t)n * 256 + c * 128 + to * 8;
                #pragma unroll
                for (int b = 0; b < 8; ++b) op[b] = acc[a][b];
            }
        }
    }
}

__global__ void elogit1_kernel(const int* __restrict__ ei, const int* __restrict__ et,
                               const float* __restrict__ qk1, float* __restrict__ e1) {
    int e = blockIdx.x * blockDim.x + threadIdx.x;
    if (e >= NE) return;
    int src = ei[e], dst = ei[NE + e], r = et[e];
    const float* qp = qk1 + (size_t)dst * 256 + r * 16;
    const float* kp = qk1 + (size_t)src * 256 + r * 16 + 8;
    float* ep = e1 + (size_t)e * 8;
    #pragma unroll
    for (int h = 0; h < 8; ++h) {
        float l = qp[h] + kp[h];
        l = l > 0.f ? l : 0.2f * l;
        ep[h] = __expf(l);
    }
}

// ---------------- layer1 GEMM ----------------
__global__ __launch_bounds__(256, 2)
void l1_gemm_kernel(const unsigned short* __restrict__ xhi, const unsigned short* __restrict__ xlo,
                    const unsigned short* __restrict__ W1Thi, const unsigned short* __restrict__ W1Tlo,
                    const int* __restrict__ ei, const int* __restrict__ border,
                    const int* __restrict__ tile_b, const int* __restrict__ tile_s,
                    const int* __restrict__ boffs, const int* __restrict__ cts,
                    int c, unsigned* __restrict__ msgu) {
    int wg = (blockIdx.x & 7) * (MAXTPC / 8) + (blockIdx.x >> 3);   // XCD-contiguous
    int t = cts[c] + wg;
    if (t >= cts[c + 1]) return;
    int b = tile_b[t];
    int r = b & (NR - 1);
    int start = tile_s[t];
    int cstart = boffs[c * NR];
    int cnt = boffs[b + 1] - start; if (cnt > TILE) cnt = TILE;
    __shared__ __align__(16) unsigned short Ah[64 * 128];
    __shared__ __align__(16) unsigned short Al[64 * 128];
    __shared__ int srcS[TILE];
    int tid = threadIdx.x;
    if (tid < TILE) {
        int sv = 0;
        if (tid < cnt) { int e = border[start + tid]; sv = ei[e]; }
        srcS[tid] = sv;
    }
    __syncthreads();
    {
        int row = tid >> 2, seg = tid & 3;
        const uint4* ph = (const uint4*)(xhi + (size_t)srcS[row] * DIN + seg * 32);
        const uint4* pl = (const uint4*)(xlo + (size_t)srcS[row] * DIN + seg * 32);
        unsigned rb = row * 256, sw = (row & 7) << 4;
        #pragma unroll
        for (int i = 0; i < 4; ++i) {
            unsigned off = (rb + seg * 64 + i * 16) ^ sw;
            *(uint4*)((char*)Ah + off) = ph[i];
            *(uint4*)((char*)Al + off) = pl[i];
        }
    }
    __syncthreads();
    int w = tid >> 6, lane = tid & 63;
    int l15 = lane & 15, l4 = lane >> 4;
    const unsigned short* Bh = W1Thi + ((size_t)r * DH + w * 128 + l15) * DIN + l4 * 8;
    const unsigned short* Bl = W1Tlo + ((size_t)r * DH + w * 128 + l15) * DIN + l4 * 8;
    f32x4 acc[4][8];
    #pragma unroll
    for (int m = 0; m < 4; ++m)
        #pragma unroll
        for (int n = 0; n < 8; ++n) acc[m][n] = (f32x4){0.f, 0.f, 0.f, 0.f};
    #pragma unroll
    for (int mg = 0; mg < 2; ++mg) {
        bf16x8 ah[2][4], al[2][4];
        #pragma unroll
        for (int mm = 0; mm < 2; ++mm) {
            int row = (mg * 2 + mm) * 16 + l15;
            unsigned rb = row * 256, sw = (row & 7) << 4;
            #pragma unroll
            for (int k = 0; k < 4; ++k) {
                unsigned off = (rb + k * 64 + l4 * 16) ^ sw;
                ah[mm][k] = *(const bf16x8*)((const char*)Ah + off);
                al[mm][k] = *(const bf16x8*)((const char*)Al + off);
            }
        }
        #pragma unroll
        for (int n = 0; n < 8; ++n) {
            #pragma unroll
            for (int k = 0; k < 4; ++k) {
                bf16x8 bh = *(const bf16x8*)(Bh + (size_t)n * 16 * DIN + k * 32);
                bf16x8 bl = *(const bf16x8*)(Bl + (size_t)n * 16 * DIN + k * 32);
                #pragma unroll
                for (int mm = 0; mm < 2; ++mm) {
                    int m = mg * 2 + mm;
                    acc[m][n] = __builtin_amdgcn_mfma_f32_16x16x32_bf16(ah[mm][k], bh, acc[m][n], 0, 0, 0);
                    acc[m][n] = __builtin_amdgcn_mfma_f32_16x16x32_bf16(ah[mm][k], bl, acc[m][n], 0, 0, 0);
                    acc[m][n] = __builtin_amdgcn_mfma_f32_16x16x32_bf16(al[mm][k], bh, acc[m][n], 0, 0, 0);
                }
            }
        }
    }
    unsigned* mb = msgu + (size_t)(start - cstart) * 256 + w * 64 + l15;
    #pragma unroll
    for (int m = 0; m < 4; ++m) {
        int row0 = m * 16 + l4 * 4;
        #pragma unroll
        for (int rg = 0; rg < 4; ++rg) {
            int row = row0 + rg;
            if (row < cnt) {
                unsigned* mp = mb + (size_t)row * 256;
                #pragma unroll
                for (int q = 0; q < 4; ++q) {
                    int n0 = ((q >> 1) << 2) | (q & 1);
                    mp[q * 16] = packbf(acc[m][n0][rg], acc[m][n0 + 2][rg]);
                }
            }
        }
    }
}

// ---------------- layer1 agg (fused qk2) ----------------
__global__ void l1_agg_kernel(const unsigned* __restrict__ msgu, const float* __restrict__ e1,
                              const int* __restrict__ dlist, const int* __restrict__ dedge,
                              const int* __restrict__ doffs, const int* __restrict__ boffs,
                              int c, unsigned short* __restrict__ hhi, unsigned short* __restrict__ hlo,
                              const float* __restrict__ alpha2, float* __restrict__ qk2v) {
    __shared__ float hrow[DH];
    __shared__ float red[32][9];
    int tid = threadIdx.x;
    int d = c * CHD + blockIdx.x;
    int lo_ = doffs[d], hi_ = doffs[d + 1];
    int cstart = boffs[c * NR];
    int head = tid >> 5;
    float a0 = 0.f, a1 = 0.f, se = 0.f;
    for (int p = lo_; p < hi_; ++p) {
        int pos = dlist[p];
        float wgt = e1[(size_t)dedge[p] * 8 + head];
        se += wgt;
        unsigned v = msgu[(size_t)(pos - cstart) * 256 + tid];
        a0 += wgt * bf2f((unsigned short)(v & 0xffff));
        a1 += wgt * bf2f((unsigned short)(v >> 16));
    }
    float inv = 1.f / (se + 1e-16f);
    a0 *= inv; a1 *= inv;
    a0 = a0 > 0.f ? a0 : 0.f;
    a1 = a1 > 0.f ? a1 : 0.f;
    int w = tid >> 6, q = (tid >> 4) & 3, l15 = tid & 15;
    int n0 = ((q >> 1) << 2) | (q & 1);
    int c0 = w * 128 + n0 * 16 + l15;
    hrow[c0] = a0; hrow[c0 + 32] = a1;
    unsigned short h0 = f2bf(a0), h1 = f2bf(a1);
    hhi[(size_t)d * DH + c0] = h0;
    hlo[(size_t)d * DH + c0] = f2bf(a0 - bf2f(h0));
    hhi[(size_t)d * DH + c0 + 32] = h1;
    hlo[(size_t)d * DH + c0 + 32] = f2bf(a1 - bf2f(h1));
    __syncthreads();
    int j = tid & 31, ib = tid >> 5;
    float s = 0.f;
    #pragma unroll 8
    for (int i = ib * 64; i < ib * 64 + 64; ++i) s += hrow[i] * alpha2[(size_t)i * 32 + j];
    red[j][ib] = s;
    __syncthreads();
    if (tid < 32) {
        float t = 0.f;
        #pragma unroll
        for (int g = 0; g < 8; ++g) t += red[tid][g];
        qk2v[(size_t)d * 32 + tid] = t;
    }
}

__global__ void elogit2_kernel(const int* __restrict__ ei, const int* __restrict__ et,
                               const float* __restrict__ qk2, float* __restrict__ e2) {
    int e = blockIdx.x * blockDim.x + threadIdx.x;
    if (e >= NE) return;
    int src = ei[e], dst = ei[NE + e], r = et[e];
    float l = qk2[(size_t)dst * 32 + r * 2] + qk2[(size_t)src * 32 + r * 2 + 1];
    l = l > 0.f ? l : 0.2f * l;
    e2[e] = __expf(l);
}

// ---------------- layer2 GEMM: full graph, src-sorted, XCD-swizzled ----------------
__global__ __launch_bounds__(256, 2)
void l2_gemm_kernel(const unsigned short* __restrict__ hhi, const unsigned short* __restrict__ hlo,
                    const unsigned short* __restrict__ W2Thi, const unsigned short* __restrict__ W2Tlo,
                    const int* __restrict__ ei, const int* __restrict__ border2,
                    const int* __restrict__ tile_b2, const int* __restrict__ tile_s2,
                    const int* __restrict__ offs2, unsigned* __restrict__ msgu2) {
    int t = (blockIdx.x & 7) * (MAXT2 / 8) + (blockIdx.x >> 3);    // XCD-contiguous
    int tb = tile_b2[t];
    if (tb < 0) return;
    int r = tb & (NR - 1);
    int start = tile_s2[t];
    int cnt = offs2[tb + 1] - start; if (cnt > TILE) cnt = TILE;
    __shared__ __align__(16) unsigned short Ah[64 * 128];
    __shared__ __align__(16) unsigned short Al[64 * 128];
    __shared__ int srcS[TILE];
    int tid = threadIdx.x;
    if (tid < TILE) {
        int sv = 0;
        if (tid < cnt) { int e = border2[start + tid]; sv = ei[e]; }
        srcS[tid] = sv;
    }
    __syncthreads();
    int w = tid >> 6, lane = tid & 63;
    int l15 = lane & 15, l4 = lane >> 4;
    const unsigned short* Bh = W2Thi + ((size_t)r * DOUT + w * 32 + l15) * DH + l4 * 8;
    const unsigned short* Bl = W2Tlo + ((size_t)r * DOUT + w * 32 + l15) * DH + l4 * 8;
    f32x4 acc[4][2];
    #pragma unroll
    for (int m = 0; m < 4; ++m) { acc[m][0] = (f32x4){0.f,0.f,0.f,0.f}; acc[m][1] = (f32x4){0.f,0.f,0.f,0.f}; }
    for (int kc = 0; kc < 4; ++kc) {
        if (kc) __syncthreads();
        {
            int row = tid >> 2, seg = tid & 3;
            const uint4* ph = (const uint4*)(hhi + (size_t)srcS[row] * DH + kc * 128 + seg * 32);
            const uint4* pl = (const uint4*)(hlo + (size_t)srcS[row] * DH + kc * 128 + seg * 32);
            unsigned rb = row * 256, sw = (row & 7) << 4;
            #pragma unroll
            for (int i = 0; i < 4; ++i) {
                unsigned off = (rb + seg * 64 + i * 16) ^ sw;
                *(uint4*)((char*)Ah + off) = ph[i];
                *(uint4*)((char*)Al + off) = pl[i];
            }
        }
        __syncthreads();
        bf16x8 ah[4][4], al[4][4];
        #pragma unroll
        for (int m = 0; m < 4; ++m) {
            int row = m * 16 + l15;
            unsigned rb = row * 256, sw = (row & 7) << 4;
            #pragma unroll
            for (int k = 0; k < 4; ++k) {
                unsigned off = (rb + k * 64 + l4 * 16) ^ sw;
                ah[m][k] = *(const bf16x8*)((const char*)Ah + off);
                al[m][k] = *(const bf16x8*)((const char*)Al + off);
            }
        }
        #pragma unroll
        for (int n = 0; n < 2; ++n) {
            #pragma unroll
            for (int k = 0; k < 4; ++k) {
                bf16x8 bh = *(const bf16x8*)(Bh + (size_t)n * 16 * DH + kc * 128 + k * 32);
                bf16x8 bl = *(const bf16x8*)(Bl + (size_t)n * 16 * DH + kc * 128 + k * 32);
                #pragma unroll
                for (int m = 0; m < 4; ++m) {
                    acc[m][n] = __builtin_amdgcn_mfma_f32_16x16x32_bf16(ah[m][k], bh, acc[m][n], 0, 0, 0);
                    acc[m][n] = __builtin_amdgcn_mfma_f32_16x16x32_bf16(ah[m][k], bl, acc[m][n], 0, 0, 0);
                    acc[m][n] = __builtin_amdgcn_mfma_f32_16x16x32_bf16(al[m][k], bh, acc[m][n], 0, 0, 0);
                }
            }
        }
    }
    unsigned* mb = msgu2 + (size_t)start * 64 + w * 16 + l15;
    #pragma unroll
    for (int m = 0; m < 4; ++m) {
        int row0 = m * 16 + l4 * 4;
        #pragma unroll
        for (int rg = 0; rg < 4; ++rg) {
            int row = row0 + rg;
            if (row < cnt) {
                mb[(size_t)row * 64] = packbf(acc[m][0][rg], acc[m][1][rg]);
            }
        }
    }
}

// ---------------- layer2 agg: full graph, permutation read ----------------
__global__ void l2_agg_kernel(const unsigned* __restrict__ msgu2, const float* __restrict__ e2,
                              const int* __restrict__ dlist, const int* __restrict__ dedge,
                              const int* __restrict__ doffs, float* __restrict__ zacc) {
    int tid = threadIdx.x;
    int d = blockIdx.x * 4 + (tid >> 6);
    if (d >= NN) return;
    int slot = tid & 63;
    int lo_ = doffs[d], hi_ = doffs[d + 1];
    float a0 = 0.f, a1 = 0.f, se = 0.f;
    for (int p = lo_; p < hi_; ++p) {
        float wgt = e2[dedge[p]];
        se += wgt;
        unsigned v = msgu2[(size_t)dlist[p] * 64 + slot];
        a0 += wgt * bf2f((unsigned short)(v & 0xffff));
        a1 += wgt * bf2f((unsigned short)(v >> 16));
    }
    float inv = 1.f / (se + 1e-16f);
    int w = slot >> 4, l15 = slot & 15;
    int c0l = w * 32 + l15;
    zacc[(size_t)d * DOUT + c0l] = a0 * inv;
    zacc[(size_t)d * DOUT + c0l + 16] = a1 * inv;
}

// ---------------- link-prediction decoder (MFMA, split bf16) ----------------
__global__ __launch_bounds__(256, 2)
void decode_kernel(const float* __restrict__ z, const int* __restrict__ tgt,
                   const unsigned short* __restrict__ Lhi, const unsigned short* __restrict__ Llo,
                   const float* __restrict__ lb1, const float* __restrict__ lw2,
                   const float* __restrict__ lb2, float* __restrict__ out) {
    __shared__ __align__(16) unsigned short Ah[64 * 256];
    __shared__ __align__(16) unsigned short Al[64 * 256];
    __shared__ float red[TILE][5];
    int t0 = blockIdx.x * TILE;
    int tid = threadIdx.x;
    int cnt = NT - t0; if (cnt > TILE) cnt = TILE;
    {
        int row = tid >> 2, seg = tid & 3;
        int node = 0;
        bool live = (row < cnt);
        if (live) node = tgt[(seg >> 1) * NT + t0 + row];
        const float4* pz = (const float4*)(z + (size_t)node * DOUT + (seg & 1) * 64);
        unsigned rb = row * 512, sb = (seg >> 1) * 256 + (seg & 1) * 128;
        unsigned sw = (row & 7) << 4;
        #pragma unroll
        for (int g = 0; g < 8; ++g) {
            float4 a = live ? pz[g * 2] : (float4){0,0,0,0};
            float4 bq = live ? pz[g * 2 + 1] : (float4){0,0,0,0};
            unsigned short h0 = f2bf(a.x), h1 = f2bf(a.y), h2 = f2bf(a.z), h3 = f2bf(a.w);
            unsigned short h4 = f2bf(bq.x), h5 = f2bf(bq.y), h6 = f2bf(bq.z), h7 = f2bf(bq.w);
            uint4 uh, ul;
            uh.x = (unsigned)h0 | ((unsigned)h1 << 16);
            uh.y = (unsigned)h2 | ((unsigned)h3 << 16);
            uh.z = (unsigned)h4 | ((unsigned)h5 << 16);
            uh.w = (unsigned)h6 | ((unsigned)h7 << 16);
            ul.x = (unsigned)f2bf(a.x - bf2f(h0)) | ((unsigned)f2bf(a.y - bf2f(h1)) << 16);
            ul.y = (unsigned)f2bf(a.z - bf2f(h2)) | ((unsigned)f2bf(a.w - bf2f(h3)) << 16);
            ul.z = (unsigned)f2bf(bq.x - bf2f(h4)) | ((unsigned)f2bf(bq.y - bf2f(h5)) << 16);
            ul.w = (unsigned)f2bf(bq.z - bf2f(h6)) | ((unsigned)f2bf(bq.w - bf2f(h7)) << 16);
            unsigned off = (rb + sb + g * 16) ^ sw;
            *(uint4*)((char*)Ah + off) = uh;
            *(uint4*)((char*)Al + off) = ul;
        }
    }
    __syncthreads();
    int w = tid >> 6, lane = tid & 63;
    int l15 = lane & 15, l4 = lane >> 4;
    const unsigned short* Bh = Lhi + (size_t)(w * 32 + l15) * 256 + l4 * 8;
    const unsigned short* Bl = Llo + (size_t)(w * 32 + l15) * 256 + l4 * 8;
    f32x4 acc[4][2];
    #pragma unroll
    for (int m = 0; m < 4; ++m) { acc[m][0] = (f32x4){0.f,0.f,0.f,0.f}; acc[m][1] = (f32x4){0.f,0.f,0.f,0.f}; }
    #pragma unroll
    for (int k = 0; k < 8; ++k) {
        bf16x8 ah[4], al[4];
        #pragma unroll
        for (int m = 0; m < 4; ++m) {
            int row = m * 16 + l15;
            unsigned off = ((unsigned)row * 512 + k * 64 + l4 * 16) ^ ((unsigned)(row & 7) << 4);
            ah[m] = *(const bf16x8*)((const char*)Ah + off);
            al[m] = *(const bf16x8*)((const char*)Al + off);
        }
        #pragma unroll
        for (int n = 0; n < 2; ++n) {
            bf16x8 bh = *(const bf16x8*)(Bh + (size_t)n * 16 * 256 + k * 32);
            bf16x8 bl = *(const bf16x8*)(Bl + (size_t)n * 16 * 256 + k * 32);
            #pragma unroll
            for (int m = 0; m < 4; ++m) {
                acc[m][n] = __builtin_amdgcn_mfma_f32_16x16x32_bf16(ah[m], bh, acc[m][n], 0, 0, 0);
                acc[m][n] = __builtin_amdgcn_mfma_f32_16x16x32_bf16(ah[m], bl, acc[m][n], 0, 0, 0);
                acc[m][n] = __builtin_amdgcn_mfma_f32_16x16x32_bf16(al[m], bh, acc[m][n], 0, 0, 0);
            }
        }
    }
    int col0 = w * 32 + l15;
    float lb_0 = lb1[col0], lb_1 = lb1[col0 + 16];
    float lwa = lw2[col0], lwb = lw2[col0 + 16];
    #pragma unroll
    for (int m = 0; m < 4; ++m) {
        #pragma unroll
        for (int rg = 0; rg < 4; ++rg) {
            float h0 = acc[m][0][rg] + lb_0; h0 = h0 > 0.f ? h0 : 0.f;
            float h1 = acc[m][1][rg] + lb_1; h1 = h1 > 0.f ? h1 : 0.f;
            float s = h0 * lwa + h1 * lwb;
            s += __shfl_xor(s, 1); s += __shfl_xor(s, 2);
            s += __shfl_xor(s, 4); s += __shfl_xor(s, 8);
            if (l15 == 0) red[m * 16 + l4 * 4 + rg][w] = s;
        }
    }
    __syncthreads();
    if (tid < cnt) out[t0 + tid] = red[tid][0] + red[tid][1] + red[tid][2] + red[tid][3] + lb2[0];
}

extern "C" void kernel_launch(void* const* d_in, const int* in_sizes, int n_in,
                              void* d_out, int out_size, void* d_ws, size_t ws_size,
                              hipStream_t stream) {
    const float* x   = (const float*)d_in[0];
    const int*   ei  = (const int*)d_in[1];
    const int*   et  = (const int*)d_in[2];
    const int*   tgt = (const int*)d_in[3];
    const float* W1  = (const float*)d_in[4];
    const float* aq1 = (const float*)d_in[5];
    const float* ak1 = (const float*)d_in[6];
    const float* W2  = (const float*)d_in[7];
    const float* aq2 = (const float*)d_in[8];
    const float* ak2 = (const float*)d_in[9];
    const float* lw1 = (const float*)d_in[10];
    const float* lb1 = (const float*)d_in[11];
    const float* lw2 = (const float*)d_in[12];
    const float* lb2 = (const float*)d_in[13];
    float* out = (float*)d_out;
    (void)in_sizes; (void)n_in; (void)out_size; (void)ws_size;

    char* ws = (char*)d_ws;
    size_t off = 0;
    auto alloc = [&](size_t bytes) -> void* {
        void* p = ws + off;
        off += (bytes + 255) & ~(size_t)255;
        return p;
    };
    // zero-init block: histograms only
    int* hist1 = (int*)alloc(NKEY1 * sizeof(int));
    int* hist2 = (int*)alloc(NKEY2 * sizeof(int));
    int* cnt_d = (int*)alloc((size_t)NN * sizeof(int));
    size_t zero_bytes = off;
    // no-init scratch
    int*   offs1    = (int*)alloc((NKEY1 + 1) * sizeof(int));
    int*   cursor1  = (int*)alloc(NKEY1 * sizeof(int));
    int*   offs2    = (int*)alloc((NKEY2 + 1) * sizeof(int));
    int*   cursor2  = (int*)alloc(NKEY2 * sizeof(int));
    int*   boffs    = (int*)alloc((NBUCKET + 1) * sizeof(int));
    int*   cts      = (int*)alloc((CHUNKS + 1) * sizeof(int));
    int*   doffs    = (int*)alloc((size_t)(NN + 1) * sizeof(int));
    int*   cursor_d = (int*)alloc((size_t)NN * sizeof(int));
    int*   border1  = (int*)alloc((size_t)NE * sizeof(int));
    int*   border2  = (int*)alloc((size_t)NE * sizeof(int));
    int*   dlist    = (int*)alloc((size_t)NE * sizeof(int));
    int*   dedge    = (int*)alloc((size_t)NE * sizeof(int));
    int*   tile_b   = (int*)alloc((size_t)NTILESMAX * sizeof(int));
    int*   tile_s   = (int*)alloc((size_t)NTILESMAX * sizeof(int));
    int*   tile_b2  = (int*)alloc((size_t)MAXT2 * sizeof(int));
    int*   tile_s2  = (int*)alloc((size_t)MAXT2 * sizeof(int));
    float* alpha2   = (float*)alloc((size_t)512 * 32 * 4);
    float* qk2v     = (float*)alloc((size_t)NN * 32 * 4);
    float* e2       = (float*)alloc((size_t)NE * 4);
    float* zacc     = (float*)alloc((size_t)NN * DOUT * 4);
    unsigned short* xhi   = (unsigned short*)alloc((size_t)NN * DIN * 2);
    unsigned short* xlo   = (unsigned short*)alloc((size_t)NN * DIN * 2);
    unsigned short* hhi   = (unsigned short*)alloc((size_t)NN * DH * 2);
    unsigned short* hlo   = (unsigned short*)alloc((size_t)NN * DH * 2);
    unsigned short* W1Thi = (unsigned short*)alloc((size_t)NR * DH * DIN * 2);
    unsigned short* W1Tlo = (unsigned short*)alloc((size_t)NR * DH * DIN * 2);
    unsigned short* W2Thi = (unsigned short*)alloc((size_t)NR * DOUT * DH * 2);
    unsigned short* W2Tlo = (unsigned short*)alloc((size_t)NR * DOUT * DH * 2);
    unsigned short* Lhi   = (unsigned short*)alloc((size_t)128 * 256 * 2);
    unsigned short* Llo   = (unsigned short*)alloc((size_t)128 * 256 * 2);
    // msg region: 82 MB. l1 uses first 47.2 MB per chunk; l2 uses all of it.
    // alpha1/qk1/e1 alias the tail (dead before l2_gemm writes the full region).
    char* msgr = (char*)alloc((size_t)NE * 64 * 4);                 // 81,920,000 B
    unsigned* msgu = (unsigned*)msgr;
    float* alpha1 = (float*)(msgr + (size_t)MSGROWS * 256 * 4);     // +47,185,920
    float* qk1    = alpha1 + 128 * 256;                             // +131,072 B
    float* e1     = qk1 + (size_t)NN * 256;                         // +20,480,000 B; ends at 78.0 MB < 81.9 MB

    hipMemsetAsync(ws, 0, zero_bytes, stream);
    alpha1_kernel<<<DIN, 256, 0, stream>>>(W1, aq1, ak1, alpha1);
    alpha2_kernel<<<(DH * 32 + 255) / 256, 256, 0, stream>>>(W2, aq2, ak2, alpha2);
    split_x_kernel<<<(NN * DIN / 4 + 255) / 256, 256, 0, stream>>>(x, xhi, xlo);
    splitW1T_kernel<<<NR * 8, 256, 0, stream>>>(W1, W1Thi, W1Tlo);
    splitW2T_kernel<<<NR * 2, 256, 0, stream>>>(W2, W2Thi, W2Tlo);
    splitLw1_kernel<<<(256 * 128 + 255) / 256, 256, 0, stream>>>(lw1, Lhi, Llo);
    hist_all_kernel<<<(NE + 255) / 256, 256, 0, stream>>>(ei, et, hist1, hist2, cnt_d);
    scan1_kernel<<<1, 1024, 0, stream>>>(hist1, offs1, cursor1, boffs, cts);
    scan2_kernel<<<1, NKEY2, 0, stream>>>(hist2, offs2, cursor2);
    tilemap_kernel<<<(NTILESMAX + 255) / 256, 256, 0, stream>>>(boffs, tile_b, tile_s);
    tilemap2_kernel<<<(MAXT2 + 255) / 256, 256, 0, stream>>>(offs2, tile_b2, tile_s2);
    place1_kernel<<<(NE + 255) / 256, 256, 0, stream>>>(ei, et, cursor1, border1);
    place2_kernel<<<(NE + 255) / 256, 256, 0, stream>>>(ei, et, cursor2, border2);
    scan_dst_kernel<<<1, 1024, 0, stream>>>(cnt_d, doffs, cursor_d);
    place_dst_kernel<<<(NE + 255) / 256, 256, 0, stream>>>(border1, ei, cursor_d, dlist, dedge);
    qk1_kernel<<<(NN + TILE - 1) / TILE, 256, 0, stream>>>(x, alpha1, qk1);
    elogit1_kernel<<<(NE + 255) / 256, 256, 0, stream>>>(ei, et, qk1, e1);
    for (int c = 0; c < CHUNKS; ++c) {
        l1_gemm_kernel<<<MAXTPC, 256, 0, stream>>>(xhi, xlo, W1Thi, W1Tlo, ei, border1,
                                                   tile_b, tile_s, boffs, cts, c, msgu);
        l1_agg_kernel<<<CHD, 256, 0, stream>>>(msgu, e1, dlist, dedge, doffs, boffs, c,
                                               hhi, hlo, alpha2, qk2v);
    }
    // rebuild dst lists against border2 order (reuses dlist/dedge; l1_agg is done)
    scan_dst_kernel<<<1, 1024, 0, stream>>>(cnt_d, doffs, cursor_d);
    place_dst_kernel<<<(NE + 255) / 256, 256, 0, stream>>>(border2, ei, cursor_d, dlist, dedge);
    elogit2_kernel<<<(NE + 255) / 256, 256, 0, stream>>>(ei, et, qk2v, e2);
    l2_gemm_kernel<<<MAXT2, 256, 0, stream>>>(hhi, hlo, W2Thi, W2Tlo, ei, border2,
                                              tile_b2, tile_s2, offs2, msgu);
    l2_agg_kernel<<<(NN + 3) / 4, 256, 0, stream>>>(msgu, e2, dlist, dedge, doffs, zacc);
    decode_kernel<<<(NT + TILE - 1) / TILE, 256, 0, stream>>>(zacc, tgt, Lhi, Llo,
                                                              lb1, lw2, lb2, out);
}

// Round 8
// 1084.351 us; speedup vs baseline: 1.1240x; 1.1240x over previous
//
#include <hip/hip_runtime.h>
#include <cstdint>
#include <cstddef>

#define NN     20000
#define NE     320000
#define NR     16
#define DIN    128
#define DH     512
#define DOUT   128
#define NT     50000
#define TILE   64
#define CHUNKS 8
#define CHD    2500
#define NBUCKET (CHUNKS * NR)          // 128
#define MSGROWS 46080                  // max edges per chunk
#define MAXTPC  768                    // l1 grid per chunk (8*96)
#define NTILESMAX (NE / TILE + NBUCKET)
#define MT2    ((NN + TILE - 1) / TILE)   // 313 m-tiles for dense Y2
#define YGRID  1256                       // 313*4 padded to %8==0

typedef __attribute__((ext_vector_type(8))) short bf16x8;
typedef __attribute__((ext_vector_type(4))) float f32x4;

__device__ __forceinline__ unsigned short f2bf(float x) {
    unsigned int b = __float_as_uint(x);
    b = b + 0x7fffu + ((b >> 16) & 1u);
    return (unsigned short)(b >> 16);
}
__device__ __forceinline__ float bf2f(unsigned short u) {
    return __uint_as_float(((unsigned int)u) << 16);
}
__device__ __forceinline__ unsigned packbf(float lo, float hi) {
    return (unsigned)f2bf(lo) | ((unsigned)f2bf(hi) << 16);
}

// ---------------- fold attention vectors into weights ----------------
__global__ void alpha1_kernel(const float* __restrict__ W1, const float* __restrict__ aq1,
                              const float* __restrict__ ak1, float* __restrict__ alpha1) {
    int i = blockIdx.x;
    int c = threadIdx.x;
    int r = c >> 4, s = (c >> 3) & 1, h = c & 7;
    const float* att = (s == 0 ? aq1 : ak1) + (r * 8 + h) * 64;
    const float* w = W1 + ((size_t)(r * DIN + i)) * DH + h * 64;
    float acc = 0.f;
    #pragma unroll 8
    for (int o = 0; o < 64; ++o) acc += w[o] * att[o];
    alpha1[i * 256 + c] = acc;
}

__global__ void alpha2_kernel(const float* __restrict__ W2, const float* __restrict__ aq2,
                              const float* __restrict__ ak2, float* __restrict__ alpha2) {
    int g = blockIdx.x * blockDim.x + threadIdx.x;
    if (g >= DH * 32) return;
    int i = g >> 5, c = g & 31;
    int r = c >> 1, s = c & 1;
    const float* att = (s == 0 ? aq2 : ak2) + r * DOUT;
    const float* w = W2 + ((size_t)(r * DH + i)) * DOUT;
    float acc = 0.f;
    #pragma unroll 8
    for (int o = 0; o < DOUT; ++o) acc += w[o] * att[o];
    alpha2[i * 32 + c] = acc;
}

// ---------------- bf16 hi/lo precompute ----------------
__global__ void split_x_kernel(const float* __restrict__ x, unsigned short* __restrict__ xhi,
                               unsigned short* __restrict__ xlo) {
    int g = blockIdx.x * 256 + threadIdx.x;
    if (g >= NN * DIN / 4) return;
    float4 v = ((const float4*)x)[g];
    ushort4 h, l;
    h.x = f2bf(v.x); l.x = f2bf(v.x - bf2f(h.x));
    h.y = f2bf(v.y); l.y = f2bf(v.y - bf2f(h.y));
    h.z = f2bf(v.z); l.z = f2bf(v.z - bf2f(h.z));
    h.w = f2bf(v.w); l.w = f2bf(v.w - bf2f(h.w));
    ((ushort4*)xhi)[g] = h;
    ((ushort4*)xlo)[g] = l;
}

__global__ void splitW1T_kernel(const float* __restrict__ W1, unsigned short* __restrict__ Whi,
                                unsigned short* __restrict__ Wlo) {
    __shared__ float T[128 * 65];
    int r = blockIdx.x >> 3;
    int ob = blockIdx.x & 7;
    int tid = threadIdx.x;
    for (int idx = tid; idx < 128 * 64; idx += 256) {
        int i = idx >> 6, o = idx & 63;
        T[i * 65 + o] = W1[((size_t)(r * DIN + i)) * DH + ob * 64 + o];
    }
    __syncthreads();
    for (int idx = tid; idx < 64 * 128; idx += 256) {
        int o = idx >> 7, i = idx & 127;
        float v = T[i * 65 + o];
        unsigned short h = f2bf(v);
        size_t off = ((size_t)r * DH + ob * 64 + o) * DIN + i;
        Whi[off] = h;
        Wlo[off] = f2bf(v - bf2f(h));
    }
}

__global__ void splitW2T_kernel(const float* __restrict__ W2, unsigned short* __restrict__ Whi,
                                unsigned short* __restrict__ Wlo) {
    __shared__ float T[128 * 65];
    int r = blockIdx.x >> 1;
    int ob = blockIdx.x & 1;
    int tid = threadIdx.x;
    for (int kc = 0; kc < 4; ++kc) {
        if (kc) __syncthreads();
        for (int idx = tid; idx < 128 * 64; idx += 256) {
            int k = idx >> 6, o = idx & 63;
            T[k * 65 + o] = W2[((size_t)(r * DH + kc * 128 + k)) * DOUT + ob * 64 + o];
        }
        __syncthreads();
        for (int idx = tid; idx < 64 * 128; idx += 256) {
            int o = idx >> 7, k = idx & 127;
            float v = T[k * 65 + o];
            unsigned short h = f2bf(v);
            size_t off = ((size_t)r * DOUT + ob * 64 + o) * DH + kc * 128 + k;
            Whi[off] = h;
            Wlo[off] = f2bf(v - bf2f(h));
        }
    }
}

__global__ void splitLw1_kernel(const float* __restrict__ lw1, unsigned short* __restrict__ Lhi,
                                unsigned short* __restrict__ Llo) {
    int g = blockIdx.x * 256 + threadIdx.x;
    if (g >= 256 * 128) return;
    int o = g >> 8, k = g & 255;
    float v = lw1[k * 128 + o];
    unsigned short h = f2bf(v);
    Lhi[(size_t)o * 256 + k] = h;
    Llo[(size_t)o * 256 + k] = f2bf(v - bf2f(h));
}

// ---------------- sorts (round-6 cheap version) ----------------
__global__ void hist_kernel(const int* __restrict__ ei, const int* __restrict__ et,
                            int* __restrict__ cnt, int* __restrict__ cnt_d) {
    __shared__ int bins[NBUCKET];
    int t = threadIdx.x;
    if (t < NBUCKET) bins[t] = 0;
    __syncthreads();
    int e = blockIdx.x * 256 + t;
    if (e < NE) {
        int d = ei[NE + e];
        int key = (d / CHD) * NR + et[e];
        atomicAdd(&bins[key], 1);
        atomicAdd(&cnt_d[d], 1);
    }
    __syncthreads();
    if (t < NBUCKET && bins[t]) atomicAdd(&cnt[t], bins[t]);
}

__global__ void scan_bkt_kernel(const int* __restrict__ cnt, int* __restrict__ boffs,
                                int* __restrict__ cursor, int* __restrict__ cts) {
    if (threadIdx.x != 0) return;
    int acc = 0, tiles = 0;
    for (int b = 0; b < NBUCKET; ++b) {
        if ((b & (NR - 1)) == 0) cts[b >> 4] = tiles;
        boffs[b] = acc; cursor[b] = acc;
        int cn = cnt[b];
        tiles += (cn + TILE - 1) / TILE;
        acc += cn;
    }
    boffs[NBUCKET] = acc; cts[CHUNKS] = tiles;
}

__global__ void tilemap_kernel(const int* __restrict__ boffs, int* __restrict__ tile_b,
                               int* __restrict__ tile_s) {
    __shared__ int bo[NBUCKET + 1];
    int tid = threadIdx.x;
    if (tid <= NBUCKET) bo[tid] = boffs[tid];
    __syncthreads();
    int t = blockIdx.x * 256 + tid;
    if (t >= NTILESMAX) return;
    int acc = 0, bb = -1, ss = 0;
    for (int b = 0; b < NBUCKET; ++b) {
        int cn = bo[b + 1] - bo[b];
        int nt = (cn + TILE - 1) / TILE;
        if (t >= acc && t < acc + nt) { bb = b; ss = bo[b] + (t - acc) * TILE; }
        acc += nt;
    }
    tile_b[t] = bb; tile_s[t] = ss;
}

__global__ void bucket_place_kernel(const int* __restrict__ ei, const int* __restrict__ et,
                                    int* __restrict__ cursor, int* __restrict__ border) {
    __shared__ int binc[NBUCKET], base_[NBUCKET], rank_[NBUCKET];
    int t = threadIdx.x;
    if (t < NBUCKET) { binc[t] = 0; rank_[t] = 0; }
    __syncthreads();
    int e = blockIdx.x * 256 + t;
    int key = -1;
    if (e < NE) { key = (ei[NE + e] / CHD) * NR + et[e]; atomicAdd(&binc[key], 1); }
    __syncthreads();
    if (t < NBUCKET && binc[t]) base_[t] = atomicAdd(&cursor[t], binc[t]);
    __syncthreads();
    if (key >= 0) border[base_[key] + atomicAdd(&rank_[key], 1)] = e;
}

__global__ void scan_dst_kernel(const int* __restrict__ cnt_d, int* __restrict__ doffs,
                                int* __restrict__ cursor_d) {
    __shared__ int part[1024];
    int t = threadIdx.x;
    int base = t * 20;
    int s = 0;
    for (int i = 0; i < 20 && base + i < NN; ++i) s += cnt_d[base + i];
    part[t] = s;
    __syncthreads();
    for (int off = 1; off < 1024; off <<= 1) {
        int v = (t >= off) ? part[t - off] : 0;
        __syncthreads();
        part[t] += v;
        __syncthreads();
    }
    int run = part[t] - s;
    for (int i = 0; i < 20 && base + i < NN; ++i) {
        doffs[base + i] = run; cursor_d[base + i] = run;
        run += cnt_d[base + i];
    }
    if (t == 1023) doffs[NN] = part[1023];
}

// also emits dsr = src*NR + r (row index into dense Y2 table)
__global__ void place_dst_kernel(const int* __restrict__ border, const int* __restrict__ ei,
                                 const int* __restrict__ et, int* __restrict__ cursor_d,
                                 int* __restrict__ dlist, int* __restrict__ dedge,
                                 int* __restrict__ dsr) {
    int pos = blockIdx.x * 256 + threadIdx.x;
    if (pos >= NE) return;
    int e = border[pos];
    int d = ei[NE + e];
    int idx = atomicAdd(&cursor_d[d], 1);
    dlist[idx] = pos;
    dedge[idx] = e;
    dsr[idx] = ei[e] * NR + et[e];
}

// ---------------- qk1 = x @ alpha1 ----------------
__global__ void qk1_kernel(const float* __restrict__ x, const float* __restrict__ alpha1,
                           float* __restrict__ qk1) {
    __shared__ float Xt[TILE][DIN + 1];
    int n0 = blockIdx.x * TILE;
    int tid = threadIdx.x;
    for (int idx = tid; idx < TILE * DIN; idx += 256) {
        int row = idx >> 7, i = idx & 127;
        int n = n0 + row;
        Xt[row][i] = (n < NN) ? x[(size_t)n * DIN + i] : 0.f;
    }
    __syncthreads();
    int to = tid >> 4, te = tid & 15;
    for (int c = 0; c < 2; ++c) {
        float acc[4][8] = {};
        const float* Wp = alpha1 + c * 128 + to * 8;
        for (int i = 0; i < DIN; ++i) {
            float4 w0 = *(const float4*)(Wp + (size_t)i * 256);
            float4 w1 = *(const float4*)(Wp + (size_t)i * 256 + 4);
            float w[8] = {w0.x, w0.y, w0.z, w0.w, w1.x, w1.y, w1.z, w1.w};
            #pragma unroll
            for (int a = 0; a < 4; ++a) {
                float xv = Xt[te * 4 + a][i];
                #pragma unroll
                for (int b = 0; b < 8; ++b) acc[a][b] += xv * w[b];
            }
        }
        #pragma unroll
        for (int a = 0; a < 4; ++a) {
            int n = n0 + te * 4 + a;
            if (n < NN) {
                float* op = qk1 + (size_t)n * 256 + c * 128 + to * 8;
                #pragma unroll
                for (int b = 0; b < 8; ++b) op[b] = acc[a][b];
            }
        }
    }
}

__global__ void elogit1_kernel(const int* __restrict__ ei, const int* __restrict__ et,
                               const float* __restrict__ qk1, float* __restrict__ e1) {
    int e = blockIdx.x * blockDim.x + threadIdx.x;
    if (e >= NE) return;
    int src = ei[e], dst = ei[NE + e], r = et[e];
    const float* qp = qk1 + (size_t)dst * 256 + r * 16;
    const float* kp = qk1 + (size_t)src * 256 + r * 16 + 8;
    float* ep = e1 + (size_t)e * 8;
    #pragma unroll
    for (int h = 0; h < 8; ++h) {
        float l = qp[h] + kp[h];
        l = l > 0.f ? l : 0.2f * l;
        ep[h] = __expf(l);
    }
}

// ---------------- layer1 GEMM (per-edge, MFMA split bf16) ----------------
__global__ __launch_bounds__(256, 2)
void l1_gemm_kernel(const unsigned short* __restrict__ xhi, const unsigned short* __restrict__ xlo,
                    const unsigned short* __restrict__ W1Thi, const unsigned short* __restrict__ W1Tlo,
                    const int* __restrict__ ei, const int* __restrict__ border,
                    const int* __restrict__ tile_b, const int* __restrict__ tile_s,
                    const int* __restrict__ boffs, const int* __restrict__ cts,
                    int c, unsigned* __restrict__ msgu) {
    int wg = (blockIdx.x & 7) * (MAXTPC / 8) + (blockIdx.x >> 3);   // XCD-contiguous
    int t = cts[c] + wg;
    if (t >= cts[c + 1]) return;
    int b = tile_b[t];
    int r = b & (NR - 1);
    int start = tile_s[t];
    int cstart = boffs[c * NR];
    int cnt = boffs[b + 1] - start; if (cnt > TILE) cnt = TILE;
    __shared__ __align__(16) unsigned short Ah[64 * 128];
    __shared__ __align__(16) unsigned short Al[64 * 128];
    __shared__ int srcS[TILE];
    int tid = threadIdx.x;
    if (tid < TILE) {
        int sv = 0;
        if (tid < cnt) { int e = border[start + tid]; sv = ei[e]; }
        srcS[tid] = sv;
    }
    __syncthreads();
    {
        int row = tid >> 2, seg = tid & 3;
        const uint4* ph = (const uint4*)(xhi + (size_t)srcS[row] * DIN + seg * 32);
        const uint4* pl = (const uint4*)(xlo + (size_t)srcS[row] * DIN + seg * 32);
        unsigned rb = row * 256, sw = (row & 7) << 4;
        #pragma unroll
        for (int i = 0; i < 4; ++i) {
            unsigned off = (rb + seg * 64 + i * 16) ^ sw;
            *(uint4*)((char*)Ah + off) = ph[i];
            *(uint4*)((char*)Al + off) = pl[i];
        }
    }
    __syncthreads();
    int w = tid >> 6, lane = tid & 63;
    int l15 = lane & 15, l4 = lane >> 4;
    const unsigned short* Bh = W1Thi + ((size_t)r * DH + w * 128 + l15) * DIN + l4 * 8;
    const unsigned short* Bl = W1Tlo + ((size_t)r * DH + w * 128 + l15) * DIN + l4 * 8;
    f32x4 acc[4][8];
    #pragma unroll
    for (int m = 0; m < 4; ++m)
        #pragma unroll
        for (int n = 0; n < 8; ++n) acc[m][n] = (f32x4){0.f, 0.f, 0.f, 0.f};
    #pragma unroll
    for (int mg = 0; mg < 2; ++mg) {
        bf16x8 ah[2][4], al[2][4];
        #pragma unroll
        for (int mm = 0; mm < 2; ++mm) {
            int row = (mg * 2 + mm) * 16 + l15;
            unsigned rb = row * 256, sw = (row & 7) << 4;
            #pragma unroll
            for (int k = 0; k < 4; ++k) {
                unsigned off = (rb + k * 64 + l4 * 16) ^ sw;
                ah[mm][k] = *(const bf16x8*)((const char*)Ah + off);
                al[mm][k] = *(const bf16x8*)((const char*)Al + off);
            }
        }
        #pragma unroll
        for (int n = 0; n < 8; ++n) {
            #pragma unroll
            for (int k = 0; k < 4; ++k) {
                bf16x8 bh = *(const bf16x8*)(Bh + (size_t)n * 16 * DIN + k * 32);
                bf16x8 bl = *(const bf16x8*)(Bl + (size_t)n * 16 * DIN + k * 32);
                #pragma unroll
                for (int mm = 0; mm < 2; ++mm) {
                    int m = mg * 2 + mm;
                    acc[m][n] = __builtin_amdgcn_mfma_f32_16x16x32_bf16(ah[mm][k], bh, acc[m][n], 0, 0, 0);
                    acc[m][n] = __builtin_amdgcn_mfma_f32_16x16x32_bf16(ah[mm][k], bl, acc[m][n], 0, 0, 0);
                    acc[m][n] = __builtin_amdgcn_mfma_f32_16x16x32_bf16(al[mm][k], bh, acc[m][n], 0, 0, 0);
                }
            }
        }
    }
    unsigned* mb = msgu + (size_t)(start - cstart) * 256 + w * 64 + l15;
    #pragma unroll
    for (int m = 0; m < 4; ++m) {
        int row0 = m * 16 + l4 * 4;
        #pragma unroll
        for (int rg = 0; rg < 4; ++rg) {
            int row = row0 + rg;
            if (row < cnt) {
                unsigned* mp = mb + (size_t)row * 256;
                #pragma unroll
                for (int q = 0; q < 4; ++q) {
                    int nq = ((q >> 1) << 2) | (q & 1);
                    mp[q * 16] = packbf(acc[m][nq][rg], acc[m][nq + 2][rg]);
                }
            }
        }
    }
}

// ---------------- layer1 agg (fused qk2) ----------------
__global__ void l1_agg_kernel(const unsigned* __restrict__ msgu, const float* __restrict__ e1,
                              const int* __restrict__ dlist, const int* __restrict__ dedge,
                              const int* __restrict__ doffs, const int* __restrict__ boffs,
                              int c, unsigned short* __restrict__ hhi, unsigned short* __restrict__ hlo,
                              const float* __restrict__ alpha2, float* __restrict__ qk2v) {
    __shared__ float hrow[DH];
    __shared__ float red[32][9];
    int tid = threadIdx.x;
    int d = c * CHD + blockIdx.x;
    int lo_ = doffs[d], hi_ = doffs[d + 1];
    int cstart = boffs[c * NR];
    int head = tid >> 5;
    float a0 = 0.f, a1 = 0.f, se = 0.f;
    for (int p = lo_; p < hi_; ++p) {
        int pos = dlist[p];
        float wgt = e1[(size_t)dedge[p] * 8 + head];
        se += wgt;
        unsigned v = msgu[(size_t)(pos - cstart) * 256 + tid];
        a0 += wgt * bf2f((unsigned short)(v & 0xffff));
        a1 += wgt * bf2f((unsigned short)(v >> 16));
    }
    float inv = 1.f / (se + 1e-16f);
    a0 *= inv; a1 *= inv;
    a0 = a0 > 0.f ? a0 : 0.f;
    a1 = a1 > 0.f ? a1 : 0.f;
    int w = tid >> 6, q = (tid >> 4) & 3, l15 = tid & 15;
    int nq = ((q >> 1) << 2) | (q & 1);
    int c0 = w * 128 + nq * 16 + l15;
    hrow[c0] = a0; hrow[c0 + 32] = a1;
    unsigned short h0 = f2bf(a0), h1 = f2bf(a1);
    hhi[(size_t)d * DH + c0] = h0;
    hlo[(size_t)d * DH + c0] = f2bf(a0 - bf2f(h0));
    hhi[(size_t)d * DH + c0 + 32] = h1;
    hlo[(size_t)d * DH + c0 + 32] = f2bf(a1 - bf2f(h1));
    __syncthreads();
    int j = tid & 31, ib = tid >> 5;
    float s = 0.f;
    #pragma unroll 8
    for (int i = ib * 64; i < ib * 64 + 64; ++i) s += hrow[i] * alpha2[(size_t)i * 32 + j];
    red[j][ib] = s;
    __syncthreads();
    if (tid < 32) {
        float t = 0.f;
        #pragma unroll
        for (int g = 0; g < 8; ++g) t += red[tid][g];
        qk2v[(size_t)d * 32 + tid] = t;
    }
}

__global__ void elogit2_kernel(const int* __restrict__ ei, const int* __restrict__ et,
                               const float* __restrict__ qk2, float* __restrict__ e2) {
    int e = blockIdx.x * blockDim.x + threadIdx.x;
    if (e >= NE) return;
    int src = ei[e], dst = ei[NE + e], r = et[e];
    float l = qk2[(size_t)dst * 32 + r * 2] + qk2[(size_t)src * 32 + r * 2 + 1];
    l = l > 0.f ? l : 0.2f * l;
    e2[e] = __expf(l);
}

// ---------------- dense Y2 = H @ W2_all  ([20000x512] @ [512x2048]) ----------------
// Wave w of block (mt, ns) computes relation r = ns*4+w's 128 cols for rows mt*64..+64.
// Output packed like msgu: row stride 1024 u32; slot r*64 + q*16 + l15 holds
// cols (r*128 + nq*16 + l15, +32), nq = (q>>1)*4 + (q&1).
__global__ __launch_bounds__(256, 2)
void y2_gemm_kernel(const unsigned short* __restrict__ hhi, const unsigned short* __restrict__ hlo,
                    const unsigned short* __restrict__ W2Thi, const unsigned short* __restrict__ W2Tlo,
                    unsigned* __restrict__ Y2u) {
    int t = (blockIdx.x & 7) * (YGRID / 8) + (blockIdx.x >> 3);   // XCD-contiguous
    if (t >= MT2 * 4) return;
    int mt = t >> 2, ns = t & 3;
    int n0 = mt * TILE;
    __shared__ __align__(16) unsigned short Ah[64 * 128];
    __shared__ __align__(16) unsigned short Al[64 * 128];
    int tid = threadIdx.x;
    int w = tid >> 6, lane = tid & 63;
    int l15 = lane & 15, l4 = lane >> 4;
    const unsigned short* Bh = W2Thi + ((size_t)((ns * 4 + w) * 128) + l15) * DH + l4 * 8;
    const unsigned short* Bl = W2Tlo + ((size_t)((ns * 4 + w) * 128) + l15) * DH + l4 * 8;
    f32x4 acc[4][8];
    #pragma unroll
    for (int m = 0; m < 4; ++m)
        #pragma unroll
        for (int n = 0; n < 8; ++n) acc[m][n] = (f32x4){0.f, 0.f, 0.f, 0.f};
    for (int kc = 0; kc < 4; ++kc) {
        if (kc) __syncthreads();
        {
            int row = tid >> 2, seg = tid & 3;
            int n = n0 + row; if (n >= NN) n = NN - 1;
            const uint4* ph = (const uint4*)(hhi + (size_t)n * DH + kc * 128 + seg * 32);
            const uint4* pl = (const uint4*)(hlo + (size_t)n * DH + kc * 128 + seg * 32);
            unsigned rb = row * 256, sw = (row & 7) << 4;
            #pragma unroll
            for (int i = 0; i < 4; ++i) {
                unsigned off = (rb + seg * 64 + i * 16) ^ sw;
                *(uint4*)((char*)Ah + off) = ph[i];
                *(uint4*)((char*)Al + off) = pl[i];
            }
        }
        __syncthreads();
        #pragma unroll
        for (int mg = 0; mg < 2; ++mg) {
            bf16x8 ah[2][4], al[2][4];
            #pragma unroll
            for (int mm = 0; mm < 2; ++mm) {
                int row = (mg * 2 + mm) * 16 + l15;
                unsigned rb = row * 256, sw = (row & 7) << 4;
                #pragma unroll
                for (int k = 0; k < 4; ++k) {
                    unsigned off = (rb + k * 64 + l4 * 16) ^ sw;
                    ah[mm][k] = *(const bf16x8*)((const char*)Ah + off);
                    al[mm][k] = *(const bf16x8*)((const char*)Al + off);
                }
            }
            #pragma unroll
            for (int n = 0; n < 8; ++n) {
                #pragma unroll
                for (int k = 0; k < 4; ++k) {
                    bf16x8 bh = *(const bf16x8*)(Bh + (size_t)n * 16 * DH + kc * 128 + k * 32);
                    bf16x8 bl = *(const bf16x8*)(Bl + (size_t)n * 16 * DH + kc * 128 + k * 32);
                    #pragma unroll
                    for (int mm = 0; mm < 2; ++mm) {
                        int m = mg * 2 + mm;
                        acc[m][n] = __builtin_amdgcn_mfma_f32_16x16x32_bf16(ah[mm][k], bh, acc[m][n], 0, 0, 0);
                        acc[m][n] = __builtin_amdgcn_mfma_f32_16x16x32_bf16(ah[mm][k], bl, acc[m][n], 0, 0, 0);
                        acc[m][n] = __builtin_amdgcn_mfma_f32_16x16x32_bf16(al[mm][k], bh, acc[m][n], 0, 0, 0);
                    }
                }
            }
        }
    }
    unsigned* mb = Y2u + (size_t)n0 * 1024 + (ns * 4 + w) * 64 + l15;
    #pragma unroll
    for (int m = 0; m < 4; ++m) {
        int row0 = m * 16 + l4 * 4;
        #pragma unroll
        for (int rg = 0; rg < 4; ++rg) {
            int row = row0 + rg;
            if (n0 + row < NN) {
                unsigned* mp = mb + (size_t)row * 1024;
                #pragma unroll
                for (int q = 0; q < 4; ++q) {
                    int nq = ((q >> 1) << 2) | (q & 1);
                    mp[q * 16] = packbf(acc[m][nq][rg], acc[m][nq + 2][rg]);
                }
            }
        }
    }
}

// ---------------- layer2 agg: gather Y2[src*16+r] rows per dst ----------------
__global__ void l2_agg_kernel(const unsigned* __restrict__ Y2u, const float* __restrict__ e2,
                              const int* __restrict__ dedge, const int* __restrict__ dsr,
                              const int* __restrict__ doffs, float* __restrict__ zacc) {
    int tid = threadIdx.x;
    int d = blockIdx.x * 4 + (tid >> 6);
    if (d >= NN) return;
    int lane = tid & 63;
    int lo_ = doffs[d], hi_ = doffs[d + 1];
    float a0 = 0.f, a1 = 0.f, se = 0.f;
    for (int p = lo_; p < hi_; ++p) {
        float wgt = e2[dedge[p]];
        se += wgt;
        unsigned v = Y2u[(size_t)dsr[p] * 64 + lane];
        a0 += wgt * bf2f((unsigned short)(v & 0xffff));
        a1 += wgt * bf2f((unsigned short)(v >> 16));
    }
    float inv = 1.f / (se + 1e-16f);
    int q = lane >> 4, l15 = lane & 15;
    int nq = ((q >> 1) << 2) | (q & 1);
    int c0 = nq * 16 + l15;
    zacc[(size_t)d * DOUT + c0] = a0 * inv;
    zacc[(size_t)d * DOUT + c0 + 32] = a1 * inv;
}

// ---------------- link-prediction decoder (MFMA, split bf16) ----------------
__global__ __launch_bounds__(256, 2)
void decode_kernel(const float* __restrict__ z, const int* __restrict__ tgt,
                   const unsigned short* __restrict__ Lhi, const unsigned short* __restrict__ Llo,
                   const float* __restrict__ lb1, const float* __restrict__ lw2,
                   const float* __restrict__ lb2, float* __restrict__ out) {
    __shared__ __align__(16) unsigned short Ah[64 * 256];
    __shared__ __align__(16) unsigned short Al[64 * 256];
    __shared__ float red[TILE][5];
    int t0 = blockIdx.x * TILE;
    int tid = threadIdx.x;
    int cnt = NT - t0; if (cnt > TILE) cnt = TILE;
    {
        int row = tid >> 2, seg = tid & 3;
        int node = 0;
        bool live = (row < cnt);
        if (live) node = tgt[(seg >> 1) * NT + t0 + row];
        const float4* pz = (const float4*)(z + (size_t)node * DOUT + (seg & 1) * 64);
        unsigned rb = row * 512, sb = (seg >> 1) * 256 + (seg & 1) * 128;
        unsigned sw = (row & 7) << 4;
        #pragma unroll
        for (int g = 0; g < 8; ++g) {
            float4 a = live ? pz[g * 2] : (float4){0,0,0,0};
            float4 bq = live ? pz[g * 2 + 1] : (float4){0,0,0,0};
            unsigned short h0 = f2bf(a.x), h1 = f2bf(a.y), h2 = f2bf(a.z), h3 = f2bf(a.w);
            unsigned short h4 = f2bf(bq.x), h5 = f2bf(bq.y), h6 = f2bf(bq.z), h7 = f2bf(bq.w);
            uint4 uh, ul;
            uh.x = (unsigned)h0 | ((unsigned)h1 << 16);
            uh.y = (unsigned)h2 | ((unsigned)h3 << 16);
            uh.z = (unsigned)h4 | ((unsigned)h5 << 16);
            uh.w = (unsigned)h6 | ((unsigned)h7 << 16);
            ul.x = (unsigned)f2bf(a.x - bf2f(h0)) | ((unsigned)f2bf(a.y - bf2f(h1)) << 16);
            ul.y = (unsigned)f2bf(a.z - bf2f(h2)) | ((unsigned)f2bf(a.w - bf2f(h3)) << 16);
            ul.z = (unsigned)f2bf(bq.x - bf2f(h4)) | ((unsigned)f2bf(bq.y - bf2f(h5)) << 16);
            ul.w = (unsigned)f2bf(bq.z - bf2f(h6)) | ((unsigned)f2bf(bq.w - bf2f(h7)) << 16);
            unsigned off = (rb + sb + g * 16) ^ sw;
            *(uint4*)((char*)Ah + off) = uh;
            *(uint4*)((char*)Al + off) = ul;
        }
    }
    __syncthreads();
    int w = tid >> 6, lane = tid & 63;
    int l15 = lane & 15, l4 = lane >> 4;
    const unsigned short* Bh = Lhi + (size_t)(w * 32 + l15) * 256 + l4 * 8;
    const unsigned short* Bl = Llo + (size_t)(w * 32 + l15) * 256 + l4 * 8;
    f32x4 acc[4][2];
    #pragma unroll
    for (int m = 0; m < 4; ++m) { acc[m][0] = (f32x4){0.f,0.f,0.f,0.f}; acc[m][1] = (f32x4){0.f,0.f,0.f,0.f}; }
    #pragma unroll
    for (int k = 0; k < 8; ++k) {
        bf16x8 ah[4], al[4];
        #pragma unroll
        for (int m = 0; m < 4; ++m) {
            int row = m * 16 + l15;
            unsigned off = ((unsigned)row * 512 + k * 64 + l4 * 16) ^ ((unsigned)(row & 7) << 4);
            ah[m] = *(const bf16x8*)((const char*)Ah + off);
            al[m] = *(const bf16x8*)((const char*)Al + off);
        }
        #pragma unroll
        for (int n = 0; n < 2; ++n) {
            bf16x8 bh = *(const bf16x8*)(Bh + (size_t)n * 16 * 256 + k * 32);
            bf16x8 bl = *(const bf16x8*)(Bl + (size_t)n * 16 * 256 + k * 32);
            #pragma unroll
            for (int m = 0; m < 4; ++m) {
                acc[m][n] = __builtin_amdgcn_mfma_f32_16x16x32_bf16(ah[m], bh, acc[m][n], 0, 0, 0);
                acc[m][n] = __builtin_amdgcn_mfma_f32_16x16x32_bf16(ah[m], bl, acc[m][n], 0, 0, 0);
                acc[m][n] = __builtin_amdgcn_mfma_f32_16x16x32_bf16(al[m], bh, acc[m][n], 0, 0, 0);
            }
        }
    }
    int col0 = w * 32 + l15;
    float lb_0 = lb1[col0], lb_1 = lb1[col0 + 16];
    float lwa = lw2[col0], lwb = lw2[col0 + 16];
    #pragma unroll
    for (int m = 0; m < 4; ++m) {
        #pragma unroll
        for (int rg = 0; rg < 4; ++rg) {
            float h0 = acc[m][0][rg] + lb_0; h0 = h0 > 0.f ? h0 : 0.f;
            float h1 = acc[m][1][rg] + lb_1; h1 = h1 > 0.f ? h1 : 0.f;
            float s = h0 * lwa + h1 * lwb;
            s += __shfl_xor(s, 1); s += __shfl_xor(s, 2);
            s += __shfl_xor(s, 4); s += __shfl_xor(s, 8);
            if (l15 == 0) red[m * 16 + l4 * 4 + rg][w] = s;
        }
    }
    __syncthreads();
    if (tid < cnt) out[t0 + tid] = red[tid][0] + red[tid][1] + red[tid][2] + red[tid][3] + lb2[0];
}

extern "C" void kernel_launch(void* const* d_in, const int* in_sizes, int n_in,
                              void* d_out, int out_size, void* d_ws, size_t ws_size,
                              hipStream_t stream) {
    const float* x   = (const float*)d_in[0];
    const int*   ei  = (const int*)d_in[1];
    const int*   et  = (const int*)d_in[2];
    const int*   tgt = (const int*)d_in[3];
    const float* W1  = (const float*)d_in[4];
    const float* aq1 = (const float*)d_in[5];
    const float* ak1 = (const float*)d_in[6];
    const float* W2  = (const float*)d_in[7];
    const float* aq2 = (const float*)d_in[8];
    const float* ak2 = (const float*)d_in[9];
    const float* lw1 = (const float*)d_in[10];
    const float* lb1 = (const float*)d_in[11];
    const float* lw2 = (const float*)d_in[12];
    const float* lb2 = (const float*)d_in[13];
    float* out = (float*)d_out;
    (void)in_sizes; (void)n_in; (void)out_size; (void)ws_size;

    char* ws = (char*)d_ws;
    size_t off = 0;
    auto alloc = [&](size_t bytes) -> void* {
        void* p = ws + off;
        off += (bytes + 255) & ~(size_t)255;
        return p;
    };
    // zero-init block: histograms only
    int* cnt   = (int*)alloc(NBUCKET * sizeof(int));
    int* cnt_d = (int*)alloc((size_t)NN * sizeof(int));
    size_t zero_bytes = off;
    // no-init scratch
    int*   boffs    = (int*)alloc((NBUCKET + 1) * sizeof(int));
    int*   cursor   = (int*)alloc(NBUCKET * sizeof(int));
    int*   cts      = (int*)alloc((CHUNKS + 1) * sizeof(int));
    int*   doffs    = (int*)alloc((size_t)(NN + 1) * sizeof(int));
    int*   cursor_d = (int*)alloc((size_t)NN * sizeof(int));
    int*   border   = (int*)alloc((size_t)NE * sizeof(int));
    int*   dlist    = (int*)alloc((size_t)NE * sizeof(int));
    int*   dedge    = (int*)alloc((size_t)NE * sizeof(int));
    int*   dsr      = (int*)alloc((size_t)NE * sizeof(int));
    int*   tile_b   = (int*)alloc((size_t)NTILESMAX * sizeof(int));
    int*   tile_s   = (int*)alloc((size_t)NTILESMAX * sizeof(int));
    float* alpha2   = (float*)alloc((size_t)512 * 32 * 4);
    float* qk2v     = (float*)alloc((size_t)NN * 32 * 4);
    float* e2       = (float*)alloc((size_t)NE * 4);
    float* zacc     = (float*)alloc((size_t)NN * DOUT * 4);
    unsigned short* xhi   = (unsigned short*)alloc((size_t)NN * DIN * 2);
    unsigned short* xlo   = (unsigned short*)alloc((size_t)NN * DIN * 2);
    unsigned short* hhi   = (unsigned short*)alloc((size_t)NN * DH * 2);
    unsigned short* hlo   = (unsigned short*)alloc((size_t)NN * DH * 2);
    unsigned short* W1Thi = (unsigned short*)alloc((size_t)NR * DH * DIN * 2);
    unsigned short* W1Tlo = (unsigned short*)alloc((size_t)NR * DH * DIN * 2);
    unsigned short* W2Thi = (unsigned short*)alloc((size_t)NR * DOUT * DH * 2);
    unsigned short* W2Tlo = (unsigned short*)alloc((size_t)NR * DOUT * DH * 2);
    unsigned short* Lhi   = (unsigned short*)alloc((size_t)128 * 256 * 2);
    unsigned short* Llo   = (unsigned short*)alloc((size_t)128 * 256 * 2);
    // region R (82 MB): msgu (l1 phase, 47.2 MB) then reused as dense Y2 table.
    // alpha1/qk1/e1 alias R's tail — all dead before y2_gemm writes R.
    char* msgr = (char*)alloc((size_t)NN * 1024 * 4);               // 81,920,000 B
    unsigned* msgu = (unsigned*)msgr;
    unsigned* Y2u  = (unsigned*)msgr;
    float* alpha1 = (float*)(msgr + (size_t)MSGROWS * 256 * 4);     // +47,185,920
    float* qk1    = alpha1 + 128 * 256;
    float* e1     = qk1 + (size_t)NN * 256;                         // ends ~78.0 MB < 81.9 MB

    hipMemsetAsync(ws, 0, zero_bytes, stream);
    alpha1_kernel<<<DIN, 256, 0, stream>>>(W1, aq1, ak1, alpha1);
    alpha2_kernel<<<(DH * 32 + 255) / 256, 256, 0, stream>>>(W2, aq2, ak2, alpha2);
    split_x_kernel<<<(NN * DIN / 4 + 255) / 256, 256, 0, stream>>>(x, xhi, xlo);
    splitW1T_kernel<<<NR * 8, 256, 0, stream>>>(W1, W1Thi, W1Tlo);
    splitW2T_kernel<<<NR * 2, 256, 0, stream>>>(W2, W2Thi, W2Tlo);
    splitLw1_kernel<<<(256 * 128 + 255) / 256, 256, 0, stream>>>(lw1, Lhi, Llo);
    hist_kernel<<<(NE + 255) / 256, 256, 0, stream>>>(ei, et, cnt, cnt_d);
    scan_bkt_kernel<<<1, 64, 0, stream>>>(cnt, boffs, cursor, cts);
    tilemap_kernel<<<(NTILESMAX + 255) / 256, 256, 0, stream>>>(boffs, tile_b, tile_s);
    bucket_place_kernel<<<(NE + 255) / 256, 256, 0, stream>>>(ei, et, cursor, border);
    scan_dst_kernel<<<1, 1024, 0, stream>>>(cnt_d, doffs, cursor_d);
    place_dst_kernel<<<(NE + 255) / 256, 256, 0, stream>>>(border, ei, et, cursor_d, dlist, dedge, dsr);
    qk1_kernel<<<(NN + TILE - 1) / TILE, 256, 0, stream>>>(x, alpha1, qk1);
    elogit1_kernel<<<(NE + 255) / 256, 256, 0, stream>>>(ei, et, qk1, e1);
    for (int c = 0; c < CHUNKS; ++c) {
        l1_gemm_kernel<<<MAXTPC, 256, 0, stream>>>(xhi, xlo, W1Thi, W1Tlo, ei, border,
                                                   tile_b, tile_s, boffs, cts, c, msgu);
        l1_agg_kernel<<<CHD, 256, 0, stream>>>(msgu, e1, dlist, dedge, doffs, boffs, c,
                                               hhi, hlo, alpha2, qk2v);
    }
    elogit2_kernel<<<(NE + 255) / 256, 256, 0, stream>>>(ei, et, qk2v, e2);
    y2_gemm_kernel<<<YGRID, 256, 0, stream>>>(hhi, hlo, W2Thi, W2Tlo, Y2u);
    l2_agg_kernel<<<(NN + 3) / 4, 256, 0, stream>>>(Y2u, e2, dedge, dsr, doffs, zacc);
    decode_kernel<<<(NT + TILE - 1) / TILE, 256, 0, stream>>>(zacc, tgt, Lhi, Llo,
                                                              lb1, lw2, lb2, out);
}

// Round 9
// 867.968 us; speedup vs baseline: 1.4042x; 1.2493x over previous
//
#include <hip/hip_runtime.h>
#include <cstdint>
#include <cstddef>

#define NN     20000
#define NE     320000
#define NR     16
#define DIN    128
#define DH     512
#define DOUT   128
#define NT     50000
#define TILE   64                      // qk1/decode row tile
#define TILE1  128                     // layer-1 edge tile
#define CHUNKS 8
#define CHD    2500
#define NBUCKET (CHUNKS * NR)          // 128
#define MSGROWS 46080                  // max edges per chunk
#define MAXTPC1 1536                   // l1 grid per chunk (8*192), = tiles*4 padded
#define NTILESMAX1 (NE / TILE1 + NBUCKET)
#define MT2Y   157                     // ceil(20000/128)
#define YGRID  (MT2Y * 16)             // 2512 = 8*314

typedef __attribute__((ext_vector_type(8))) short bf16x8;
typedef __attribute__((ext_vector_type(4))) float f32x4;

__device__ __forceinline__ unsigned short f2bf(float x) {
    unsigned int b = __float_as_uint(x);
    b = b + 0x7fffu + ((b >> 16) & 1u);
    return (unsigned short)(b >> 16);
}
__device__ __forceinline__ float bf2f(unsigned short u) {
    return __uint_as_float(((unsigned int)u) << 16);
}
__device__ __forceinline__ unsigned packbf(float lo, float hi) {
    return (unsigned)f2bf(lo) | ((unsigned)f2bf(hi) << 16);
}

// ---------------- fold attention vectors into weights ----------------
__global__ void alpha1_kernel(const float* __restrict__ W1, const float* __restrict__ aq1,
                              const float* __restrict__ ak1, float* __restrict__ alpha1) {
    int i = blockIdx.x;
    int c = threadIdx.x;
    int r = c >> 4, s = (c >> 3) & 1, h = c & 7;
    const float* att = (s == 0 ? aq1 : ak1) + (r * 8 + h) * 64;
    const float* w = W1 + ((size_t)(r * DIN + i)) * DH + h * 64;
    float acc = 0.f;
    #pragma unroll 8
    for (int o = 0; o < 64; ++o) acc += w[o] * att[o];
    alpha1[i * 256 + c] = acc;
}

__global__ void alpha2_kernel(const float* __restrict__ W2, const float* __restrict__ aq2,
                              const float* __restrict__ ak2, float* __restrict__ alpha2) {
    int g = blockIdx.x * blockDim.x + threadIdx.x;
    if (g >= DH * 32) return;
    int i = g >> 5, c = g & 31;
    int r = c >> 1, s = c & 1;
    const float* att = (s == 0 ? aq2 : ak2) + r * DOUT;
    const float* w = W2 + ((size_t)(r * DH + i)) * DOUT;
    float acc = 0.f;
    #pragma unroll 8
    for (int o = 0; o < DOUT; ++o) acc += w[o] * att[o];
    alpha2[i * 32 + c] = acc;
}

// ---------------- bf16 hi/lo precompute ----------------
__global__ void split_x_kernel(const float* __restrict__ x, unsigned short* __restrict__ xhi,
                               unsigned short* __restrict__ xlo) {
    int g = blockIdx.x * 256 + threadIdx.x;
    if (g >= NN * DIN / 4) return;
    float4 v = ((const float4*)x)[g];
    ushort4 h, l;
    h.x = f2bf(v.x); l.x = f2bf(v.x - bf2f(h.x));
    h.y = f2bf(v.y); l.y = f2bf(v.y - bf2f(h.y));
    h.z = f2bf(v.z); l.z = f2bf(v.z - bf2f(h.z));
    h.w = f2bf(v.w); l.w = f2bf(v.w - bf2f(h.w));
    ((ushort4*)xhi)[g] = h;
    ((ushort4*)xlo)[g] = l;
}

__global__ void splitW1T_kernel(const float* __restrict__ W1, unsigned short* __restrict__ Whi,
                                unsigned short* __restrict__ Wlo) {
    __shared__ float T[128 * 65];
    int r = blockIdx.x >> 3;
    int ob = blockIdx.x & 7;
    int tid = threadIdx.x;
    for (int idx = tid; idx < 128 * 64; idx += 256) {
        int i = idx >> 6, o = idx & 63;
        T[i * 65 + o] = W1[((size_t)(r * DIN + i)) * DH + ob * 64 + o];
    }
    __syncthreads();
    for (int idx = tid; idx < 64 * 128; idx += 256) {
        int o = idx >> 7, i = idx & 127;
        float v = T[i * 65 + o];
        unsigned short h = f2bf(v);
        size_t off = ((size_t)r * DH + ob * 64 + o) * DIN + i;
        Whi[off] = h;
        Wlo[off] = f2bf(v - bf2f(h));
    }
}

__global__ void splitW2T_kernel(const float* __restrict__ W2, unsigned short* __restrict__ Whi,
                                unsigned short* __restrict__ Wlo) {
    __shared__ float T[128 * 65];
    int r = blockIdx.x >> 1;
    int ob = blockIdx.x & 1;
    int tid = threadIdx.x;
    for (int kc = 0; kc < 4; ++kc) {
        if (kc) __syncthreads();
        for (int idx = tid; idx < 128 * 64; idx += 256) {
            int k = idx >> 6, o = idx & 63;
            T[k * 65 + o] = W2[((size_t)(r * DH + kc * 128 + k)) * DOUT + ob * 64 + o];
        }
        __syncthreads();
        for (int idx = tid; idx < 64 * 128; idx += 256) {
            int o = idx >> 7, k = idx & 127;
            float v = T[k * 65 + o];
            unsigned short h = f2bf(v);
            size_t off = ((size_t)r * DOUT + ob * 64 + o) * DH + kc * 128 + k;
            Whi[off] = h;
            Wlo[off] = f2bf(v - bf2f(h));
        }
    }
}

__global__ void splitLw1_kernel(const float* __restrict__ lw1, unsigned short* __restrict__ Lhi,
                                unsigned short* __restrict__ Llo) {
    int g = blockIdx.x * 256 + threadIdx.x;
    if (g >= 256 * 128) return;
    int o = g >> 8, k = g & 255;
    float v = lw1[k * 128 + o];
    unsigned short h = f2bf(v);
    Lhi[(size_t)o * 256 + k] = h;
    Llo[(size_t)o * 256 + k] = f2bf(v - bf2f(h));
}

// ---------------- sorts ----------------
__global__ void hist_kernel(const int* __restrict__ ei, const int* __restrict__ et,
                            int* __restrict__ cnt, int* __restrict__ cnt_d) {
    __shared__ int bins[NBUCKET];
    int t = threadIdx.x;
    if (t < NBUCKET) bins[t] = 0;
    __syncthreads();
    int e = blockIdx.x * 256 + t;
    if (e < NE) {
        int d = ei[NE + e];
        int key = (d / CHD) * NR + et[e];
        atomicAdd(&bins[key], 1);
        atomicAdd(&cnt_d[d], 1);
    }
    __syncthreads();
    if (t < NBUCKET && bins[t]) atomicAdd(&cnt[t], bins[t]);
}

__global__ void scan_bkt_kernel(const int* __restrict__ cnt, int* __restrict__ boffs,
                                int* __restrict__ cursor, int* __restrict__ cts) {
    if (threadIdx.x != 0) return;
    int acc = 0, tiles = 0;
    for (int b = 0; b < NBUCKET; ++b) {
        if ((b & (NR - 1)) == 0) cts[b >> 4] = tiles;
        boffs[b] = acc; cursor[b] = acc;
        int cn = cnt[b];
        tiles += (cn + TILE1 - 1) / TILE1;
        acc += cn;
    }
    boffs[NBUCKET] = acc; cts[CHUNKS] = tiles;
}

__global__ void tilemap_kernel(const int* __restrict__ boffs, int* __restrict__ tile_b,
                               int* __restrict__ tile_s) {
    __shared__ int bo[NBUCKET + 1];
    int tid = threadIdx.x;
    if (tid <= NBUCKET) bo[tid] = boffs[tid];
    __syncthreads();
    int t = blockIdx.x * 256 + tid;
    if (t >= NTILESMAX1) return;
    int acc = 0, bb = -1, ss = 0;
    for (int b = 0; b < NBUCKET; ++b) {
        int cn = bo[b + 1] - bo[b];
        int nt = (cn + TILE1 - 1) / TILE1;
        if (t >= acc && t < acc + nt) { bb = b; ss = bo[b] + (t - acc) * TILE1; }
        acc += nt;
    }
    tile_b[t] = bb; tile_s[t] = ss;
}

__global__ void bucket_place_kernel(const int* __restrict__ ei, const int* __restrict__ et,
                                    int* __restrict__ cursor, int* __restrict__ border) {
    __shared__ int binc[NBUCKET], base_[NBUCKET], rank_[NBUCKET];
    int t = threadIdx.x;
    if (t < NBUCKET) { binc[t] = 0; rank_[t] = 0; }
    __syncthreads();
    int e = blockIdx.x * 256 + t;
    int key = -1;
    if (e < NE) { key = (ei[NE + e] / CHD) * NR + et[e]; atomicAdd(&binc[key], 1); }
    __syncthreads();
    if (t < NBUCKET && binc[t]) base_[t] = atomicAdd(&cursor[t], binc[t]);
    __syncthreads();
    if (key >= 0) border[base_[key] + atomicAdd(&rank_[key], 1)] = e;
}

__global__ void scan_dst_kernel(const int* __restrict__ cnt_d, int* __restrict__ doffs,
                                int* __restrict__ cursor_d) {
    __shared__ int part[1024];
    int t = threadIdx.x;
    int base = t * 20;
    int s = 0;
    for (int i = 0; i < 20 && base + i < NN; ++i) s += cnt_d[base + i];
    part[t] = s;
    __syncthreads();
    for (int off = 1; off < 1024; off <<= 1) {
        int v = (t >= off) ? part[t - off] : 0;
        __syncthreads();
        part[t] += v;
        __syncthreads();
    }
    int run = part[t] - s;
    for (int i = 0; i < 20 && base + i < NN; ++i) {
        doffs[base + i] = run; cursor_d[base + i] = run;
        run += cnt_d[base + i];
    }
    if (t == 1023) doffs[NN] = part[1023];
}

__global__ void place_dst_kernel(const int* __restrict__ border, const int* __restrict__ ei,
                                 const int* __restrict__ et, int* __restrict__ cursor_d,
                                 int* __restrict__ dlist, int* __restrict__ dedge,
                                 int* __restrict__ dsr) {
    int pos = blockIdx.x * 256 + threadIdx.x;
    if (pos >= NE) return;
    int e = border[pos];
    int d = ei[NE + e];
    int idx = atomicAdd(&cursor_d[d], 1);
    dlist[idx] = pos;
    dedge[idx] = e;
    dsr[idx] = ei[e] * NR + et[e];
}

// ---------------- qk1 = x @ alpha1 ----------------
__global__ void qk1_kernel(const float* __restrict__ x, const float* __restrict__ alpha1,
                           float* __restrict__ qk1) {
    __shared__ float Xt[TILE][DIN + 1];
    int n0 = blockIdx.x * TILE;
    int tid = threadIdx.x;
    for (int idx = tid; idx < TILE * DIN; idx += 256) {
        int row = idx >> 7, i = idx & 127;
        int n = n0 + row;
        Xt[row][i] = (n < NN) ? x[(size_t)n * DIN + i] : 0.f;
    }
    __syncthreads();
    int to = tid >> 4, te = tid & 15;
    for (int c = 0; c < 2; ++c) {
        float acc[4][8] = {};
        const float* Wp = alpha1 + c * 128 + to * 8;
        for (int i = 0; i < DIN; ++i) {
            float4 w0 = *(const float4*)(Wp + (size_t)i * 256);
            float4 w1 = *(const float4*)(Wp + (size_t)i * 256 + 4);
            float w[8] = {w0.x, w0.y, w0.z, w0.w, w1.x, w1.y, w1.z, w1.w};
            #pragma unroll
            for (int a = 0; a < 4; ++a) {
                float xv = Xt[te * 4 + a][i];
                #pragma unroll
                for (int b = 0; b < 8; ++b) acc[a][b] += xv * w[b];
            }
        }
        #pragma unroll
        for (int a = 0; a < 4; ++a) {
            int n = n0 + te * 4 + a;
            if (n < NN) {
                float* op = qk1 + (size_t)n * 256 + c * 128 + to * 8;
                #pragma unroll
                for (int b = 0; b < 8; ++b) op[b] = acc[a][b];
            }
        }
    }
}

__global__ void elogit1_kernel(const int* __restrict__ ei, const int* __restrict__ et,
                               const float* __restrict__ qk1, float* __restrict__ e1) {
    int e = blockIdx.x * blockDim.x + threadIdx.x;
    if (e >= NE) return;
    int src = ei[e], dst = ei[NE + e], r = et[e];
    const float* qp = qk1 + (size_t)dst * 256 + r * 16;
    const float* kp = qk1 + (size_t)src * 256 + r * 16 + 8;
    float* ep = e1 + (size_t)e * 8;
    #pragma unroll
    for (int h = 0; h < 8; ++h) {
        float l = qp[h] + kp[h];
        l = l > 0.f ? l : 0.2f * l;
        ep[h] = __expf(l);
    }
}

// ---------------- layer1 GEMM: 128-edge x 128-col tiles, A+B in LDS ----------------
__global__ __launch_bounds__(256, 2)
void l1_gemm_kernel(const unsigned short* __restrict__ xhi, const unsigned short* __restrict__ xlo,
                    const unsigned short* __restrict__ W1Thi, const unsigned short* __restrict__ W1Tlo,
                    const int* __restrict__ ei, const int* __restrict__ border,
                    const int* __restrict__ tile_b, const int* __restrict__ tile_s,
                    const int* __restrict__ boffs, const int* __restrict__ cts,
                    int c, unsigned* __restrict__ msgu) {
    int wg = (blockIdx.x & 7) * (MAXTPC1 / 8) + (blockIdx.x >> 3);   // XCD-contiguous
    int tt = wg >> 2, cb = wg & 3;
    int t = cts[c] + tt;
    if (t >= cts[c + 1]) return;
    int b = tile_b[t];
    int r = b & (NR - 1);
    int start = tile_s[t];
    int cstart = boffs[c * NR];
    int cnt = boffs[b + 1] - start; if (cnt > TILE1) cnt = TILE1;
    __shared__ __align__(16) unsigned short Ah[128 * 64];
    __shared__ __align__(16) unsigned short Al[128 * 64];
    __shared__ __align__(16) unsigned short Bh_[128 * 64];
    __shared__ __align__(16) unsigned short Bl_[128 * 64];
    __shared__ int srcS[TILE1];
    int tid = threadIdx.x;
    if (tid < TILE1) {
        int sv = 0;
        if (tid < cnt) sv = ei[border[start + tid]];
        srcS[tid] = sv;
    }
    __syncthreads();
    int w = tid >> 6, lane = tid & 63;
    int l15 = lane & 15, l4 = lane >> 4;
    int wr = w >> 1, wc = w & 1;
    f32x4 acc[4][4];
    #pragma unroll
    for (int m = 0; m < 4; ++m)
        #pragma unroll
        for (int n = 0; n < 4; ++n) acc[m][n] = (f32x4){0.f, 0.f, 0.f, 0.f};
    for (int kc = 0; kc < 2; ++kc) {            // K = 128, BK = 64
        if (kc) __syncthreads();
        {
            int row = tid >> 1, seg = tid & 1;
            unsigned rb = row * 128, sw = (row & 7) << 4;
            const uint4* ph = (const uint4*)(xhi + (size_t)srcS[row] * DIN + kc * 64 + seg * 32);
            const uint4* pl = (const uint4*)(xlo + (size_t)srcS[row] * DIN + kc * 64 + seg * 32);
            const uint4* qh = (const uint4*)(W1Thi + ((size_t)r * DH + cb * 128 + row) * DIN + kc * 64 + seg * 32);
            const uint4* ql = (const uint4*)(W1Tlo + ((size_t)r * DH + cb * 128 + row) * DIN + kc * 64 + seg * 32);
            #pragma unroll
            for (int i = 0; i < 4; ++i) {
                unsigned off = (rb + seg * 64 + i * 16) ^ sw;
                *(uint4*)((char*)Ah + off) = ph[i];
                *(uint4*)((char*)Al + off) = pl[i];
                *(uint4*)((char*)Bh_ + off) = qh[i];
                *(uint4*)((char*)Bl_ + off) = ql[i];
            }
        }
        __syncthreads();
        bf16x8 ah[4][2], al[4][2], bh[4][2], bl[4][2];
        #pragma unroll
        for (int m = 0; m < 4; ++m) {
            int row = wr * 64 + m * 16 + l15;
            unsigned rb = row * 128, sw = (row & 7) << 4;
            #pragma unroll
            for (int ks = 0; ks < 2; ++ks) {
                unsigned off = (rb + ks * 64 + l4 * 16) ^ sw;
                ah[m][ks] = *(const bf16x8*)((const char*)Ah + off);
                al[m][ks] = *(const bf16x8*)((const char*)Al + off);
            }
        }
        #pragma unroll
        for (int n = 0; n < 4; ++n) {
            int col = wc * 64 + n * 16 + l15;
            unsigned rb = col * 128, sw = (col & 7) << 4;
            #pragma unroll
            for (int ks = 0; ks < 2; ++ks) {
                unsigned off = (rb + ks * 64 + l4 * 16) ^ sw;
                bh[n][ks] = *(const bf16x8*)((const char*)Bh_ + off);
                bl[n][ks] = *(const bf16x8*)((const char*)Bl_ + off);
            }
        }
        #pragma unroll
        for (int n = 0; n < 4; ++n)
            #pragma unroll
            for (int ks = 0; ks < 2; ++ks)
                #pragma unroll
                for (int m = 0; m < 4; ++m) {
                    acc[m][n] = __builtin_amdgcn_mfma_f32_16x16x32_bf16(ah[m][ks], bh[n][ks], acc[m][n], 0, 0, 0);
                    acc[m][n] = __builtin_amdgcn_mfma_f32_16x16x32_bf16(ah[m][ks], bl[n][ks], acc[m][n], 0, 0, 0);
                    acc[m][n] = __builtin_amdgcn_mfma_f32_16x16x32_bf16(al[m][ks], bh[n][ks], acc[m][n], 0, 0, 0);
                }
    }
    // epilogue: msg slot cb*64 + wc*32 + n*16 + l15 <-> cols cb*128 + wc*64 + (n*16+l15, +32)
    unsigned* mb = msgu + (size_t)(start - cstart) * 256 + cb * 64 + wc * 32 + l15;
    #pragma unroll
    for (int m = 0; m < 4; ++m) {
        int row0 = wr * 64 + m * 16 + l4 * 4;
        #pragma unroll
        for (int rg = 0; rg < 4; ++rg) {
            int row = row0 + rg;
            if (row < cnt) {
                unsigned* mp = mb + (size_t)row * 256;
                mp[0]  = packbf(acc[m][0][rg], acc[m][2][rg]);
                mp[16] = packbf(acc[m][1][rg], acc[m][3][rg]);
            }
        }
    }
}

// ---------------- layer1 agg (fused qk2) ----------------
__global__ void l1_agg_kernel(const unsigned* __restrict__ msgu, const float* __restrict__ e1,
                              const int* __restrict__ dlist, const int* __restrict__ dedge,
                              const int* __restrict__ doffs, const int* __restrict__ boffs,
                              int c, unsigned short* __restrict__ hhi, unsigned short* __restrict__ hlo,
                              const float* __restrict__ alpha2, float* __restrict__ qk2v) {
    __shared__ float hrow[DH];
    __shared__ float red[32][9];
    int tid = threadIdx.x;
    int d = c * CHD + blockIdx.x;
    int lo_ = doffs[d], hi_ = doffs[d + 1];
    int cstart = boffs[c * NR];
    int head = tid >> 5;
    float a0 = 0.f, a1 = 0.f, se = 0.f;
    for (int p = lo_; p < hi_; ++p) {
        int pos = dlist[p];
        float wgt = e1[(size_t)dedge[p] * 8 + head];
        se += wgt;
        unsigned v = msgu[(size_t)(pos - cstart) * 256 + tid];
        a0 += wgt * bf2f((unsigned short)(v & 0xffff));
        a1 += wgt * bf2f((unsigned short)(v >> 16));
    }
    float inv = 1.f / (se + 1e-16f);
    a0 *= inv; a1 *= inv;
    a0 = a0 > 0.f ? a0 : 0.f;
    a1 = a1 > 0.f ? a1 : 0.f;
    int w = tid >> 6, q = (tid >> 4) & 3, l15 = tid & 15;
    int nq = ((q >> 1) << 2) | (q & 1);
    int c0 = w * 128 + nq * 16 + l15;
    hrow[c0] = a0; hrow[c0 + 32] = a1;
    unsigned short h0 = f2bf(a0), h1 = f2bf(a1);
    hhi[(size_t)d * DH + c0] = h0;
    hlo[(size_t)d * DH + c0] = f2bf(a0 - bf2f(h0));
    hhi[(size_t)d * DH + c0 + 32] = h1;
    hlo[(size_t)d * DH + c0 + 32] = f2bf(a1 - bf2f(h1));
    __syncthreads();
    int j = tid & 31, ib = tid >> 5;
    float s = 0.f;
    #pragma unroll 8
    for (int i = ib * 64; i < ib * 64 + 64; ++i) s += hrow[i] * alpha2[(size_t)i * 32 + j];
    red[j][ib] = s;
    __syncthreads();
    if (tid < 32) {
        float t = 0.f;
        #pragma unroll
        for (int g = 0; g < 8; ++g) t += red[tid][g];
        qk2v[(size_t)d * 32 + tid] = t;
    }
}

__global__ void elogit2_kernel(const int* __restrict__ ei, const int* __restrict__ et,
                               const float* __restrict__ qk2, float* __restrict__ e2) {
    int e = blockIdx.x * blockDim.x + threadIdx.x;
    if (e >= NE) return;
    int src = ei[e], dst = ei[NE + e], r = et[e];
    float l = qk2[(size_t)dst * 32 + r * 2] + qk2[(size_t)src * 32 + r * 2 + 1];
    l = l > 0.f ? l : 0.2f * l;
    e2[e] = __expf(l);
}

// ---------------- dense Y2 = H @ W2_all : 128x128 tiles, A+B in LDS ----------------
__global__ __launch_bounds__(256, 2)
void y2_gemm_kernel(const unsigned short* __restrict__ hhi, const unsigned short* __restrict__ hlo,
                    const unsigned short* __restrict__ W2Thi, const unsigned short* __restrict__ W2Tlo,
                    unsigned* __restrict__ Y2u) {
    int t = (blockIdx.x & 7) * (YGRID / 8) + (blockIdx.x >> 3);   // XCD-contiguous
    int mt = t >> 4, r = t & 15;
    int n0 = mt * 128;
    __shared__ __align__(16) unsigned short Ah[128 * 64];
    __shared__ __align__(16) unsigned short Al[128 * 64];
    __shared__ __align__(16) unsigned short Bh_[128 * 64];
    __shared__ __align__(16) unsigned short Bl_[128 * 64];
    int tid = threadIdx.x;
    int w = tid >> 6, lane = tid & 63;
    int l15 = lane & 15, l4 = lane >> 4;
    int wr = w >> 1, wc = w & 1;
    f32x4 acc[4][4];
    #pragma unroll
    for (int m = 0; m < 4; ++m)
        #pragma unroll
        for (int n = 0; n < 4; ++n) acc[m][n] = (f32x4){0.f, 0.f, 0.f, 0.f};
    for (int kc = 0; kc < 8; ++kc) {            // K = 512, BK = 64
        if (kc) __syncthreads();
        {
            int row = tid >> 1, seg = tid & 1;
            int n = n0 + row; if (n >= NN) n = NN - 1;
            unsigned rb = row * 128, sw = (row & 7) << 4;
            const uint4* ph = (const uint4*)(hhi + (size_t)n * DH + kc * 64 + seg * 32);
            const uint4* pl = (const uint4*)(hlo + (size_t)n * DH + kc * 64 + seg * 32);
            const uint4* qh = (const uint4*)(W2Thi + ((size_t)r * DOUT + row) * DH + kc * 64 + seg * 32);
            const uint4* ql = (const uint4*)(W2Tlo + ((size_t)r * DOUT + row) * DH + kc * 64 + seg * 32);
            #pragma unroll
            for (int i = 0; i < 4; ++i) {
                unsigned off = (rb + seg * 64 + i * 16) ^ sw;
                *(uint4*)((char*)Ah + off) = ph[i];
                *(uint4*)((char*)Al + off) = pl[i];
                *(uint4*)((char*)Bh_ + off) = qh[i];
                *(uint4*)((char*)Bl_ + off) = ql[i];
            }
        }
        __syncthreads();
        bf16x8 ah[4][2], al[4][2], bh[4][2], bl[4][2];
        #pragma unroll
        for (int m = 0; m < 4; ++m) {
            int row = wr * 64 + m * 16 + l15;
            unsigned rb = row * 128, sw = (row & 7) << 4;
            #pragma unroll
            for (int ks = 0; ks < 2; ++ks) {
                unsigned off = (rb + ks * 64 + l4 * 16) ^ sw;
                ah[m][ks] = *(const bf16x8*)((const char*)Ah + off);
                al[m][ks] = *(const bf16x8*)((const char*)Al + off);
            }
        }
        #pragma unroll
        for (int n = 0; n < 4; ++n) {
            int col = wc * 64 + n * 16 + l15;
            unsigned rb = col * 128, sw = (col & 7) << 4;
            #pragma unroll
            for (int ks = 0; ks < 2; ++ks) {
                unsigned off = (rb + ks * 64 + l4 * 16) ^ sw;
                bh[n][ks] = *(const bf16x8*)((const char*)Bh_ + off);
                bl[n][ks] = *(const bf16x8*)((const char*)Bl_ + off);
            }
        }
        #pragma unroll
        for (int n = 0; n < 4; ++n)
            #pragma unroll
            for (int ks = 0; ks < 2; ++ks)
                #pragma unroll
                for (int m = 0; m < 4; ++m) {
                    acc[m][n] = __builtin_amdgcn_mfma_f32_16x16x32_bf16(ah[m][ks], bh[n][ks], acc[m][n], 0, 0, 0);
                    acc[m][n] = __builtin_amdgcn_mfma_f32_16x16x32_bf16(ah[m][ks], bl[n][ks], acc[m][n], 0, 0, 0);
                    acc[m][n] = __builtin_amdgcn_mfma_f32_16x16x32_bf16(al[m][ks], bh[n][ks], acc[m][n], 0, 0, 0);
                }
    }
    // epilogue: Y2 slot r*64 + wc*32 + n*16 + l15 <-> rel-cols wc*64 + (n*16+l15, +32)
    unsigned* mb = Y2u + (size_t)n0 * 1024 + r * 64 + wc * 32 + l15;
    #pragma unroll
    for (int m = 0; m < 4; ++m) {
        int row0 = wr * 64 + m * 16 + l4 * 4;
        #pragma unroll
        for (int rg = 0; rg < 4; ++rg) {
            int row = row0 + rg;
            if (n0 + row < NN) {
                unsigned* mp = mb + (size_t)row * 1024;
                mp[0]  = packbf(acc[m][0][rg], acc[m][2][rg]);
                mp[16] = packbf(acc[m][1][rg], acc[m][3][rg]);
            }
        }
    }
}

// ---------------- layer2 agg: gather Y2[src*16+r] rows per dst ----------------
__global__ void l2_agg_kernel(const unsigned* __restrict__ Y2u, const float* __restrict__ e2,
                              const int* __restrict__ dedge, const int* __restrict__ dsr,
                              const int* __restrict__ doffs, float* __restrict__ zacc) {
    int tid = threadIdx.x;
    int d = blockIdx.x * 4 + (tid >> 6);
    if (d >= NN) return;
    int lane = tid & 63;
    int lo_ = doffs[d], hi_ = doffs[d + 1];
    float a0 = 0.f, a1 = 0.f, se = 0.f;
    for (int p = lo_; p < hi_; ++p) {
        float wgt = e2[dedge[p]];
        se += wgt;
        unsigned v = Y2u[(size_t)dsr[p] * 64 + lane];
        a0 += wgt * bf2f((unsigned short)(v & 0xffff));
        a1 += wgt * bf2f((unsigned short)(v >> 16));
    }
    float inv = 1.f / (se + 1e-16f);
    int q = lane >> 4, l15 = lane & 15;
    int nq = ((q >> 1) << 2) | (q & 1);
    int c0 = nq * 16 + l15;
    zacc[(size_t)d * DOUT + c0] = a0 * inv;
    zacc[(size_t)d * DOUT + c0 + 32] = a1 * inv;
}

// ---------------- link-prediction decoder (MFMA, split bf16) ----------------
__global__ __launch_bounds__(256, 2)
void decode_kernel(const float* __restrict__ z, const int* __restrict__ tgt,
                   const unsigned short* __restrict__ Lhi, const unsigned short* __restrict__ Llo,
                   const float* __restrict__ lb1, const float* __restrict__ lw2,
                   const float* __restrict__ lb2, float* __restrict__ out) {
    __shared__ __align__(16) unsigned short Ah[64 * 256];
    __shared__ __align__(16) unsigned short Al[64 * 256];
    __shared__ float red[TILE][5];
    int t0 = blockIdx.x * TILE;
    int tid = threadIdx.x;
    int cnt = NT - t0; if (cnt > TILE) cnt = TILE;
    {
        int row = tid >> 2, seg = tid & 3;
        int node = 0;
        bool live = (row < cnt);
        if (live) node = tgt[(seg >> 1) * NT + t0 + row];
        const float4* pz = (const float4*)(z + (size_t)node * DOUT + (seg & 1) * 64);
        unsigned rb = row * 512, sb = (seg >> 1) * 256 + (seg & 1) * 128;
        unsigned sw = (row & 7) << 4;
        #pragma unroll
        for (int g = 0; g < 8; ++g) {
            float4 a = live ? pz[g * 2] : (float4){0,0,0,0};
            float4 bq = live ? pz[g * 2 + 1] : (float4){0,0,0,0};
            unsigned short h0 = f2bf(a.x), h1 = f2bf(a.y), h2 = f2bf(a.z), h3 = f2bf(a.w);
            unsigned short h4 = f2bf(bq.x), h5 = f2bf(bq.y), h6 = f2bf(bq.z), h7 = f2bf(bq.w);
            uint4 uh, ul;
            uh.x = (unsigned)h0 | ((unsigned)h1 << 16);
            uh.y = (unsigned)h2 | ((unsigned)h3 << 16);
            uh.z = (unsigned)h4 | ((unsigned)h5 << 16);
            uh.w = (unsigned)h6 | ((unsigned)h7 << 16);
            ul.x = (unsigned)f2bf(a.x - bf2f(h0)) | ((unsigned)f2bf(a.y - bf2f(h1)) << 16);
            ul.y = (unsigned)f2bf(a.z - bf2f(h2)) | ((unsigned)f2bf(a.w - bf2f(h3)) << 16);
            ul.z = (unsigned)f2bf(bq.x - bf2f(h4)) | ((unsigned)f2bf(bq.y - bf2f(h5)) << 16);
            ul.w = (unsigned)f2bf(bq.z - bf2f(h6)) | ((unsigned)f2bf(bq.w - bf2f(h7)) << 16);
            unsigned off = (rb + sb + g * 16) ^ sw;
            *(uint4*)((char*)Ah + off) = uh;
            *(uint4*)((char*)Al + off) = ul;
        }
    }
    __syncthreads();
    int w = tid >> 6, lane = tid & 63;
    int l15 = lane & 15, l4 = lane >> 4;
    const unsigned short* Bh = Lhi + (size_t)(w * 32 + l15) * 256 + l4 * 8;
    const unsigned short* Bl = Llo + (size_t)(w * 32 + l15) * 256 + l4 * 8;
    f32x4 acc[4][2];
    #pragma unroll
    for (int m = 0; m < 4; ++m) { acc[m][0] = (f32x4){0.f,0.f,0.f,0.f}; acc[m][1] = (f32x4){0.f,0.f,0.f,0.f}; }
    #pragma unroll
    for (int k = 0; k < 8; ++k) {
        bf16x8 ah[4], al[4];
        #pragma unroll
        for (int m = 0; m < 4; ++m) {
            int row = m * 16 + l15;
            unsigned off = ((unsigned)row * 512 + k * 64 + l4 * 16) ^ ((unsigned)(row & 7) << 4);
            ah[m] = *(const bf16x8*)((const char*)Ah + off);
            al[m] = *(const bf16x8*)((const char*)Al + off);
        }
        #pragma unroll
        for (int n = 0; n < 2; ++n) {
            bf16x8 bh = *(const bf16x8*)(Bh + (size_t)n * 16 * 256 + k * 32);
            bf16x8 bl = *(const bf16x8*)(Bl + (size_t)n * 16 * 256 + k * 32);
            #pragma unroll
            for (int m = 0; m < 4; ++m) {
                acc[m][n] = __builtin_amdgcn_mfma_f32_16x16x32_bf16(ah[m], bh, acc[m][n], 0, 0, 0);
                acc[m][n] = __builtin_amdgcn_mfma_f32_16x16x32_bf16(ah[m], bl, acc[m][n], 0, 0, 0);
                acc[m][n] = __builtin_amdgcn_mfma_f32_16x16x32_bf16(al[m], bh, acc[m][n], 0, 0, 0);
            }
        }
    }
    int col0 = w * 32 + l15;
    float lb_0 = lb1[col0], lb_1 = lb1[col0 + 16];
    float lwa = lw2[col0], lwb = lw2[col0 + 16];
    #pragma unroll
    for (int m = 0; m < 4; ++m) {
        #pragma unroll
        for (int rg = 0; rg < 4; ++rg) {
            float h0 = acc[m][0][rg] + lb_0; h0 = h0 > 0.f ? h0 : 0.f;
            float h1 = acc[m][1][rg] + lb_1; h1 = h1 > 0.f ? h1 : 0.f;
            float s = h0 * lwa + h1 * lwb;
            s += __shfl_xor(s, 1); s += __shfl_xor(s, 2);
            s += __shfl_xor(s, 4); s += __shfl_xor(s, 8);
            if (l15 == 0) red[m * 16 + l4 * 4 + rg][w] = s;
        }
    }
    __syncthreads();
    if (tid < cnt) out[t0 + tid] = red[tid][0] + red[tid][1] + red[tid][2] + red[tid][3] + lb2[0];
}

extern "C" void kernel_launch(void* const* d_in, const int* in_sizes, int n_in,
                              void* d_out, int out_size, void* d_ws, size_t ws_size,
                              hipStream_t stream) {
    const float* x   = (const float*)d_in[0];
    const int*   ei  = (const int*)d_in[1];
    const int*   et  = (const int*)d_in[2];
    const int*   tgt = (const int*)d_in[3];
    const float* W1  = (const float*)d_in[4];
    const float* aq1 = (const float*)d_in[5];
    const float* ak1 = (const float*)d_in[6];
    const float* W2  = (const float*)d_in[7];
    const float* aq2 = (const float*)d_in[8];
    const float* ak2 = (const float*)d_in[9];
    const float* lw1 = (const float*)d_in[10];
    const float* lb1 = (const float*)d_in[11];
    const float* lw2 = (const float*)d_in[12];
    const float* lb2 = (const float*)d_in[13];
    float* out = (float*)d_out;
    (void)in_sizes; (void)n_in; (void)out_size; (void)ws_size;

    char* ws = (char*)d_ws;
    size_t off = 0;
    auto alloc = [&](size_t bytes) -> void* {
        void* p = ws + off;
        off += (bytes + 255) & ~(size_t)255;
        return p;
    };
    // zero-init block: histograms only
    int* cnt   = (int*)alloc(NBUCKET * sizeof(int));
    int* cnt_d = (int*)alloc((size_t)NN * sizeof(int));
    size_t zero_bytes = off;
    // no-init scratch
    int*   boffs    = (int*)alloc((NBUCKET + 1) * sizeof(int));
    int*   cursor   = (int*)alloc(NBUCKET * sizeof(int));
    int*   cts      = (int*)alloc((CHUNKS + 1) * sizeof(int));
    int*   doffs    = (int*)alloc((size_t)(NN + 1) * sizeof(int));
    int*   cursor_d = (int*)alloc((size_t)NN * sizeof(int));
    int*   border   = (int*)alloc((size_t)NE * sizeof(int));
    int*   dlist    = (int*)alloc((size_t)NE * sizeof(int));
    int*   dedge    = (int*)alloc((size_t)NE * sizeof(int));
    int*   dsr      = (int*)alloc((size_t)NE * sizeof(int));
    int*   tile_b   = (int*)alloc((size_t)NTILESMAX1 * sizeof(int));
    int*   tile_s   = (int*)alloc((size_t)NTILESMAX1 * sizeof(int));
    float* alpha2   = (float*)alloc((size_t)512 * 32 * 4);
    float* qk2v     = (float*)alloc((size_t)NN * 32 * 4);
    float* e2       = (float*)alloc((size_t)NE * 4);
    float* zacc     = (float*)alloc((size_t)NN * DOUT * 4);
    unsigned short* xhi   = (unsigned short*)alloc((size_t)NN * DIN * 2);
    unsigned short* xlo   = (unsigned short*)alloc((size_t)NN * DIN * 2);
    unsigned short* hhi   = (unsigned short*)alloc((size_t)NN * DH * 2);
    unsigned short* hlo   = (unsigned short*)alloc((size_t)NN * DH * 2);
    unsigned short* W1Thi = (unsigned short*)alloc((size_t)NR * DH * DIN * 2);
    unsigned short* W1Tlo = (unsigned short*)alloc((size_t)NR * DH * DIN * 2);
    unsigned short* W2Thi = (unsigned short*)alloc((size_t)NR * DOUT * DH * 2);
    unsigned short* W2Tlo = (unsigned short*)alloc((size_t)NR * DOUT * DH * 2);
    unsigned short* Lhi   = (unsigned short*)alloc((size_t)128 * 256 * 2);
    unsigned short* Llo   = (unsigned short*)alloc((size_t)128 * 256 * 2);
    // region R (82 MB): msgu (l1 phase, 47.2 MB) then reused as dense Y2 table.
    // alpha1/qk1/e1 alias R's tail — all dead before y2_gemm writes R.
    char* msgr = (char*)alloc((size_t)NN * 1024 * 4);               // 81,920,000 B
    unsigned* msgu = (unsigned*)msgr;
    unsigned* Y2u  = (unsigned*)msgr;
    float* alpha1 = (float*)(msgr + (size_t)MSGROWS * 256 * 4);     // +47,185,920
    float* qk1    = alpha1 + 128 * 256;
    float* e1     = qk1 + (size_t)NN * 256;                         // ends ~78.0 MB < 81.9 MB

    hipMemsetAsync(ws, 0, zero_bytes, stream);
    alpha1_kernel<<<DIN, 256, 0, stream>>>(W1, aq1, ak1, alpha1);
    alpha2_kernel<<<(DH * 32 + 255) / 256, 256, 0, stream>>>(W2, aq2, ak2, alpha2);
    split_x_kernel<<<(NN * DIN / 4 + 255) / 256, 256, 0, stream>>>(x, xhi, xlo);
    splitW1T_kernel<<<NR * 8, 256, 0, stream>>>(W1, W1Thi, W1Tlo);
    splitW2T_kernel<<<NR * 2, 256, 0, stream>>>(W2, W2Thi, W2Tlo);
    splitLw1_kernel<<<(256 * 128 + 255) / 256, 256, 0, stream>>>(lw1, Lhi, Llo);
    hist_kernel<<<(NE + 255) / 256, 256, 0, stream>>>(ei, et, cnt, cnt_d);
    scan_bkt_kernel<<<1, 64, 0, stream>>>(cnt, boffs, cursor, cts);
    tilemap_kernel<<<(NTILESMAX1 + 255) / 256, 256, 0, stream>>>(boffs, tile_b, tile_s);
    bucket_place_kernel<<<(NE + 255) / 256, 256, 0, stream>>>(ei, et, cursor, border);
    scan_dst_kernel<<<1, 1024, 0, stream>>>(cnt_d, doffs, cursor_d);
    place_dst_kernel<<<(NE + 255) / 256, 256, 0, stream>>>(border, ei, et, cursor_d, dlist, dedge, dsr);
    qk1_kernel<<<(NN + TILE - 1) / TILE, 256, 0, stream>>>(x, alpha1, qk1);
    elogit1_kernel<<<(NE + 255) / 256, 256, 0, stream>>>(ei, et, qk1, e1);
    for (int c = 0; c < CHUNKS; ++c) {
        l1_gemm_kernel<<<MAXTPC1, 256, 0, stream>>>(xhi, xlo, W1Thi, W1Tlo, ei, border,
                                                    tile_b, tile_s, boffs, cts, c, msgu);
        l1_agg_kernel<<<CHD, 256, 0, stream>>>(msgu, e1, dlist, dedge, doffs, boffs, c,
                                               hhi, hlo, alpha2, qk2v);
    }
    elogit2_kernel<<<(NE + 255) / 256, 256, 0, stream>>>(ei, et, qk2v, e2);
    y2_gemm_kernel<<<YGRID, 256, 0, stream>>>(hhi, hlo, W2Thi, W2Tlo, Y2u);
    l2_agg_kernel<<<(NN + 3) / 4, 256, 0, stream>>>(Y2u, e2, dedge, dsr, doffs, zacc);
    decode_kernel<<<(NT + TILE - 1) / TILE, 256, 0, stream>>>(zacc, tgt, Lhi, Llo,
                                                              lb1, lw2, lb2, out);
}

// Round 10
// 769.625 us; speedup vs baseline: 1.5836x; 1.1278x over previous
//
#include <hip/hip_runtime.h>
#include <cstdint>
#include <cstddef>

#define NN     20000
#define NE     320000
#define NR     16
#define DIN    128
#define DH     512
#define DOUT   128
#define NT     50000
#define TILE   64                      // qk1/decode row tile
#define TILE1  128                     // layer-1 edge tile
#define CHUNKS 8
#define CHD    2500
#define NBUCKET (CHUNKS * NR)          // 128
#define MSGROWS 46080                  // max edges per chunk
#define MAXTPC1 1536                   // l1 grid per chunk (8*192)
#define NTILESMAX1 (NE / TILE1 + NBUCKET)
#define MT2Y   157                     // ceil(20000/128)
#define YGRID  (MT2Y * 16)             // 2512 = 8*314

typedef __attribute__((ext_vector_type(8))) short bf16x8;
typedef __attribute__((ext_vector_type(4))) float f32x4;

__device__ __forceinline__ unsigned short f2bf(float x) {
    unsigned int b = __float_as_uint(x);
    b = b + 0x7fffu + ((b >> 16) & 1u);
    return (unsigned short)(b >> 16);
}
__device__ __forceinline__ float bf2f(unsigned short u) {
    return __uint_as_float(((unsigned int)u) << 16);
}
__device__ __forceinline__ unsigned packbf(float lo, float hi) {
    return (unsigned)f2bf(lo) | ((unsigned)f2bf(hi) << 16);
}

// ---------------- fold attention vectors into weights ----------------
__global__ void alpha1_kernel(const float* __restrict__ W1, const float* __restrict__ aq1,
                              const float* __restrict__ ak1, float* __restrict__ alpha1) {
    int i = blockIdx.x;
    int c = threadIdx.x;
    int r = c >> 4, s = (c >> 3) & 1, h = c & 7;
    const float* att = (s == 0 ? aq1 : ak1) + (r * 8 + h) * 64;
    const float* w = W1 + ((size_t)(r * DIN + i)) * DH + h * 64;
    float acc = 0.f;
    #pragma unroll 8
    for (int o = 0; o < 64; ++o) acc += w[o] * att[o];
    alpha1[i * 256 + c] = acc;
}

__global__ void alpha2_kernel(const float* __restrict__ W2, const float* __restrict__ aq2,
                              const float* __restrict__ ak2, float* __restrict__ alpha2) {
    int g = blockIdx.x * blockDim.x + threadIdx.x;
    if (g >= DH * 32) return;
    int i = g >> 5, c = g & 31;
    int r = c >> 1, s = c & 1;
    const float* att = (s == 0 ? aq2 : ak2) + r * DOUT;
    const float* w = W2 + ((size_t)(r * DH + i)) * DOUT;
    float acc = 0.f;
    #pragma unroll 8
    for (int o = 0; o < DOUT; ++o) acc += w[o] * att[o];
    alpha2[i * 32 + c] = acc;
}

// ---------------- bf16 hi/lo precompute ----------------
__global__ void split_x_kernel(const float* __restrict__ x, unsigned short* __restrict__ xhi,
                               unsigned short* __restrict__ xlo) {
    int g = blockIdx.x * 256 + threadIdx.x;
    if (g >= NN * DIN / 4) return;
    float4 v = ((const float4*)x)[g];
    ushort4 h, l;
    h.x = f2bf(v.x); l.x = f2bf(v.x - bf2f(h.x));
    h.y = f2bf(v.y); l.y = f2bf(v.y - bf2f(h.y));
    h.z = f2bf(v.z); l.z = f2bf(v.z - bf2f(h.z));
    h.w = f2bf(v.w); l.w = f2bf(v.w - bf2f(h.w));
    ((ushort4*)xhi)[g] = h;
    ((ushort4*)xlo)[g] = l;
}

// W1 [16][128][512] -> W1T hi [16][512][128]  (bf16 only; x carries the residual)
__global__ void splitW1T_kernel(const float* __restrict__ W1, unsigned short* __restrict__ Whi) {
    __shared__ float T[128 * 65];
    int r = blockIdx.x >> 3;
    int ob = blockIdx.x & 7;
    int tid = threadIdx.x;
    for (int idx = tid; idx < 128 * 64; idx += 256) {
        int i = idx >> 6, o = idx & 63;
        T[i * 65 + o] = W1[((size_t)(r * DIN + i)) * DH + ob * 64 + o];
    }
    __syncthreads();
    for (int idx = tid; idx < 64 * 128; idx += 256) {
        int o = idx >> 7, i = idx & 127;
        Whi[((size_t)r * DH + ob * 64 + o) * DIN + i] = f2bf(T[i * 65 + o]);
    }
}

// W2 [16][512][128] -> W2T hi [16][128][512]
__global__ void splitW2T_kernel(const float* __restrict__ W2, unsigned short* __restrict__ Whi) {
    __shared__ float T[128 * 65];
    int r = blockIdx.x >> 1;
    int ob = blockIdx.x & 1;
    int tid = threadIdx.x;
    for (int kc = 0; kc < 4; ++kc) {
        if (kc) __syncthreads();
        for (int idx = tid; idx < 128 * 64; idx += 256) {
            int k = idx >> 6, o = idx & 63;
            T[k * 65 + o] = W2[((size_t)(r * DH + kc * 128 + k)) * DOUT + ob * 64 + o];
        }
        __syncthreads();
        for (int idx = tid; idx < 64 * 128; idx += 256) {
            int o = idx >> 7, k = idx & 127;
            Whi[((size_t)r * DOUT + ob * 64 + o) * DH + kc * 128 + k] = f2bf(T[k * 65 + o]);
        }
    }
}

__global__ void splitLw1_kernel(const float* __restrict__ lw1, unsigned short* __restrict__ Lhi,
                                unsigned short* __restrict__ Llo) {
    int g = blockIdx.x * 256 + threadIdx.x;
    if (g >= 256 * 128) return;
    int o = g >> 8, k = g & 255;
    float v = lw1[k * 128 + o];
    unsigned short h = f2bf(v);
    Lhi[(size_t)o * 256 + k] = h;
    Llo[(size_t)o * 256 + k] = f2bf(v - bf2f(h));
}

// ---------------- sorts ----------------
__global__ void hist_kernel(const int* __restrict__ ei, const int* __restrict__ et,
                            int* __restrict__ cnt, int* __restrict__ cnt_d) {
    __shared__ int bins[NBUCKET];
    int t = threadIdx.x;
    if (t < NBUCKET) bins[t] = 0;
    __syncthreads();
    int e = blockIdx.x * 256 + t;
    if (e < NE) {
        int d = ei[NE + e];
        int key = (d / CHD) * NR + et[e];
        atomicAdd(&bins[key], 1);
        atomicAdd(&cnt_d[d], 1);
    }
    __syncthreads();
    if (t < NBUCKET && bins[t]) atomicAdd(&cnt[t], bins[t]);
}

__global__ void scan_bkt_kernel(const int* __restrict__ cnt, int* __restrict__ boffs,
                                int* __restrict__ cursor, int* __restrict__ cts) {
    if (threadIdx.x != 0) return;
    int acc = 0, tiles = 0;
    for (int b = 0; b < NBUCKET; ++b) {
        if ((b & (NR - 1)) == 0) cts[b >> 4] = tiles;
        boffs[b] = acc; cursor[b] = acc;
        int cn = cnt[b];
        tiles += (cn + TILE1 - 1) / TILE1;
        acc += cn;
    }
    boffs[NBUCKET] = acc; cts[CHUNKS] = tiles;
}

__global__ void tilemap_kernel(const int* __restrict__ boffs, int* __restrict__ tile_b,
                               int* __restrict__ tile_s) {
    __shared__ int bo[NBUCKET + 1];
    int tid = threadIdx.x;
    if (tid <= NBUCKET) bo[tid] = boffs[tid];
    __syncthreads();
    int t = blockIdx.x * 256 + tid;
    if (t >= NTILESMAX1) return;
    int acc = 0, bb = -1, ss = 0;
    for (int b = 0; b < NBUCKET; ++b) {
        int cn = bo[b + 1] - bo[b];
        int nt = (cn + TILE1 - 1) / TILE1;
        if (t >= acc && t < acc + nt) { bb = b; ss = bo[b] + (t - acc) * TILE1; }
        acc += nt;
    }
    tile_b[t] = bb; tile_s[t] = ss;
}

__global__ void bucket_place_kernel(const int* __restrict__ ei, const int* __restrict__ et,
                                    int* __restrict__ cursor, int* __restrict__ border) {
    __shared__ int binc[NBUCKET], base_[NBUCKET], rank_[NBUCKET];
    int t = threadIdx.x;
    if (t < NBUCKET) { binc[t] = 0; rank_[t] = 0; }
    __syncthreads();
    int e = blockIdx.x * 256 + t;
    int key = -1;
    if (e < NE) { key = (ei[NE + e] / CHD) * NR + et[e]; atomicAdd(&binc[key], 1); }
    __syncthreads();
    if (t < NBUCKET && binc[t]) base_[t] = atomicAdd(&cursor[t], binc[t]);
    __syncthreads();
    if (key >= 0) border[base_[key] + atomicAdd(&rank_[key], 1)] = e;
}

__global__ void scan_dst_kernel(const int* __restrict__ cnt_d, int* __restrict__ doffs,
                                int* __restrict__ cursor_d) {
    __shared__ int part[1024];
    int t = threadIdx.x;
    int base = t * 20;
    int s = 0;
    for (int i = 0; i < 20 && base + i < NN; ++i) s += cnt_d[base + i];
    part[t] = s;
    __syncthreads();
    for (int off = 1; off < 1024; off <<= 1) {
        int v = (t >= off) ? part[t - off] : 0;
        __syncthreads();
        part[t] += v;
        __syncthreads();
    }
    int run = part[t] - s;
    for (int i = 0; i < 20 && base + i < NN; ++i) {
        doffs[base + i] = run; cursor_d[base + i] = run;
        run += cnt_d[base + i];
    }
    if (t == 1023) doffs[NN] = part[1023];
}

__global__ void place_dst_kernel(const int* __restrict__ border, const int* __restrict__ ei,
                                 const int* __restrict__ et, int* __restrict__ cursor_d,
                                 int* __restrict__ dlist, int* __restrict__ dedge,
                                 int* __restrict__ dsr) {
    int pos = blockIdx.x * 256 + threadIdx.x;
    if (pos >= NE) return;
    int e = border[pos];
    int d = ei[NE + e];
    int idx = atomicAdd(&cursor_d[d], 1);
    dlist[idx] = pos;
    dedge[idx] = e;
    dsr[idx] = ei[e] * NR + et[e];
}

// ---------------- qk1 = x @ alpha1 ----------------
__global__ void qk1_kernel(const float* __restrict__ x, const float* __restrict__ alpha1,
                           float* __restrict__ qk1) {
    __shared__ float Xt[TILE][DIN + 1];
    int n0 = blockIdx.x * TILE;
    int tid = threadIdx.x;
    for (int idx = tid; idx < TILE * DIN; idx += 256) {
        int row = idx >> 7, i = idx & 127;
        int n = n0 + row;
        Xt[row][i] = (n < NN) ? x[(size_t)n * DIN + i] : 0.f;
    }
    __syncthreads();
    int to = tid >> 4, te = tid & 15;
    for (int c = 0; c < 2; ++c) {
        float acc[4][8] = {};
        const float* Wp = alpha1 + c * 128 + to * 8;
        for (int i = 0; i < DIN; ++i) {
            float4 w0 = *(const float4*)(Wp + (size_t)i * 256);
            float4 w1 = *(const float4*)(Wp + (size_t)i * 256 + 4);
            float w[8] = {w0.x, w0.y, w0.z, w0.w, w1.x, w1.y, w1.z, w1.w};
            #pragma unroll
            for (int a = 0; a < 4; ++a) {
                float xv = Xt[te * 4 + a][i];
                #pragma unroll
                for (int b = 0; b < 8; ++b) acc[a][b] += xv * w[b];
            }
        }
        #pragma unroll
        for (int a = 0; a < 4; ++a) {
            int n = n0 + te * 4 + a;
            if (n < NN) {
                float* op = qk1 + (size_t)n * 256 + c * 128 + to * 8;
                #pragma unroll
                for (int b = 0; b < 8; ++b) op[b] = acc[a][b];
            }
        }
    }
}

__global__ void elogit1_kernel(const int* __restrict__ ei, const int* __restrict__ et,
                               const float* __restrict__ qk1, float* __restrict__ e1) {
    int e = blockIdx.x * blockDim.x + threadIdx.x;
    if (e >= NE) return;
    int src = ei[e], dst = ei[NE + e], r = et[e];
    const float* qp = qk1 + (size_t)dst * 256 + r * 16;
    const float* kp = qk1 + (size_t)src * 256 + r * 16 + 8;
    float* ep = e1 + (size_t)e * 8;
    #pragma unroll
    for (int h = 0; h < 8; ++h) {
        float l = qp[h] + kp[h];
        l = l > 0.f ? l : 0.2f * l;
        ep[h] = __expf(l);
    }
}

// ---------------- layer1 GEMM: 128x128 tiles, A(hi,lo)+B(hi) in LDS, 2 MFMA/product ----------------
__global__ __launch_bounds__(256, 3)
void l1_gemm_kernel(const unsigned short* __restrict__ xhi, const unsigned short* __restrict__ xlo,
                    const unsigned short* __restrict__ W1Thi,
                    const int* __restrict__ ei, const int* __restrict__ border,
                    const int* __restrict__ tile_b, const int* __restrict__ tile_s,
                    const int* __restrict__ boffs, const int* __restrict__ cts,
                    int c, unsigned* __restrict__ msgu) {
    int wg = (blockIdx.x & 7) * (MAXTPC1 / 8) + (blockIdx.x >> 3);   // XCD-contiguous
    int tt = wg >> 2, cb = wg & 3;
    int t = cts[c] + tt;
    if (t >= cts[c + 1]) return;
    int b = tile_b[t];
    int r = b & (NR - 1);
    int start = tile_s[t];
    int cstart = boffs[c * NR];
    int cnt = boffs[b + 1] - start; if (cnt > TILE1) cnt = TILE1;
    __shared__ __align__(16) unsigned short Ah[128 * 64];
    __shared__ __align__(16) unsigned short Al[128 * 64];
    __shared__ __align__(16) unsigned short Bh_[128 * 64];
    __shared__ int srcS[TILE1];
    int tid = threadIdx.x;
    if (tid < TILE1) {
        int sv = 0;
        if (tid < cnt) sv = ei[border[start + tid]];
        srcS[tid] = sv;
    }
    __syncthreads();
    int w = tid >> 6, lane = tid & 63;
    int l15 = lane & 15, l4 = lane >> 4;
    int wr = w >> 1, wc = w & 1;
    f32x4 acc[4][4];
    #pragma unroll
    for (int m = 0; m < 4; ++m)
        #pragma unroll
        for (int n = 0; n < 4; ++n) acc[m][n] = (f32x4){0.f, 0.f, 0.f, 0.f};
    for (int kc = 0; kc < 2; ++kc) {            // K = 128, BK = 64
        if (kc) __syncthreads();
        {
            int row = tid >> 1, seg = tid & 1;
            unsigned rb = row * 128, sw = (row & 7) << 4;
            const uint4* ph = (const uint4*)(xhi + (size_t)srcS[row] * DIN + kc * 64 + seg * 32);
            const uint4* pl = (const uint4*)(xlo + (size_t)srcS[row] * DIN + kc * 64 + seg * 32);
            const uint4* qh = (const uint4*)(W1Thi + ((size_t)r * DH + cb * 128 + row) * DIN + kc * 64 + seg * 32);
            #pragma unroll
            for (int i = 0; i < 4; ++i) {
                unsigned off = (rb + seg * 64 + i * 16) ^ sw;
                *(uint4*)((char*)Ah + off) = ph[i];
                *(uint4*)((char*)Al + off) = pl[i];
                *(uint4*)((char*)Bh_ + off) = qh[i];
            }
        }
        __syncthreads();
        bf16x8 ah[4][2], al[4][2], bh[4][2];
        #pragma unroll
        for (int m = 0; m < 4; ++m) {
            int row = wr * 64 + m * 16 + l15;
            unsigned rb = row * 128, sw = (row & 7) << 4;
            #pragma unroll
            for (int ks = 0; ks < 2; ++ks) {
                unsigned off = (rb + ks * 64 + l4 * 16) ^ sw;
                ah[m][ks] = *(const bf16x8*)((const char*)Ah + off);
                al[m][ks] = *(const bf16x8*)((const char*)Al + off);
            }
        }
        #pragma unroll
        for (int n = 0; n < 4; ++n) {
            int col = wc * 64 + n * 16 + l15;
            unsigned rb = col * 128, sw = (col & 7) << 4;
            #pragma unroll
            for (int ks = 0; ks < 2; ++ks) {
                unsigned off = (rb + ks * 64 + l4 * 16) ^ sw;
                bh[n][ks] = *(const bf16x8*)((const char*)Bh_ + off);
            }
        }
        #pragma unroll
        for (int n = 0; n < 4; ++n)
            #pragma unroll
            for (int ks = 0; ks < 2; ++ks)
                #pragma unroll
                for (int m = 0; m < 4; ++m) {
                    acc[m][n] = __builtin_amdgcn_mfma_f32_16x16x32_bf16(ah[m][ks], bh[n][ks], acc[m][n], 0, 0, 0);
                    acc[m][n] = __builtin_amdgcn_mfma_f32_16x16x32_bf16(al[m][ks], bh[n][ks], acc[m][n], 0, 0, 0);
                }
    }
    unsigned* mb = msgu + (size_t)(start - cstart) * 256 + cb * 64 + wc * 32 + l15;
    #pragma unroll
    for (int m = 0; m < 4; ++m) {
        int row0 = wr * 64 + m * 16 + l4 * 4;
        #pragma unroll
        for (int rg = 0; rg < 4; ++rg) {
            int row = row0 + rg;
            if (row < cnt) {
                unsigned* mp = mb + (size_t)row * 256;
                mp[0]  = packbf(acc[m][0][rg], acc[m][2][rg]);
                mp[16] = packbf(acc[m][1][rg], acc[m][3][rg]);
            }
        }
    }
}

// ---------------- layer1 agg (fused qk2) ----------------
__global__ void l1_agg_kernel(const unsigned* __restrict__ msgu, const float* __restrict__ e1,
                              const int* __restrict__ dlist, const int* __restrict__ dedge,
                              const int* __restrict__ doffs, const int* __restrict__ boffs,
                              int c, unsigned short* __restrict__ hhi, unsigned short* __restrict__ hlo,
                              const float* __restrict__ alpha2, float* __restrict__ qk2v) {
    __shared__ float hrow[DH];
    __shared__ float red[32][9];
    int tid = threadIdx.x;
    int d = c * CHD + blockIdx.x;
    int lo_ = doffs[d], hi_ = doffs[d + 1];
    int cstart = boffs[c * NR];
    int head = tid >> 5;
    float a0 = 0.f, a1 = 0.f, se = 0.f;
    for (int p = lo_; p < hi_; ++p) {
        int pos = dlist[p];
        float wgt = e1[(size_t)dedge[p] * 8 + head];
        se += wgt;
        unsigned v = msgu[(size_t)(pos - cstart) * 256 + tid];
        a0 += wgt * bf2f((unsigned short)(v & 0xffff));
        a1 += wgt * bf2f((unsigned short)(v >> 16));
    }
    float inv = 1.f / (se + 1e-16f);
    a0 *= inv; a1 *= inv;
    a0 = a0 > 0.f ? a0 : 0.f;
    a1 = a1 > 0.f ? a1 : 0.f;
    int w = tid >> 6, q = (tid >> 4) & 3, l15 = tid & 15;
    int nq = ((q >> 1) << 2) | (q & 1);
    int c0 = w * 128 + nq * 16 + l15;
    hrow[c0] = a0; hrow[c0 + 32] = a1;
    unsigned short h0 = f2bf(a0), h1 = f2bf(a1);
    hhi[(size_t)d * DH + c0] = h0;
    hlo[(size_t)d * DH + c0] = f2bf(a0 - bf2f(h0));
    hhi[(size_t)d * DH + c0 + 32] = h1;
    hlo[(size_t)d * DH + c0 + 32] = f2bf(a1 - bf2f(h1));
    __syncthreads();
    int j = tid & 31, ib = tid >> 5;
    float s = 0.f;
    #pragma unroll 8
    for (int i = ib * 64; i < ib * 64 + 64; ++i) s += hrow[i] * alpha2[(size_t)i * 32 + j];
    red[j][ib] = s;
    __syncthreads();
    if (tid < 32) {
        float t = 0.f;
        #pragma unroll
        for (int g = 0; g < 8; ++g) t += red[tid][g];
        qk2v[(size_t)d * 32 + tid] = t;
    }
}

__global__ void elogit2_kernel(const int* __restrict__ ei, const int* __restrict__ et,
                               const float* __restrict__ qk2, float* __restrict__ e2) {
    int e = blockIdx.x * blockDim.x + threadIdx.x;
    if (e >= NE) return;
    int src = ei[e], dst = ei[NE + e], r = et[e];
    float l = qk2[(size_t)dst * 32 + r * 2] + qk2[(size_t)src * 32 + r * 2 + 1];
    l = l > 0.f ? l : 0.2f * l;
    e2[e] = __expf(l);
}

// ---------------- dense Y2 = H @ W2_all : 128x128 tiles, A(hi,lo)+B(hi), 2 MFMA ----------------
__global__ __launch_bounds__(256, 3)
void y2_gemm_kernel(const unsigned short* __restrict__ hhi, const unsigned short* __restrict__ hlo,
                    const unsigned short* __restrict__ W2Thi,
                    unsigned* __restrict__ Y2u) {
    int t = (blockIdx.x & 7) * (YGRID / 8) + (blockIdx.x >> 3);   // XCD-contiguous
    int mt = t >> 4, r = t & 15;
    int n0 = mt * 128;
    __shared__ __align__(16) unsigned short Ah[128 * 64];
    __shared__ __align__(16) unsigned short Al[128 * 64];
    __shared__ __align__(16) unsigned short Bh_[128 * 64];
    int tid = threadIdx.x;
    int w = tid >> 6, lane = tid & 63;
    int l15 = lane & 15, l4 = lane >> 4;
    int wr = w >> 1, wc = w & 1;
    f32x4 acc[4][4];
    #pragma unroll
    for (int m = 0; m < 4; ++m)
        #pragma unroll
        for (int n = 0; n < 4; ++n) acc[m][n] = (f32x4){0.f, 0.f, 0.f, 0.f};
    for (int kc = 0; kc < 8; ++kc) {            // K = 512, BK = 64
        if (kc) __syncthreads();
        {
            int row = tid >> 1, seg = tid & 1;
            int n = n0 + row; if (n >= NN) n = NN - 1;
            unsigned rb = row * 128, sw = (row & 7) << 4;
            const uint4* ph = (const uint4*)(hhi + (size_t)n * DH + kc * 64 + seg * 32);
            const uint4* pl = (const uint4*)(hlo + (size_t)n * DH + kc * 64 + seg * 32);
            const uint4* qh = (const uint4*)(W2Thi + ((size_t)r * DOUT + row) * DH + kc * 64 + seg * 32);
            #pragma unroll
            for (int i = 0; i < 4; ++i) {
                unsigned off = (rb + seg * 64 + i * 16) ^ sw;
                *(uint4*)((char*)Ah + off) = ph[i];
                *(uint4*)((char*)Al + off) = pl[i];
                *(uint4*)((char*)Bh_ + off) = qh[i];
            }
        }
        __syncthreads();
        bf16x8 ah[4][2], al[4][2], bh[4][2];
        #pragma unroll
        for (int m = 0; m < 4; ++m) {
            int row = wr * 64 + m * 16 + l15;
            unsigned rb = row * 128, sw = (row & 7) << 4;
            #pragma unroll
            for (int ks = 0; ks < 2; ++ks) {
                unsigned off = (rb + ks * 64 + l4 * 16) ^ sw;
                ah[m][ks] = *(const bf16x8*)((const char*)Ah + off);
                al[m][ks] = *(const bf16x8*)((const char*)Al + off);
            }
        }
        #pragma unroll
        for (int n = 0; n < 4; ++n) {
            int col = wc * 64 + n * 16 + l15;
            unsigned rb = col * 128, sw = (col & 7) << 4;
            #pragma unroll
            for (int ks = 0; ks < 2; ++ks) {
                unsigned off = (rb + ks * 64 + l4 * 16) ^ sw;
                bh[n][ks] = *(const bf16x8*)((const char*)Bh_ + off);
            }
        }
        #pragma unroll
        for (int n = 0; n < 4; ++n)
            #pragma unroll
            for (int ks = 0; ks < 2; ++ks)
                #pragma unroll
                for (int m = 0; m < 4; ++m) {
                    acc[m][n] = __builtin_amdgcn_mfma_f32_16x16x32_bf16(ah[m][ks], bh[n][ks], acc[m][n], 0, 0, 0);
                    acc[m][n] = __builtin_amdgcn_mfma_f32_16x16x32_bf16(al[m][ks], bh[n][ks], acc[m][n], 0, 0, 0);
                }
    }
    unsigned* mb = Y2u + (size_t)n0 * 1024 + r * 64 + wc * 32 + l15;
    #pragma unroll
    for (int m = 0; m < 4; ++m) {
        int row0 = wr * 64 + m * 16 + l4 * 4;
        #pragma unroll
        for (int rg = 0; rg < 4; ++rg) {
            int row = row0 + rg;
            if (n0 + row < NN) {
                unsigned* mp = mb + (size_t)row * 1024;
                mp[0]  = packbf(acc[m][0][rg], acc[m][2][rg]);
                mp[16] = packbf(acc[m][1][rg], acc[m][3][rg]);
            }
        }
    }
}

// ---------------- layer2 agg: gather Y2[src*16+r] rows per dst ----------------
__global__ void l2_agg_kernel(const unsigned* __restrict__ Y2u, const float* __restrict__ e2,
                              const int* __restrict__ dedge, const int* __restrict__ dsr,
                              const int* __restrict__ doffs, float* __restrict__ zacc) {
    int tid = threadIdx.x;
    int d = blockIdx.x * 4 + (tid >> 6);
    if (d >= NN) return;
    int lane = tid & 63;
    int lo_ = doffs[d], hi_ = doffs[d + 1];
    float a0 = 0.f, a1 = 0.f, se = 0.f;
    for (int p = lo_; p < hi_; ++p) {
        float wgt = e2[dedge[p]];
        se += wgt;
        unsigned v = Y2u[(size_t)dsr[p] * 64 + lane];
        a0 += wgt * bf2f((unsigned short)(v & 0xffff));
        a1 += wgt * bf2f((unsigned short)(v >> 16));
    }
    float inv = 1.f / (se + 1e-16f);
    int q = lane >> 4, l15 = lane & 15;
    int nq = ((q >> 1) << 2) | (q & 1);
    int c0 = nq * 16 + l15;
    zacc[(size_t)d * DOUT + c0] = a0 * inv;
    zacc[(size_t)d * DOUT + c0 + 32] = a1 * inv;
}

// ---------------- link-prediction decoder (MFMA, split bf16, full 3-term) ----------------
__global__ __launch_bounds__(256, 2)
void decode_kernel(const float* __restrict__ z, const int* __restrict__ tgt,
                   const unsigned short* __restrict__ Lhi, const unsigned short* __restrict__ Llo,
                   const float* __restrict__ lb1, const float* __restrict__ lw2,
                   const float* __restrict__ lb2, float* __restrict__ out) {
    __shared__ __align__(16) unsigned short Ah[64 * 256];
    __shared__ __align__(16) unsigned short Al[64 * 256];
    __shared__ float red[TILE][5];
    int t0 = blockIdx.x * TILE;
    int tid = threadIdx.x;
    int cnt = NT - t0; if (cnt > TILE) cnt = TILE;
    {
        int row = tid >> 2, seg = tid & 3;
        int node = 0;
        bool live = (row < cnt);
        if (live) node = tgt[(seg >> 1) * NT + t0 + row];
        const float4* pz = (const float4*)(z + (size_t)node * DOUT + (seg & 1) * 64);
        unsigned rb = row * 512, sb = (seg >> 1) * 256 + (seg & 1) * 128;
        unsigned sw = (row & 7) << 4;
        #pragma unroll
        for (int g = 0; g < 8; ++g) {
            float4 a = live ? pz[g * 2] : (float4){0,0,0,0};
            float4 bq = live ? pz[g * 2 + 1] : (float4){0,0,0,0};
            unsigned short h0 = f2bf(a.x), h1 = f2bf(a.y), h2 = f2bf(a.z), h3 = f2bf(a.w);
            unsigned short h4 = f2bf(bq.x), h5 = f2bf(bq.y), h6 = f2bf(bq.z), h7 = f2bf(bq.w);
            uint4 uh, ul;
            uh.x = (unsigned)h0 | ((unsigned)h1 << 16);
            uh.y = (unsigned)h2 | ((unsigned)h3 << 16);
            uh.z = (unsigned)h4 | ((unsigned)h5 << 16);
            uh.w = (unsigned)h6 | ((unsigned)h7 << 16);
            ul.x = (unsigned)f2bf(a.x - bf2f(h0)) | ((unsigned)f2bf(a.y - bf2f(h1)) << 16);
            ul.y = (unsigned)f2bf(a.z - bf2f(h2)) | ((unsigned)f2bf(a.w - bf2f(h3)) << 16);
            ul.z = (unsigned)f2bf(bq.x - bf2f(h4)) | ((unsigned)f2bf(bq.y - bf2f(h5)) << 16);
            ul.w = (unsigned)f2bf(bq.z - bf2f(h6)) | ((unsigned)f2bf(bq.w - bf2f(h7)) << 16);
            unsigned off = (rb + sb + g * 16) ^ sw;
            *(uint4*)((char*)Ah + off) = uh;
            *(uint4*)((char*)Al + off) = ul;
        }
    }
    __syncthreads();
    int w = tid >> 6, lane = tid & 63;
    int l15 = lane & 15, l4 = lane >> 4;
    const unsigned short* Bh = Lhi + (size_t)(w * 32 + l15) * 256 + l4 * 8;
    const unsigned short* Bl = Llo + (size_t)(w * 32 + l15) * 256 + l4 * 8;
    f32x4 acc[4][2];
    #pragma unroll
    for (int m = 0; m < 4; ++m) { acc[m][0] = (f32x4){0.f,0.f,0.f,0.f}; acc[m][1] = (f32x4){0.f,0.f,0.f,0.f}; }
    #pragma unroll
    for (int k = 0; k < 8; ++k) {
        bf16x8 ah[4], al[4];
        #pragma unroll
        for (int m = 0; m < 4; ++m) {
            int row = m * 16 + l15;
            unsigned off = ((unsigned)row * 512 + k * 64 + l4 * 16) ^ ((unsigned)(row & 7) << 4);
            ah[m] = *(const bf16x8*)((const char*)Ah + off);
            al[m] = *(const bf16x8*)((const char*)Al + off);
        }
        #pragma unroll
        for (int n = 0; n < 2; ++n) {
            bf16x8 bh = *(const bf16x8*)(Bh + (size_t)n * 16 * 256 + k * 32);
            bf16x8 bl = *(const bf16x8*)(Bl + (size_t)n * 16 * 256 + k * 32);
            #pragma unroll
            for (int m = 0; m < 4; ++m) {
                acc[m][n] = __builtin_amdgcn_mfma_f32_16x16x32_bf16(ah[m], bh, acc[m][n], 0, 0, 0);
                acc[m][n] = __builtin_amdgcn_mfma_f32_16x16x32_bf16(ah[m], bl, acc[m][n], 0, 0, 0);
                acc[m][n] = __builtin_amdgcn_mfma_f32_16x16x32_bf16(al[m], bh, acc[m][n], 0, 0, 0);
            }
        }
    }
    int col0 = w * 32 + l15;
    float lb_0 = lb1[col0], lb_1 = lb1[col0 + 16];
    float lwa = lw2[col0], lwb = lw2[col0 + 16];
    #pragma unroll
    for (int m = 0; m < 4; ++m) {
        #pragma unroll
        for (int rg = 0; rg < 4; ++rg) {
            float h0 = acc[m][0][rg] + lb_0; h0 = h0 > 0.f ? h0 : 0.f;
            float h1 = acc[m][1][rg] + lb_1; h1 = h1 > 0.f ? h1 : 0.f;
            float s = h0 * lwa + h1 * lwb;
            s += __shfl_xor(s, 1); s += __shfl_xor(s, 2);
            s += __shfl_xor(s, 4); s += __shfl_xor(s, 8);
            if (l15 == 0) red[m * 16 + l4 * 4 + rg][w] = s;
        }
    }
    __syncthreads();
    if (tid < cnt) out[t0 + tid] = red[tid][0] + red[tid][1] + red[tid][2] + red[tid][3] + lb2[0];
}

extern "C" void kernel_launch(void* const* d_in, const int* in_sizes, int n_in,
                              void* d_out, int out_size, void* d_ws, size_t ws_size,
                              hipStream_t stream) {
    const float* x   = (const float*)d_in[0];
    const int*   ei  = (const int*)d_in[1];
    const int*   et  = (const int*)d_in[2];
    const int*   tgt = (const int*)d_in[3];
    const float* W1  = (const float*)d_in[4];
    const float* aq1 = (const float*)d_in[5];
    const float* ak1 = (const float*)d_in[6];
    const float* W2  = (const float*)d_in[7];
    const float* aq2 = (const float*)d_in[8];
    const float* ak2 = (const float*)d_in[9];
    const float* lw1 = (const float*)d_in[10];
    const float* lb1 = (const float*)d_in[11];
    const float* lw2 = (const float*)d_in[12];
    const float* lb2 = (const float*)d_in[13];
    float* out = (float*)d_out;
    (void)in_sizes; (void)n_in; (void)out_size; (void)ws_size;

    char* ws = (char*)d_ws;
    size_t off = 0;
    auto alloc = [&](size_t bytes) -> void* {
        void* p = ws + off;
        off += (bytes + 255) & ~(size_t)255;
        return p;
    };
    // zero-init block: histograms only
    int* cnt   = (int*)alloc(NBUCKET * sizeof(int));
    int* cnt_d = (int*)alloc((size_t)NN * sizeof(int));
    size_t zero_bytes = off;
    // no-init scratch
    int*   boffs    = (int*)alloc((NBUCKET + 1) * sizeof(int));
    int*   cursor   = (int*)alloc(NBUCKET * sizeof(int));
    int*   cts      = (int*)alloc((CHUNKS + 1) * sizeof(int));
    int*   doffs    = (int*)alloc((size_t)(NN + 1) * sizeof(int));
    int*   cursor_d = (int*)alloc((size_t)NN * sizeof(int));
    int*   border   = (int*)alloc((size_t)NE * sizeof(int));
    int*   dlist    = (int*)alloc((size_t)NE * sizeof(int));
    int*   dedge    = (int*)alloc((size_t)NE * sizeof(int));
    int*   dsr      = (int*)alloc((size_t)NE * sizeof(int));
    int*   tile_b   = (int*)alloc((size_t)NTILESMAX1 * sizeof(int));
    int*   tile_s   = (int*)alloc((size_t)NTILESMAX1 * sizeof(int));
    float* alpha2   = (float*)alloc((size_t)512 * 32 * 4);
    float* qk2v     = (float*)alloc((size_t)NN * 32 * 4);
    float* e2       = (float*)alloc((size_t)NE * 4);
    float* zacc     = (float*)alloc((size_t)NN * DOUT * 4);
    unsigned short* xhi   = (unsigned short*)alloc((size_t)NN * DIN * 2);
    unsigned short* xlo   = (unsigned short*)alloc((size_t)NN * DIN * 2);
    unsigned short* hhi   = (unsigned short*)alloc((size_t)NN * DH * 2);
    unsigned short* hlo   = (unsigned short*)alloc((size_t)NN * DH * 2);
    unsigned short* W1Thi = (unsigned short*)alloc((size_t)NR * DH * DIN * 2);
    unsigned short* W2Thi = (unsigned short*)alloc((size_t)NR * DOUT * DH * 2);
    unsigned short* Lhi   = (unsigned short*)alloc((size_t)128 * 256 * 2);
    unsigned short* Llo   = (unsigned short*)alloc((size_t)128 * 256 * 2);
    // region R (82 MB): msgu (l1 phase, 47.2 MB) then reused as dense Y2 table.
    // alpha1/qk1/e1 alias R's tail — all dead before y2_gemm writes R.
    char* msgr = (char*)alloc((size_t)NN * 1024 * 4);               // 81,920,000 B
    unsigned* msgu = (unsigned*)msgr;
    unsigned* Y2u  = (unsigned*)msgr;
    float* alpha1 = (float*)(msgr + (size_t)MSGROWS * 256 * 4);     // +47,185,920
    float* qk1    = alpha1 + 128 * 256;
    float* e1     = qk1 + (size_t)NN * 256;                         // ends ~78.0 MB < 81.9 MB

    hipMemsetAsync(ws, 0, zero_bytes, stream);
    alpha1_kernel<<<DIN, 256, 0, stream>>>(W1, aq1, ak1, alpha1);
    alpha2_kernel<<<(DH * 32 + 255) / 256, 256, 0, stream>>>(W2, aq2, ak2, alpha2);
    split_x_kernel<<<(NN * DIN / 4 + 255) / 256, 256, 0, stream>>>(x, xhi, xlo);
    splitW1T_kernel<<<NR * 8, 256, 0, stream>>>(W1, W1Thi);
    splitW2T_kernel<<<NR * 2, 256, 0, stream>>>(W2, W2Thi);
    splitLw1_kernel<<<(256 * 128 + 255) / 256, 256, 0, stream>>>(lw1, Lhi, Llo);
    hist_kernel<<<(NE + 255) / 256, 256, 0, stream>>>(ei, et, cnt, cnt_d);
    scan_bkt_kernel<<<1, 64, 0, stream>>>(cnt, boffs, cursor, cts);
    tilemap_kernel<<<(NTILESMAX1 + 255) / 256, 256, 0, stream>>>(boffs, tile_b, tile_s);
    bucket_place_kernel<<<(NE + 255) / 256, 256, 0, stream>>>(ei, et, cursor, border);
    scan_dst_kernel<<<1, 1024, 0, stream>>>(cnt_d, doffs, cursor_d);
    place_dst_kernel<<<(NE + 255) / 256, 256, 0, stream>>>(border, ei, et, cursor_d, dlist, dedge, dsr);
    qk1_kernel<<<(NN + TILE - 1) / TILE, 256, 0, stream>>>(x, alpha1, qk1);
    elogit1_kernel<<<(NE + 255) / 256, 256, 0, stream>>>(ei, et, qk1, e1);
    for (int c = 0; c < CHUNKS; ++c) {
        l1_gemm_kernel<<<MAXTPC1, 256, 0, stream>>>(xhi, xlo, W1Thi, ei, border,
                                                    tile_b, tile_s, boffs, cts, c, msgu);
        l1_agg_kernel<<<CHD, 256, 0, stream>>>(msgu, e1, dlist, dedge, doffs, boffs, c,
                                               hhi, hlo, alpha2, qk2v);
    }
    elogit2_kernel<<<(NE + 255) / 256, 256, 0, stream>>>(ei, et, qk2v, e2);
    y2_gemm_kernel<<<YGRID, 256, 0, stream>>>(hhi, hlo, W2Thi, Y2u);
    l2_agg_kernel<<<(NN + 3) / 4, 256, 0, stream>>>(Y2u, e2, dedge, dsr, doffs, zacc);
    decode_kernel<<<(NT + TILE - 1) / TILE, 256, 0, stream>>>(zacc, tgt, Lhi, Llo,
                                                              lb1, lw2, lb2, out);
}

// Round 11
// 659.510 us; speedup vs baseline: 1.8480x; 1.1670x over previous
//
#include <hip/hip_runtime.h>
#include <cstdint>
#include <cstddef>

#define NN     20000
#define NE     320000
#define NR     16
#define DIN    128
#define DH     512
#define DOUT   128
#define NT     50000
#define TILE   64                      // decode row tile
#define TILE1  128                     // layer-1 edge tile
#define CHUNKS 5
#define CHD    4000
#define NBUCKET (CHUNKS * NR)          // 80
#define MSGROWS 69888                  // max edges per chunk (64000 avg + >25 sigma)
#define MAXTPC1 2240                   // l1 grid per chunk (8*280 >= tiles*4)
#define NTILESMAX1 (NE / TILE1 + NBUCKET)
#define MT2Y   157                     // ceil(20000/128)
#define YGRID  (MT2Y * 16)             // 2512 = 8*314
#define QGRID  320                     // 157*2=314 padded to %8

typedef __attribute__((ext_vector_type(8))) short bf16x8;
typedef __attribute__((ext_vector_type(4))) float f32x4;

__device__ __forceinline__ unsigned short f2bf(float x) {
    unsigned int b = __float_as_uint(x);
    b = b + 0x7fffu + ((b >> 16) & 1u);
    return (unsigned short)(b >> 16);
}
__device__ __forceinline__ float bf2f(unsigned short u) {
    return __uint_as_float(((unsigned int)u) << 16);
}
__device__ __forceinline__ unsigned packbf(float lo, float hi) {
    return (unsigned)f2bf(lo) | ((unsigned)f2bf(hi) << 16);
}

// ---------------- fold attention vectors into weights ----------------
__global__ void alpha1_kernel(const float* __restrict__ W1, const float* __restrict__ aq1,
                              const float* __restrict__ ak1, float* __restrict__ alpha1) {
    int i = blockIdx.x;
    int c = threadIdx.x;
    int r = c >> 4, s = (c >> 3) & 1, h = c & 7;
    const float* att = (s == 0 ? aq1 : ak1) + (r * 8 + h) * 64;
    const float* w = W1 + ((size_t)(r * DIN + i)) * DH + h * 64;
    float acc = 0.f;
    #pragma unroll 8
    for (int o = 0; o < 64; ++o) acc += w[o] * att[o];
    alpha1[i * 256 + c] = acc;
}

__global__ void alpha2_kernel(const float* __restrict__ W2, const float* __restrict__ aq2,
                              const float* __restrict__ ak2, float* __restrict__ alpha2) {
    int g = blockIdx.x * blockDim.x + threadIdx.x;
    if (g >= DH * 32) return;
    int i = g >> 5, c = g & 31;
    int r = c >> 1, s = c & 1;
    const float* att = (s == 0 ? aq2 : ak2) + r * DOUT;
    const float* w = W2 + ((size_t)(r * DH + i)) * DOUT;
    float acc = 0.f;
    #pragma unroll 8
    for (int o = 0; o < DOUT; ++o) acc += w[o] * att[o];
    alpha2[i * 32 + c] = acc;
}

// alpha1 [128][256] f32 -> A1T hi/lo [256][128] bf16
__global__ void splitA1T_kernel(const float* __restrict__ alpha1, unsigned short* __restrict__ A1Thi,
                                unsigned short* __restrict__ A1Tlo) {
    int g = blockIdx.x * 256 + threadIdx.x;
    if (g >= 128 * 256) return;
    int c = g >> 7, i = g & 127;
    float v = alpha1[i * 256 + c];
    unsigned short h = f2bf(v);
    A1Thi[g] = h;
    A1Tlo[g] = f2bf(v - bf2f(h));
}

// ---------------- bf16 hi/lo precompute ----------------
__global__ void split_x_kernel(const float* __restrict__ x, unsigned short* __restrict__ xhi,
                               unsigned short* __restrict__ xlo) {
    int g = blockIdx.x * 256 + threadIdx.x;
    if (g >= NN * DIN / 4) return;
    float4 v = ((const float4*)x)[g];
    ushort4 h, l;
    h.x = f2bf(v.x); l.x = f2bf(v.x - bf2f(h.x));
    h.y = f2bf(v.y); l.y = f2bf(v.y - bf2f(h.y));
    h.z = f2bf(v.z); l.z = f2bf(v.z - bf2f(h.z));
    h.w = f2bf(v.w); l.w = f2bf(v.w - bf2f(h.w));
    ((ushort4*)xhi)[g] = h;
    ((ushort4*)xlo)[g] = l;
}

// W1 [16][128][512] -> W1T hi [16][512][128]
__global__ void splitW1T_kernel(const float* __restrict__ W1, unsigned short* __restrict__ Whi) {
    __shared__ float T[128 * 65];
    int r = blockIdx.x >> 3;
    int ob = blockIdx.x & 7;
    int tid = threadIdx.x;
    for (int idx = tid; idx < 128 * 64; idx += 256) {
        int i = idx >> 6, o = idx & 63;
        T[i * 65 + o] = W1[((size_t)(r * DIN + i)) * DH + ob * 64 + o];
    }
    __syncthreads();
    for (int idx = tid; idx < 64 * 128; idx += 256) {
        int o = idx >> 7, i = idx & 127;
        Whi[((size_t)r * DH + ob * 64 + o) * DIN + i] = f2bf(T[i * 65 + o]);
    }
}

// W2 [16][512][128] -> W2T hi [16][128][512]
__global__ void splitW2T_kernel(const float* __restrict__ W2, unsigned short* __restrict__ Whi) {
    __shared__ float T[128 * 65];
    int r = blockIdx.x >> 1;
    int ob = blockIdx.x & 1;
    int tid = threadIdx.x;
    for (int kc = 0; kc < 4; ++kc) {
        if (kc) __syncthreads();
        for (int idx = tid; idx < 128 * 64; idx += 256) {
            int k = idx >> 6, o = idx & 63;
            T[k * 65 + o] = W2[((size_t)(r * DH + kc * 128 + k)) * DOUT + ob * 64 + o];
        }
        __syncthreads();
        for (int idx = tid; idx < 64 * 128; idx += 256) {
            int o = idx >> 7, k = idx & 127;
            Whi[((size_t)r * DOUT + ob * 64 + o) * DH + kc * 128 + k] = f2bf(T[k * 65 + o]);
        }
    }
}

__global__ void splitLw1_kernel(const float* __restrict__ lw1, unsigned short* __restrict__ Lhi,
                                unsigned short* __restrict__ Llo) {
    int g = blockIdx.x * 256 + threadIdx.x;
    if (g >= 256 * 128) return;
    int o = g >> 8, k = g & 255;
    float v = lw1[k * 128 + o];
    unsigned short h = f2bf(v);
    Lhi[(size_t)o * 256 + k] = h;
    Llo[(size_t)o * 256 + k] = f2bf(v - bf2f(h));
}

// ---------------- sorts ----------------
__global__ void hist_kernel(const int* __restrict__ ei, const int* __restrict__ et,
                            int* __restrict__ cnt, int* __restrict__ cnt_d) {
    __shared__ int bins[NBUCKET];
    int t = threadIdx.x;
    if (t < NBUCKET) bins[t] = 0;
    __syncthreads();
    int e = blockIdx.x * 256 + t;
    if (e < NE) {
        int d = ei[NE + e];
        int key = (d / CHD) * NR + et[e];
        atomicAdd(&bins[key], 1);
        atomicAdd(&cnt_d[d], 1);
    }
    __syncthreads();
    if (t < NBUCKET && bins[t]) atomicAdd(&cnt[t], bins[t]);
}

__global__ void scan_bkt_kernel(const int* __restrict__ cnt, int* __restrict__ boffs,
                                int* __restrict__ cursor, int* __restrict__ cts) {
    if (threadIdx.x != 0) return;
    int acc = 0, tiles = 0;
    for (int b = 0; b < NBUCKET; ++b) {
        if ((b & (NR - 1)) == 0) cts[b >> 4] = tiles;
        boffs[b] = acc; cursor[b] = acc;
        int cn = cnt[b];
        tiles += (cn + TILE1 - 1) / TILE1;
        acc += cn;
    }
    boffs[NBUCKET] = acc; cts[CHUNKS] = tiles;
}

__global__ void tilemap_kernel(const int* __restrict__ boffs, int* __restrict__ tile_b,
                               int* __restrict__ tile_s) {
    __shared__ int bo[NBUCKET + 1];
    int tid = threadIdx.x;
    if (tid <= NBUCKET) bo[tid] = boffs[tid];
    __syncthreads();
    int t = blockIdx.x * 256 + tid;
    if (t >= NTILESMAX1) return;
    int acc = 0, bb = -1, ss = 0;
    for (int b = 0; b < NBUCKET; ++b) {
        int cn = bo[b + 1] - bo[b];
        int nt = (cn + TILE1 - 1) / TILE1;
        if (t >= acc && t < acc + nt) { bb = b; ss = bo[b] + (t - acc) * TILE1; }
        acc += nt;
    }
    tile_b[t] = bb; tile_s[t] = ss;
}

__global__ void bucket_place_kernel(const int* __restrict__ ei, const int* __restrict__ et,
                                    int* __restrict__ cursor, int* __restrict__ border) {
    __shared__ int binc[NBUCKET], base_[NBUCKET], rank_[NBUCKET];
    int t = threadIdx.x;
    if (t < NBUCKET) { binc[t] = 0; rank_[t] = 0; }
    __syncthreads();
    int e = blockIdx.x * 256 + t;
    int key = -1;
    if (e < NE) { key = (ei[NE + e] / CHD) * NR + et[e]; atomicAdd(&binc[key], 1); }
    __syncthreads();
    if (t < NBUCKET && binc[t]) base_[t] = atomicAdd(&cursor[t], binc[t]);
    __syncthreads();
    if (key >= 0) border[base_[key] + atomicAdd(&rank_[key], 1)] = e;
}

__global__ void scan_dst_kernel(const int* __restrict__ cnt_d, int* __restrict__ doffs,
                                int* __restrict__ cursor_d) {
    __shared__ int part[1024];
    int t = threadIdx.x;
    int base = t * 20;
    int s = 0;
    for (int i = 0; i < 20 && base + i < NN; ++i) s += cnt_d[base + i];
    part[t] = s;
    __syncthreads();
    for (int off = 1; off < 1024; off <<= 1) {
        int v = (t >= off) ? part[t - off] : 0;
        __syncthreads();
        part[t] += v;
        __syncthreads();
    }
    int run = part[t] - s;
    for (int i = 0; i < 20 && base + i < NN; ++i) {
        doffs[base + i] = run; cursor_d[base + i] = run;
        run += cnt_d[base + i];
    }
    if (t == 1023) doffs[NN] = part[1023];
}

__global__ void place_dst_kernel(const int* __restrict__ border, const int* __restrict__ ei,
                                 const int* __restrict__ et, int* __restrict__ cursor_d,
                                 int* __restrict__ dlist, int* __restrict__ dedge,
                                 int* __restrict__ dsr) {
    int pos = blockIdx.x * 256 + threadIdx.x;
    if (pos >= NE) return;
    int e = border[pos];
    int d = ei[NE + e];
    int idx = atomicAdd(&cursor_d[d], 1);
    dlist[idx] = pos;
    dedge[idx] = e;
    dsr[idx] = ei[e] * NR + et[e];
}

// ---------------- qk1 = x @ alpha1 (MFMA, 3-term split bf16) ----------------
__global__ __launch_bounds__(256, 2)
void qk1_mfma_kernel(const unsigned short* __restrict__ xhi, const unsigned short* __restrict__ xlo,
                     const unsigned short* __restrict__ A1Thi, const unsigned short* __restrict__ A1Tlo,
                     float* __restrict__ qk1) {
    int t = (blockIdx.x & 7) * (QGRID / 8) + (blockIdx.x >> 3);
    if (t >= MT2Y * 2) return;
    int mt = t >> 1, nb = t & 1;
    int n0 = mt * 128;
    __shared__ __align__(16) unsigned short Ah[128 * 64];
    __shared__ __align__(16) unsigned short Al[128 * 64];
    __shared__ __align__(16) unsigned short Bh_[128 * 64];
    __shared__ __align__(16) unsigned short Bl_[128 * 64];
    int tid = threadIdx.x;
    int w = tid >> 6, lane = tid & 63;
    int l15 = lane & 15, l4 = lane >> 4;
    int wr = w >> 1, wc = w & 1;
    f32x4 acc[4][4];
    #pragma unroll
    for (int m = 0; m < 4; ++m)
        #pragma unroll
        for (int n = 0; n < 4; ++n) acc[m][n] = (f32x4){0.f, 0.f, 0.f, 0.f};
    for (int kc = 0; kc < 2; ++kc) {            // K = 128, BK = 64
        if (kc) __syncthreads();
        {
            int row = tid >> 1, seg = tid & 1;
            int n = n0 + row; if (n >= NN) n = NN - 1;
            unsigned rb = row * 128, sw = (row & 7) << 4;
            const uint4* ph = (const uint4*)(xhi + (size_t)n * DIN + kc * 64 + seg * 32);
            const uint4* pl = (const uint4*)(xlo + (size_t)n * DIN + kc * 64 + seg * 32);
            const uint4* qh = (const uint4*)(A1Thi + (size_t)(nb * 128 + row) * DIN + kc * 64 + seg * 32);
            const uint4* ql = (const uint4*)(A1Tlo + (size_t)(nb * 128 + row) * DIN + kc * 64 + seg * 32);
            #pragma unroll
            for (int i = 0; i < 4; ++i) {
                unsigned off = (rb + seg * 64 + i * 16) ^ sw;
                *(uint4*)((char*)Ah + off) = ph[i];
                *(uint4*)((char*)Al + off) = pl[i];
                *(uint4*)((char*)Bh_ + off) = qh[i];
                *(uint4*)((char*)Bl_ + off) = ql[i];
            }
        }
        __syncthreads();
        bf16x8 ah[4][2], al[4][2], bh[4][2], bl[4][2];
        #pragma unroll
        for (int m = 0; m < 4; ++m) {
            int row = wr * 64 + m * 16 + l15;
            unsigned rb = row * 128, sw = (row & 7) << 4;
            #pragma unroll
            for (int ks = 0; ks < 2; ++ks) {
                unsigned off = (rb + ks * 64 + l4 * 16) ^ sw;
                ah[m][ks] = *(const bf16x8*)((const char*)Ah + off);
                al[m][ks] = *(const bf16x8*)((const char*)Al + off);
            }
        }
        #pragma unroll
        for (int n = 0; n < 4; ++n) {
            int col = wc * 64 + n * 16 + l15;
            unsigned rb = col * 128, sw = (col & 7) << 4;
            #pragma unroll
            for (int ks = 0; ks < 2; ++ks) {
                unsigned off = (rb + ks * 64 + l4 * 16) ^ sw;
                bh[n][ks] = *(const bf16x8*)((const char*)Bh_ + off);
                bl[n][ks] = *(const bf16x8*)((const char*)Bl_ + off);
            }
        }
        #pragma unroll
        for (int n = 0; n < 4; ++n)
            #pragma unroll
            for (int ks = 0; ks < 2; ++ks)
                #pragma unroll
                for (int m = 0; m < 4; ++m) {
                    acc[m][n] = __builtin_amdgcn_mfma_f32_16x16x32_bf16(ah[m][ks], bh[n][ks], acc[m][n], 0, 0, 0);
                    acc[m][n] = __builtin_amdgcn_mfma_f32_16x16x32_bf16(al[m][ks], bh[n][ks], acc[m][n], 0, 0, 0);
                    acc[m][n] = __builtin_amdgcn_mfma_f32_16x16x32_bf16(ah[m][ks], bl[n][ks], acc[m][n], 0, 0, 0);
                }
    }
    #pragma unroll
    for (int m = 0; m < 4; ++m) {
        int row0 = n0 + wr * 64 + m * 16 + l4 * 4;
        #pragma unroll
        for (int rg = 0; rg < 4; ++rg) {
            int row = row0 + rg;
            if (row < NN) {
                float* op = qk1 + (size_t)row * 256 + nb * 128 + wc * 64 + l15;
                #pragma unroll
                for (int n = 0; n < 4; ++n) op[n * 16] = acc[m][n][rg];
            }
        }
    }
}

__global__ void elogit1_kernel(const int* __restrict__ ei, const int* __restrict__ et,
                               const float* __restrict__ qk1, float* __restrict__ e1) {
    int e = blockIdx.x * blockDim.x + threadIdx.x;
    if (e >= NE) return;
    int src = ei[e], dst = ei[NE + e], r = et[e];
    const float* qp = qk1 + (size_t)dst * 256 + r * 16;
    const float* kp = qk1 + (size_t)src * 256 + r * 16 + 8;
    float* ep = e1 + (size_t)e * 8;
    #pragma unroll
    for (int h = 0; h < 8; ++h) {
        float l = qp[h] + kp[h];
        l = l > 0.f ? l : 0.2f * l;
        ep[h] = __expf(l);
    }
}

// ---------------- layer1 GEMM: 128x128 tiles, A(hi,lo)+B(hi) in LDS, 2 MFMA/product ----------------
__global__ __launch_bounds__(256, 3)
void l1_gemm_kernel(const unsigned short* __restrict__ xhi, const unsigned short* __restrict__ xlo,
                    const unsigned short* __restrict__ W1Thi,
                    const int* __restrict__ ei, const int* __restrict__ border,
                    const int* __restrict__ tile_b, const int* __restrict__ tile_s,
                    const int* __restrict__ boffs, const int* __restrict__ cts,
                    int c, unsigned* __restrict__ msgu) {
    int wg = (blockIdx.x & 7) * (MAXTPC1 / 8) + (blockIdx.x >> 3);   // XCD-contiguous
    int tt = wg >> 2, cb = wg & 3;
    int t = cts[c] + tt;
    if (t >= cts[c + 1]) return;
    int b = tile_b[t];
    int r = b & (NR - 1);
    int start = tile_s[t];
    int cstart = boffs[c * NR];
    int cnt = boffs[b + 1] - start; if (cnt > TILE1) cnt = TILE1;
    __shared__ __align__(16) unsigned short Ah[128 * 64];
    __shared__ __align__(16) unsigned short Al[128 * 64];
    __shared__ __align__(16) unsigned short Bh_[128 * 64];
    __shared__ int srcS[TILE1];
    int tid = threadIdx.x;
    if (tid < TILE1) {
        int sv = 0;
        if (tid < cnt) sv = ei[border[start + tid]];
        srcS[tid] = sv;
    }
    __syncthreads();
    int w = tid >> 6, lane = tid & 63;
    int l15 = lane & 15, l4 = lane >> 4;
    int wr = w >> 1, wc = w & 1;
    f32x4 acc[4][4];
    #pragma unroll
    for (int m = 0; m < 4; ++m)
        #pragma unroll
        for (int n = 0; n < 4; ++n) acc[m][n] = (f32x4){0.f, 0.f, 0.f, 0.f};
    for (int kc = 0; kc < 2; ++kc) {            // K = 128, BK = 64
        if (kc) __syncthreads();
        {
            int row = tid >> 1, seg = tid & 1;
            unsigned rb = row * 128, sw = (row & 7) << 4;
            const uint4* ph = (const uint4*)(xhi + (size_t)srcS[row] * DIN + kc * 64 + seg * 32);
            const uint4* pl = (const uint4*)(xlo + (size_t)srcS[row] * DIN + kc * 64 + seg * 32);
            const uint4* qh = (const uint4*)(W1Thi + ((size_t)r * DH + cb * 128 + row) * DIN + kc * 64 + seg * 32);
            #pragma unroll
            for (int i = 0; i < 4; ++i) {
                unsigned off = (rb + seg * 64 + i * 16) ^ sw;
                *(uint4*)((char*)Ah + off) = ph[i];
                *(uint4*)((char*)Al + off) = pl[i];
                *(uint4*)((char*)Bh_ + off) = qh[i];
            }
        }
        __syncthreads();
        bf16x8 ah[4][2], al[4][2], bh[4][2];
        #pragma unroll
        for (int m = 0; m < 4; ++m) {
            int row = wr * 64 + m * 16 + l15;
            unsigned rb = row * 128, sw = (row & 7) << 4;
            #pragma unroll
            for (int ks = 0; ks < 2; ++ks) {
                unsigned off = (rb + ks * 64 + l4 * 16) ^ sw;
                ah[m][ks] = *(const bf16x8*)((const char*)Ah + off);
                al[m][ks] = *(const bf16x8*)((const char*)Al + off);
            }
        }
        #pragma unroll
        for (int n = 0; n < 4; ++n) {
            int col = wc * 64 + n * 16 + l15;
            unsigned rb = col * 128, sw = (col & 7) << 4;
            #pragma unroll
            for (int ks = 0; ks < 2; ++ks) {
                unsigned off = (rb + ks * 64 + l4 * 16) ^ sw;
                bh[n][ks] = *(const bf16x8*)((const char*)Bh_ + off);
            }
        }
        #pragma unroll
        for (int n = 0; n < 4; ++n)
            #pragma unroll
            for (int ks = 0; ks < 2; ++ks)
                #pragma unroll
                for (int m = 0; m < 4; ++m) {
                    acc[m][n] = __builtin_amdgcn_mfma_f32_16x16x32_bf16(ah[m][ks], bh[n][ks], acc[m][n], 0, 0, 0);
                    acc[m][n] = __builtin_amdgcn_mfma_f32_16x16x32_bf16(al[m][ks], bh[n][ks], acc[m][n], 0, 0, 0);
                }
    }
    unsigned* mb = msgu + (size_t)(start - cstart) * 256 + cb * 64 + wc * 32 + l15;
    #pragma unroll
    for (int m = 0; m < 4; ++m) {
        int row0 = wr * 64 + m * 16 + l4 * 4;
        #pragma unroll
        for (int rg = 0; rg < 4; ++rg) {
            int row = row0 + rg;
            if (row < cnt) {
                unsigned* mp = mb + (size_t)row * 256;
                mp[0]  = packbf(acc[m][0][rg], acc[m][2][rg]);
                mp[16] = packbf(acc[m][1][rg], acc[m][3][rg]);
            }
        }
    }
}

// ---------------- layer1 agg (fused qk2) ----------------
__global__ void l1_agg_kernel(const unsigned* __restrict__ msgu, const float* __restrict__ e1,
                              const int* __restrict__ dlist, const int* __restrict__ dedge,
                              const int* __restrict__ doffs, const int* __restrict__ boffs,
                              int c, unsigned short* __restrict__ hhi, unsigned short* __restrict__ hlo,
                              const float* __restrict__ alpha2, float* __restrict__ qk2v) {
    __shared__ float hrow[DH];
    __shared__ float red[32][9];
    int tid = threadIdx.x;
    int d = c * CHD + blockIdx.x;
    if (d >= NN) return;
    int lo_ = doffs[d], hi_ = doffs[d + 1];
    int cstart = boffs[c * NR];
    int head = tid >> 5;
    float a0 = 0.f, a1 = 0.f, se = 0.f;
    for (int p = lo_; p < hi_; ++p) {
        int pos = dlist[p];
        float wgt = e1[(size_t)dedge[p] * 8 + head];
        se += wgt;
        unsigned v = msgu[(size_t)(pos - cstart) * 256 + tid];
        a0 += wgt * bf2f((unsigned short)(v & 0xffff));
        a1 += wgt * bf2f((unsigned short)(v >> 16));
    }
    float inv = 1.f / (se + 1e-16f);
    a0 *= inv; a1 *= inv;
    a0 = a0 > 0.f ? a0 : 0.f;
    a1 = a1 > 0.f ? a1 : 0.f;
    int w = tid >> 6, q = (tid >> 4) & 3, l15 = tid & 15;
    int nq = ((q >> 1) << 2) | (q & 1);
    int c0 = w * 128 + nq * 16 + l15;
    hrow[c0] = a0; hrow[c0 + 32] = a1;
    unsigned short h0 = f2bf(a0), h1 = f2bf(a1);
    hhi[(size_t)d * DH + c0] = h0;
    hlo[(size_t)d * DH + c0] = f2bf(a0 - bf2f(h0));
    hhi[(size_t)d * DH + c0 + 32] = h1;
    hlo[(size_t)d * DH + c0 + 32] = f2bf(a1 - bf2f(h1));
    __syncthreads();
    int j = tid & 31, ib = tid >> 5;
    float s = 0.f;
    #pragma unroll 8
    for (int i = ib * 64; i < ib * 64 + 64; ++i) s += hrow[i] * alpha2[(size_t)i * 32 + j];
    red[j][ib] = s;
    __syncthreads();
    if (tid < 32) {
        float t = 0.f;
        #pragma unroll
        for (int g = 0; g < 8; ++g) t += red[tid][g];
        qk2v[(size_t)d * 32 + tid] = t;
    }
}

__global__ void elogit2_kernel(const int* __restrict__ ei, const int* __restrict__ et,
                               const float* __restrict__ qk2, float* __restrict__ e2) {
    int e = blockIdx.x * blockDim.x + threadIdx.x;
    if (e >= NE) return;
    int src = ei[e], dst = ei[NE + e], r = et[e];
    float l = qk2[(size_t)dst * 32 + r * 2] + qk2[(size_t)src * 32 + r * 2 + 1];
    l = l > 0.f ? l : 0.2f * l;
    e2[e] = __expf(l);
}

// ---------------- dense Y2 = H @ W2_all : 128x128 tiles, A(hi,lo)+B(hi), 2 MFMA ----------------
__global__ __launch_bounds__(256, 3)
void y2_gemm_kernel(const unsigned short* __restrict__ hhi, const unsigned short* __restrict__ hlo,
                    const unsigned short* __restrict__ W2Thi,
                    unsigned* __restrict__ Y2u) {
    int t = (blockIdx.x & 7) * (YGRID / 8) + (blockIdx.x >> 3);   // XCD-contiguous
    int mt = t >> 4, r = t & 15;
    int n0 = mt * 128;
    __shared__ __align__(16) unsigned short Ah[128 * 64];
    __shared__ __align__(16) unsigned short Al[128 * 64];
    __shared__ __align__(16) unsigned short Bh_[128 * 64];
    int tid = threadIdx.x;
    int w = tid >> 6, lane = tid & 63;
    int l15 = lane & 15, l4 = lane >> 4;
    int wr = w >> 1, wc = w & 1;
    f32x4 acc[4][4];
    #pragma unroll
    for (int m = 0; m < 4; ++m)
        #pragma unroll
        for (int n = 0; n < 4; ++n) acc[m][n] = (f32x4){0.f, 0.f, 0.f, 0.f};
    for (int kc = 0; kc < 8; ++kc) {            // K = 512, BK = 64
        if (kc) __syncthreads();
        {
            int row = tid >> 1, seg = tid & 1;
            int n = n0 + row; if (n >= NN) n = NN - 1;
            unsigned rb = row * 128, sw = (row & 7) << 4;
            const uint4* ph = (const uint4*)(hhi + (size_t)n * DH + kc * 64 + seg * 32);
            const uint4* pl = (const uint4*)(hlo + (size_t)n * DH + kc * 64 + seg * 32);
            const uint4* qh = (const uint4*)(W2Thi + ((size_t)r * DOUT + row) * DH + kc * 64 + seg * 32);
            #pragma unroll
            for (int i = 0; i < 4; ++i) {
                unsigned off = (rb + seg * 64 + i * 16) ^ sw;
                *(uint4*)((char*)Ah + off) = ph[i];
                *(uint4*)((char*)Al + off) = pl[i];
                *(uint4*)((char*)Bh_ + off) = qh[i];
            }
        }
        __syncthreads();
        bf16x8 ah[4][2], al[4][2], bh[4][2];
        #pragma unroll
        for (int m = 0; m < 4; ++m) {
            int row = wr * 64 + m * 16 + l15;
            unsigned rb = row * 128, sw = (row & 7) << 4;
            #pragma unroll
            for (int ks = 0; ks < 2; ++ks) {
                unsigned off = (rb + ks * 64 + l4 * 16) ^ sw;
                ah[m][ks] = *(const bf16x8*)((const char*)Ah + off);
                al[m][ks] = *(const bf16x8*)((const char*)Al + off);
            }
        }
        #pragma unroll
        for (int n = 0; n < 4; ++n) {
            int col = wc * 64 + n * 16 + l15;
            unsigned rb = col * 128, sw = (col & 7) << 4;
            #pragma unroll
            for (int ks = 0; ks < 2; ++ks) {
                unsigned off = (rb + ks * 64 + l4 * 16) ^ sw;
                bh[n][ks] = *(const bf16x8*)((const char*)Bh_ + off);
            }
        }
        #pragma unroll
        for (int n = 0; n < 4; ++n)
            #pragma unroll
            for (int ks = 0; ks < 2; ++ks)
                #pragma unroll
                for (int m = 0; m < 4; ++m) {
                    acc[m][n] = __builtin_amdgcn_mfma_f32_16x16x32_bf16(ah[m][ks], bh[n][ks], acc[m][n], 0, 0, 0);
                    acc[m][n] = __builtin_amdgcn_mfma_f32_16x16x32_bf16(al[m][ks], bh[n][ks], acc[m][n], 0, 0, 0);
                }
    }
    unsigned* mb = Y2u + (size_t)n0 * 1024 + r * 64 + wc * 32 + l15;
    #pragma unroll
    for (int m = 0; m < 4; ++m) {
        int row0 = wr * 64 + m * 16 + l4 * 4;
        #pragma unroll
        for (int rg = 0; rg < 4; ++rg) {
            int row = row0 + rg;
            if (n0 + row < NN) {
                unsigned* mp = mb + (size_t)row * 1024;
                mp[0]  = packbf(acc[m][0][rg], acc[m][2][rg]);
                mp[16] = packbf(acc[m][1][rg], acc[m][3][rg]);
            }
        }
    }
}

// ---------------- layer2 agg: gather Y2[src*16+r] rows per dst ----------------
__global__ void l2_agg_kernel(const unsigned* __restrict__ Y2u, const float* __restrict__ e2,
                              const int* __restrict__ dedge, const int* __restrict__ dsr,
                              const int* __restrict__ doffs, float* __restrict__ zacc) {
    int tid = threadIdx.x;
    int d = blockIdx.x * 4 + (tid >> 6);
    if (d >= NN) return;
    int lane = tid & 63;
    int lo_ = doffs[d], hi_ = doffs[d + 1];
    float a0 = 0.f, a1 = 0.f, se = 0.f;
    for (int p = lo_; p < hi_; ++p) {
        float wgt = e2[dedge[p]];
        se += wgt;
        unsigned v = Y2u[(size_t)dsr[p] * 64 + lane];
        a0 += wgt * bf2f((unsigned short)(v & 0xffff));
        a1 += wgt * bf2f((unsigned short)(v >> 16));
    }
    float inv = 1.f / (se + 1e-16f);
    int q = lane >> 4, l15 = lane & 15;
    int nq = ((q >> 1) << 2) | (q & 1);
    int c0 = nq * 16 + l15;
    zacc[(size_t)d * DOUT + c0] = a0 * inv;
    zacc[(size_t)d * DOUT + c0 + 32] = a1 * inv;
}

// ---------------- link-prediction decoder (MFMA, split bf16, full 3-term) ----------------
__global__ __launch_bounds__(256, 2)
void decode_kernel(const float* __restrict__ z, const int* __restrict__ tgt,
                   const unsigned short* __restrict__ Lhi, const unsigned short* __restrict__ Llo,
                   const float* __restrict__ lb1, const float* __restrict__ lw2,
                   const float* __restrict__ lb2, float* __restrict__ out) {
    __shared__ __align__(16) unsigned short Ah[64 * 256];
    __shared__ __align__(16) unsigned short Al[64 * 256];
    __shared__ float red[TILE][5];
    int t0 = blockIdx.x * TILE;
    int tid = threadIdx.x;
    int cnt = NT - t0; if (cnt > TILE) cnt = TILE;
    {
        int row = tid >> 2, seg = tid & 3;
        int node = 0;
        bool live = (row < cnt);
        if (live) node = tgt[(seg >> 1) * NT + t0 + row];
        const float4* pz = (const float4*)(z + (size_t)node * DOUT + (seg & 1) * 64);
        unsigned rb = row * 512, sb = (seg >> 1) * 256 + (seg & 1) * 128;
        unsigned sw = (row & 7) << 4;
        #pragma unroll
        for (int g = 0; g < 8; ++g) {
            float4 a = live ? pz[g * 2] : (float4){0,0,0,0};
            float4 bq = live ? pz[g * 2 + 1] : (float4){0,0,0,0};
            unsigned short h0 = f2bf(a.x), h1 = f2bf(a.y), h2 = f2bf(a.z), h3 = f2bf(a.w);
            unsigned short h4 = f2bf(bq.x), h5 = f2bf(bq.y), h6 = f2bf(bq.z), h7 = f2bf(bq.w);
            uint4 uh, ul;
            uh.x = (unsigned)h0 | ((unsigned)h1 << 16);
            uh.y = (unsigned)h2 | ((unsigned)h3 << 16);
            uh.z = (unsigned)h4 | ((unsigned)h5 << 16);
            uh.w = (unsigned)h6 | ((unsigned)h7 << 16);
            ul.x = (unsigned)f2bf(a.x - bf2f(h0)) | ((unsigned)f2bf(a.y - bf2f(h1)) << 16);
            ul.y = (unsigned)f2bf(a.z - bf2f(h2)) | ((unsigned)f2bf(a.w - bf2f(h3)) << 16);
            ul.z = (unsigned)f2bf(bq.x - bf2f(h4)) | ((unsigned)f2bf(bq.y - bf2f(h5)) << 16);
            ul.w = (unsigned)f2bf(bq.z - bf2f(h6)) | ((unsigned)f2bf(bq.w - bf2f(h7)) << 16);
            unsigned off = (rb + sb + g * 16) ^ sw;
            *(uint4*)((char*)Ah + off) = uh;
            *(uint4*)((char*)Al + off) = ul;
        }
    }
    __syncthreads();
    int w = tid >> 6, lane = tid & 63;
    int l15 = lane & 15, l4 = lane >> 4;
    const unsigned short* Bh = Lhi + (size_t)(w * 32 + l15) * 256 + l4 * 8;
    const unsigned short* Bl = Llo + (size_t)(w * 32 + l15) * 256 + l4 * 8;
    f32x4 acc[4][2];
    #pragma unroll
    for (int m = 0; m < 4; ++m) { acc[m][0] = (f32x4){0.f,0.f,0.f,0.f}; acc[m][1] = (f32x4){0.f,0.f,0.f,0.f}; }
    #pragma unroll
    for (int k = 0; k < 8; ++k) {
        bf16x8 ah[4], al[4];
        #pragma unroll
        for (int m = 0; m < 4; ++m) {
            int row = m * 16 + l15;
            unsigned off = ((unsigned)row * 512 + k * 64 + l4 * 16) ^ ((unsigned)(row & 7) << 4);
            ah[m] = *(const bf16x8*)((const char*)Ah + off);
            al[m] = *(const bf16x8*)((const char*)Al + off);
        }
        #pragma unroll
        for (int n = 0; n < 2; ++n) {
            bf16x8 bh = *(const bf16x8*)(Bh + (size_t)n * 16 * 256 + k * 32);
            bf16x8 bl = *(const bf16x8*)(Bl + (size_t)n * 16 * 256 + k * 32);
            #pragma unroll
            for (int m = 0; m < 4; ++m) {
                acc[m][n] = __builtin_amdgcn_mfma_f32_16x16x32_bf16(ah[m], bh, acc[m][n], 0, 0, 0);
                acc[m][n] = __builtin_amdgcn_mfma_f32_16x16x32_bf16(ah[m], bl, acc[m][n], 0, 0, 0);
                acc[m][n] = __builtin_amdgcn_mfma_f32_16x16x32_bf16(al[m], bh, acc[m][n], 0, 0, 0);
            }
        }
    }
    int col0 = w * 32 + l15;
    float lb_0 = lb1[col0], lb_1 = lb1[col0 + 16];
    float lwa = lw2[col0], lwb = lw2[col0 + 16];
    #pragma unroll
    for (int m = 0; m < 4; ++m) {
        #pragma unroll
        for (int rg = 0; rg < 4; ++rg) {
            float h0 = acc[m][0][rg] + lb_0; h0 = h0 > 0.f ? h0 : 0.f;
            float h1 = acc[m][1][rg] + lb_1; h1 = h1 > 0.f ? h1 : 0.f;
            float s = h0 * lwa + h1 * lwb;
            s += __shfl_xor(s, 1); s += __shfl_xor(s, 2);
            s += __shfl_xor(s, 4); s += __shfl_xor(s, 8);
            if (l15 == 0) red[m * 16 + l4 * 4 + rg][w] = s;
        }
    }
    __syncthreads();
    if (tid < cnt) out[t0 + tid] = red[tid][0] + red[tid][1] + red[tid][2] + red[tid][3] + lb2[0];
}

extern "C" void kernel_launch(void* const* d_in, const int* in_sizes, int n_in,
                              void* d_out, int out_size, void* d_ws, size_t ws_size,
                              hipStream_t stream) {
    const float* x   = (const float*)d_in[0];
    const int*   ei  = (const int*)d_in[1];
    const int*   et  = (const int*)d_in[2];
    const int*   tgt = (const int*)d_in[3];
    const float* W1  = (const float*)d_in[4];
    const float* aq1 = (const float*)d_in[5];
    const float* ak1 = (const float*)d_in[6];
    const float* W2  = (const float*)d_in[7];
    const float* aq2 = (const float*)d_in[8];
    const float* ak2 = (const float*)d_in[9];
    const float* lw1 = (const float*)d_in[10];
    const float* lb1 = (const float*)d_in[11];
    const float* lw2 = (const float*)d_in[12];
    const float* lb2 = (const float*)d_in[13];
    float* out = (float*)d_out;
    (void)in_sizes; (void)n_in; (void)out_size; (void)ws_size;

    char* ws = (char*)d_ws;
    size_t off = 0;
    auto alloc = [&](size_t bytes) -> void* {
        void* p = ws + off;
        off += (bytes + 255) & ~(size_t)255;
        return p;
    };
    // zero-init block: histograms only
    int* cnt   = (int*)alloc(NBUCKET * sizeof(int));
    int* cnt_d = (int*)alloc((size_t)NN * sizeof(int));
    size_t zero_bytes = off;
    // no-init scratch
    int*   boffs    = (int*)alloc((NBUCKET + 1) * sizeof(int));
    int*   cursor   = (int*)alloc(NBUCKET * sizeof(int));
    int*   cts      = (int*)alloc((CHUNKS + 1) * sizeof(int));
    int*   doffs    = (int*)alloc((size_t)(NN + 1) * sizeof(int));
    int*   cursor_d = (int*)alloc((size_t)NN * sizeof(int));
    int*   border   = (int*)alloc((size_t)NE * sizeof(int));
    int*   dlist    = (int*)alloc((size_t)NE * sizeof(int));
    int*   dedge    = (int*)alloc((size_t)NE * sizeof(int));
    int*   dsr      = (int*)alloc((size_t)NE * sizeof(int));
    int*   tile_b   = (int*)alloc((size_t)NTILESMAX1 * sizeof(int));
    int*   tile_s   = (int*)alloc((size_t)NTILESMAX1 * sizeof(int));
    float* alpha2   = (float*)alloc((size_t)512 * 32 * 4);
    float* qk2v     = (float*)alloc((size_t)NN * 32 * 4);
    float* e2       = (float*)alloc((size_t)NE * 4);
    float* zacc     = (float*)alloc((size_t)NN * DOUT * 4);
    unsigned short* xhi   = (unsigned short*)alloc((size_t)NN * DIN * 2);
    unsigned short* xlo   = (unsigned short*)alloc((size_t)NN * DIN * 2);
    unsigned short* hhi   = (unsigned short*)alloc((size_t)NN * DH * 2);
    unsigned short* hlo   = (unsigned short*)alloc((size_t)NN * DH * 2);
    unsigned short* W1Thi = (unsigned short*)alloc((size_t)NR * DH * DIN * 2);
    unsigned short* W2Thi = (unsigned short*)alloc((size_t)NR * DOUT * DH * 2);
    unsigned short* Lhi   = (unsigned short*)alloc((size_t)128 * 256 * 2);
    unsigned short* Llo   = (unsigned short*)alloc((size_t)128 * 256 * 2);
    unsigned short* A1Thi = (unsigned short*)alloc((size_t)256 * 128 * 2);
    unsigned short* A1Tlo = (unsigned short*)alloc((size_t)256 * 128 * 2);
    // region R (82 MB): [alpha1|qk1] alias the head (dead before chunk-0 gemm);
    // msg occupies rows [0, MSGROWS); e1 sits at the fixed tail offset.
    // After the l1 loop the whole region is reused as the dense Y2 table.
    char* msgr = (char*)alloc((size_t)NN * 1024 * 4);               // 81,920,000 B
    unsigned* msgu = (unsigned*)msgr;
    unsigned* Y2u  = (unsigned*)msgr;
    float* alpha1 = (float*)msgr;                                   // 131,072 B
    float* qk1    = (float*)(msgr + 131072);                        // 20,480,000 B
    float* e1     = (float*)(msgr + (size_t)MSGROWS * 1024);        // 10,240,000 B, ends 81.8 MB

    hipMemsetAsync(ws, 0, zero_bytes, stream);
    alpha1_kernel<<<DIN, 256, 0, stream>>>(W1, aq1, ak1, alpha1);
    splitA1T_kernel<<<(128 * 256 + 255) / 256, 256, 0, stream>>>(alpha1, A1Thi, A1Tlo);
    alpha2_kernel<<<(DH * 32 + 255) / 256, 256, 0, stream>>>(W2, aq2, ak2, alpha2);
    split_x_kernel<<<(NN * DIN / 4 + 255) / 256, 256, 0, stream>>>(x, xhi, xlo);
    splitW1T_kernel<<<NR * 8, 256, 0, stream>>>(W1, W1Thi);
    splitW2T_kernel<<<NR * 2, 256, 0, stream>>>(W2, W2Thi);
    splitLw1_kernel<<<(256 * 128 + 255) / 256, 256, 0, stream>>>(lw1, Lhi, Llo);
    hist_kernel<<<(NE + 255) / 256, 256, 0, stream>>>(ei, et, cnt, cnt_d);
    scan_bkt_kernel<<<1, 64, 0, stream>>>(cnt, boffs, cursor, cts);
    tilemap_kernel<<<(NTILESMAX1 + 255) / 256, 256, 0, stream>>>(boffs, tile_b, tile_s);
    bucket_place_kernel<<<(NE + 255) / 256, 256, 0, stream>>>(ei, et, cursor, border);
    scan_dst_kernel<<<1, 1024, 0, stream>>>(cnt_d, doffs, cursor_d);
    place_dst_kernel<<<(NE + 255) / 256, 256, 0, stream>>>(border, ei, et, cursor_d, dlist, dedge, dsr);
    qk1_mfma_kernel<<<QGRID, 256, 0, stream>>>(xhi, xlo, A1Thi, A1Tlo, qk1);
    elogit1_kernel<<<(NE + 255) / 256, 256, 0, stream>>>(ei, et, qk1, e1);
    for (int c = 0; c < CHUNKS; ++c) {
        l1_gemm_kernel<<<MAXTPC1, 256, 0, stream>>>(xhi, xlo, W1Thi, ei, border,
                                                    tile_b, tile_s, boffs, cts, c, msgu);
        l1_agg_kernel<<<CHD, 256, 0, stream>>>(msgu, e1, dlist, dedge, doffs, boffs, c,
                                               hhi, hlo, alpha2, qk2v);
    }
    elogit2_kernel<<<(NE + 255) / 256, 256, 0, stream>>>(ei, et, qk2v, e2);
    y2_gemm_kernel<<<YGRID, 256, 0, stream>>>(hhi, hlo, W2Thi, Y2u);
    l2_agg_kernel<<<(NN + 3) / 4, 256, 0, stream>>>(Y2u, e2, dedge, dsr, doffs, zacc);
    decode_kernel<<<(NT + TILE - 1) / TILE, 256, 0, stream>>>(zacc, tgt, Lhi, Llo,
                                                              lb1, lw2, lb2, out);
}